// Round 11
// baseline (664.100 us; speedup 1.0000x reference)
//
#include <hip/hip_runtime.h>

// ---------------------------------------------------------------------------
// Hybrid MRHA: conv-downsample + 3 attention branches + LN + gated fusion.
// k_gemm64  : 128x64 tile, BK=64, XOR-swizzled LDS, counted-vmcnt 2-barrier
//             loop, 48 KB LDS -> 3 blocks/CU. All projections, conv, PV.
// k_gemm256 : 256x256, BK=32, XOR-swizzled LDS, counted-vmcnt 2-barrier loop,
//             direct write-exact epilogue. Scores only.
// V^T computed directly as W_v * X^T (mode 3) — no transposed scatter.
// ---------------------------------------------------------------------------

typedef __attribute__((ext_vector_type(8))) __bf16 bf16x8;
typedef __attribute__((ext_vector_type(4))) float f32x4;

#define CDIM 512
#define TFULL 2048

#define GLL16(gp, lp)                                                        \
  __builtin_amdgcn_global_load_lds(                                          \
      (const __attribute__((address_space(1))) unsigned int*)(gp),           \
      (__attribute__((address_space(3))) unsigned int*)(lp), 16, 0, 0)

__device__ __forceinline__ unsigned short f2bf(float f) {
  unsigned u = __float_as_uint(f);
  u = (u + 0x7fffu + ((u >> 16) & 1u)) >> 16;   // round-to-nearest-even
  return (unsigned short)u;
}
__device__ __forceinline__ float bf2f(unsigned short h) {
  return __uint_as_float(((unsigned)h) << 16);
}

// ---------------- conversion: f32 -> bf16 (vec4) ----------------
__global__ __launch_bounds__(256)
void k_tobf16(const float* __restrict__ src, unsigned short* __restrict__ dst, long n4) {
  long i = (long)blockIdx.x * 256 + threadIdx.x;
  if (i >= n4) return;
  float4 f = reinterpret_cast<const float4*>(src)[i];
  unsigned short o4[4] = {f2bf(f.x), f2bf(f.y), f2bf(f.z), f2bf(f.w)};
  reinterpret_cast<uint2*>(dst)[i] = *reinterpret_cast<const uint2*>(o4);
}

// ---------------- batched weight conversion: 9 x 512x512 -> WB ----------
struct WPtrs { const float* p[9]; };
__global__ __launch_bounds__(256)
void k_tobf16w(WPtrs w, unsigned short* __restrict__ dst) {
  int idx = blockIdx.x * 256 + threadIdx.x;       // over 9*65536 vec4 units
  if (idx >= 9 * 65536) return;
  int m = idx >> 16, off = idx & 65535;
  float4 f = reinterpret_cast<const float4*>(w.p[m])[off];
  unsigned short o4[4] = {f2bf(f.x), f2bf(f.y), f2bf(f.z), f2bf(f.w)};
  reinterpret_cast<uint2*>(dst + (long)m * 262144)[off] = *reinterpret_cast<const uint2*>(o4);
}

// ---------------- dw [o][i][k] -> DWB bf16 [o][k*512+i] ----------------
__global__ __launch_bounds__(256)
void k_dwreorder(const float* __restrict__ dw, unsigned short* __restrict__ dwb) {
  int idx = blockIdx.x * 256 + threadIdx.x;           // over 512*1536
  if (idx >= 512 * 1536) return;
  int o = idx / 1536, rem = idx - o * 1536;
  int k = rem >> 9, i = rem & 511;
  dwb[idx] = f2bf(dw[(o * 512 + i) * 3 + k]);
}

// ---------------- conv row-0 fixup: one wave per (b,o), coalesced ---------
__global__ __launch_bounds__(256)
void k_fix(const unsigned short* __restrict__ XB, const unsigned short* __restrict__ DWB,
           const float* __restrict__ db, unsigned short* __restrict__ XD) {
  const int lane = threadIdx.x & 63, wave = threadIdx.x >> 6;
  const int idx = blockIdx.x * 4 + wave;      // 4096 = 8 batches * 512 outputs
  const int b = idx >> 9, o = idx & 511;
  const unsigned short* xr = XB + (long)b * TFULL * CDIM + lane * 16;  // rows 0,1
  const unsigned short* wr = DWB + (long)o * 1536 + 512 + lane * 16;   // taps 1,2
  float acc = 0.f;
  uint4 xv0 = *reinterpret_cast<const uint4*>(xr);
  uint4 xv1 = *reinterpret_cast<const uint4*>(xr + 8);
  uint4 wv0 = *reinterpret_cast<const uint4*>(wr);
  uint4 wv1 = *reinterpret_cast<const uint4*>(wr + 8);
  const unsigned short* xp0 = (const unsigned short*)&xv0;
  const unsigned short* xp1 = (const unsigned short*)&xv1;
  const unsigned short* wp0 = (const unsigned short*)&wv0;
  const unsigned short* wp1 = (const unsigned short*)&wv1;
#pragma unroll
  for (int j = 0; j < 8; ++j) acc += bf2f(xp0[j]) * bf2f(wp0[j]);
#pragma unroll
  for (int j = 0; j < 8; ++j) acc += bf2f(xp1[j]) * bf2f(wp1[j]);
#pragma unroll
  for (int off = 32; off > 0; off >>= 1) acc += __shfl_xor(acc, off);
  if (lane == 0) XD[(long)b * 1024 * 512 + o] = f2bf(acc + db[o]);
}

// ---------------- GEMM 128x64: C = alpha * A * B^T + bias ----------------
// mode 1: bf16 store, bias[col] | mode 3: bf16 store, bias[row]
// counted-vmcnt 2-barrier pipeline; 48 KB LDS -> 3 blocks/CU.
// Requires: M%128==0, N%64==0, K%64==0, (M/128)*(N/64)%8==0.
__global__ __launch_bounds__(256)
void k_gemm64(const unsigned short* __restrict__ A,
              const unsigned short* __restrict__ B,
              void* __restrict__ Cp,
              int K, int lda, int ldb, int ldc,
              long sA, long sB, long sC,
              const float* __restrict__ bias,
              float alpha, int mode) {
  const int gx = gridDim.x;
  const int nwg = gx * gridDim.y;
  int wg = blockIdx.x + gx * blockIdx.y;
  wg = (wg & 7) * (nwg >> 3) + (wg >> 3);
  const int tm0 = (wg % gx) * 128, tn0 = (wg / gx) * 64;
  const int bz = blockIdx.z;
  const unsigned short* Ag = A + (long)bz * sA;
  const unsigned short* Bg = B + (long)bz * sB;

  // A: 2 bufs x 8192 elems (128x64); B: 2 bufs x 4096 elems (64x64) = 48 KB
  __shared__ __align__(16) unsigned short smem[24576];

  const int tid = threadIdx.x;
  const int lane = tid & 63;
  const int wave = tid >> 6;
  const int wm = (wave >> 1) * 64, wn = (wave & 1) * 32;
  const int lrow = lane & 15, kq = lane >> 4;

  f32x4 acc[4][2];
#pragma unroll
  for (int i = 0; i < 4; ++i)
#pragma unroll
    for (int j = 0; j < 2; ++j) acc[i][j] = f32x4{0.f, 0.f, 0.f, 0.f};

  const int sr = tid >> 3;                 // 0..31
  const int sj = (tid & 7) ^ (sr & 7);     // inverse-swizzled source slot
  const unsigned short* aSrc = Ag + (long)(tm0 + sr) * lda + sj * 8;
  const unsigned short* bSrc = Bg + (long)(tn0 + sr) * ldb + sj * 8;

  const int nt = K >> 6;

#define STAGE64(kt_, buf_)                                                   \
  {                                                                          \
    unsigned short* aD = smem + (buf_) * 8192 + wave * 512;                  \
    unsigned short* bD = smem + 16384 + (buf_) * 4096 + wave * 512;          \
    _Pragma("unroll")                                                        \
    for (int rd = 0; rd < 4; ++rd)                                           \
      GLL16(aSrc + (kt_) + (long)rd * 32 * lda, aD + rd * 2048);             \
    _Pragma("unroll")                                                        \
    for (int rd = 0; rd < 2; ++rd)                                           \
      GLL16(bSrc + (kt_) + (long)rd * 32 * ldb, bD + rd * 2048);             \
  }

  STAGE64(0, 0);

  const int xr = (lrow & 7) << 3;
  for (int t = 0; t < nt; ++t) {
    if (t + 1 < nt) {
      STAGE64((t + 1) << 6, (t + 1) & 1);  // prefetch stays in flight
      asm volatile("s_waitcnt vmcnt(6)" ::: "memory");   // my tile-t loads done
    } else {
      asm volatile("s_waitcnt vmcnt(0)" ::: "memory");   // final drain (once)
    }
    __builtin_amdgcn_s_barrier();          // everyone's tile-t loads done
    __builtin_amdgcn_sched_barrier(0);
    const unsigned short* As_ = smem + (t & 1) * 8192;
    const unsigned short* Bs_ = smem + 16384 + (t & 1) * 4096;
    bf16x8 af[4][2], bfv[2][2];
#pragma unroll
    for (int mi = 0; mi < 4; ++mi)
#pragma unroll
      for (int ks = 0; ks < 2; ++ks)
        af[mi][ks] = *reinterpret_cast<const bf16x8*>(
            &As_[(wm + mi * 16 + lrow) * 64 + ((ks * 32 + kq * 8) ^ xr)]);
#pragma unroll
    for (int ni = 0; ni < 2; ++ni)
#pragma unroll
      for (int ks = 0; ks < 2; ++ks)
        bfv[ni][ks] = *reinterpret_cast<const bf16x8*>(
            &Bs_[(wn + ni * 16 + lrow) * 64 + ((ks * 32 + kq * 8) ^ xr)]);
#pragma unroll
    for (int mi = 0; mi < 4; ++mi)
#pragma unroll
      for (int ni = 0; ni < 2; ++ni) {
        acc[mi][ni] = __builtin_amdgcn_mfma_f32_16x16x32_bf16(af[mi][0], bfv[ni][0], acc[mi][ni], 0, 0, 0);
        acc[mi][ni] = __builtin_amdgcn_mfma_f32_16x16x32_bf16(af[mi][1], bfv[ni][1], acc[mi][ni], 0, 0, 0);
      }
    __builtin_amdgcn_sched_barrier(0);
    if (t + 1 < nt) __builtin_amdgcn_s_barrier();  // reads done: next STAGE may overwrite
  }
#undef STAGE64

  unsigned short* Cb = (unsigned short*)Cp + (long)bz * sC;
  if (mode == 1) {
#pragma unroll
    for (int mi = 0; mi < 4; ++mi) {
      int rg = tm0 + wm + mi * 16 + kq * 4;
#pragma unroll
      for (int ni = 0; ni < 2; ++ni) {
        int cg = tn0 + wn + ni * 16 + lrow;
        float bb = bias ? bias[cg] : 0.f;
        f32x4 v = acc[mi][ni];
#pragma unroll
        for (int r = 0; r < 4; ++r)
          Cb[(long)(rg + r) * ldc + cg] = f2bf(v[r] * alpha + bb);
      }
    }
  } else {                                 // mode 3: bias indexed by row
#pragma unroll
    for (int mi = 0; mi < 4; ++mi) {
      int rg = tm0 + wm + mi * 16 + kq * 4;
      float rb[4];
#pragma unroll
      for (int r = 0; r < 4; ++r) rb[r] = bias[rg + r];
#pragma unroll
      for (int ni = 0; ni < 2; ++ni) {
        int cg = tn0 + wn + ni * 16 + lrow;
        f32x4 v = acc[mi][ni];
#pragma unroll
        for (int r = 0; r < 4; ++r)
          Cb[(long)(rg + r) * ldc + cg] = f2bf(v[r] * alpha + rb[r]);
      }
    }
  }
}

// ---------------- GEMM 256x256 (scores): C = alpha * A * B^T --------------
// BK=32 dbuf, counted vmcnt(4) + 2 raw barriers per K-tile.
// Direct write-exact epilogue.
// Requires M%256==0, N%256==0, K%32==0, (M/256)*(N/256)%8==0.
__global__ __launch_bounds__(512)
void k_gemm256(const unsigned short* __restrict__ A,
               const unsigned short* __restrict__ B,
               unsigned short* __restrict__ C,
               int K, int lda, int ldb, int ldc,
               long sA, long sB, long sC,
               float alpha, const float* __restrict__ tempPtr) {
  const int gx = gridDim.x;
  const int nwg = gx * gridDim.y;
  int wg = blockIdx.x + gx * blockIdx.y;
  wg = (wg & 7) * (nwg >> 3) + (wg >> 3);
  const int tm0 = (wg % gx) * 256, tn0 = (wg / gx) * 256;
  const unsigned short* Ag = A + (long)blockIdx.z * sA;
  const unsigned short* Bg = B + (long)blockIdx.z * sB;

  __shared__ __align__(16) unsigned short smem[32768];

  const int tid = threadIdx.x;
  const int lane = tid & 63;
  const int wave = tid >> 6;               // 0..7
  const int wm = (wave >> 2) * 128, wn = (wave & 3) * 64;
  const int lrow = lane & 15, kq = lane >> 4;

  f32x4 acc[8][4];
#pragma unroll
  for (int i = 0; i < 8; ++i)
#pragma unroll
    for (int j = 0; j < 4; ++j) acc[i][j] = f32x4{0.f, 0.f, 0.f, 0.f};

  const int srow = lane >> 2;                          // 0..15
  const int sslot = (lane & 3) ^ ((lane >> 3) & 3);    // inverse swizzle
  const unsigned short* aS0 = Ag + (long)(tm0 + wave * 16 + srow) * lda + sslot * 8;
  const unsigned short* aS1 = aS0 + 128L * lda;
  const unsigned short* bS0 = Bg + (long)(tn0 + wave * 16 + srow) * ldb + sslot * 8;
  const unsigned short* bS1 = bS0 + 128L * ldb;

  const int nt = K >> 5;

#define STAGE256(kt_, buf_)                                                  \
  {                                                                          \
    unsigned short* aD = smem + (buf_) * 8192 + wave * 512;                  \
    unsigned short* bD = smem + 16384 + (buf_) * 8192 + wave * 512;          \
    GLL16(aS0 + (kt_), aD);                                                  \
    GLL16(aS1 + (kt_), aD + 4096);                                           \
    GLL16(bS0 + (kt_), bD);                                                  \
    GLL16(bS1 + (kt_), bD + 4096);                                           \
  }

  STAGE256(0, 0);                          // prologue

  const int xr = ((lrow >> 1) & 3) << 3;   // read-side elem XOR
  for (int t = 0; t < nt; ++t) {
    if (t + 1 < nt) {
      STAGE256((t + 1) << 5, (t + 1) & 1); // prefetch next tile
      asm volatile("s_waitcnt vmcnt(4)" ::: "memory");   // tile t landed (mine)
    } else {
      asm volatile("s_waitcnt vmcnt(0)" ::: "memory");   // final drain (once)
    }
    __builtin_amdgcn_s_barrier();          // tile t landed (everyone)
    __builtin_amdgcn_sched_barrier(0);
    const unsigned short* As_ = smem + (t & 1) * 8192;
    const unsigned short* Bs_ = smem + 16384 + (t & 1) * 8192;
    bf16x8 bfv[4];
#pragma unroll
    for (int ni = 0; ni < 4; ++ni)
      bfv[ni] = *reinterpret_cast<const bf16x8*>(
          &Bs_[(wn + ni * 16 + lrow) * 32 + ((kq * 8) ^ xr)]);
#pragma unroll
    for (int mi = 0; mi < 8; ++mi) {
      bf16x8 af = *reinterpret_cast<const bf16x8*>(
          &As_[(wm + mi * 16 + lrow) * 32 + ((kq * 8) ^ xr)]);
#pragma unroll
      for (int ni = 0; ni < 4; ++ni)
        acc[mi][ni] = __builtin_amdgcn_mfma_f32_16x16x32_bf16(af, bfv[ni], acc[mi][ni], 0, 0, 0);
    }
    __builtin_amdgcn_sched_barrier(0);
    if (t + 1 < nt) __builtin_amdgcn_s_barrier();  // reads done: next STAGE may overwrite
  }
#undef STAGE256

  if (tempPtr) alpha = 1.0f / fmaxf(*tempPtr, 0.01f);

  C += (long)blockIdx.z * sC;
#pragma unroll
  for (int mi = 0; mi < 8; ++mi) {
    int rg = tm0 + wm + mi * 16 + kq * 4;
#pragma unroll
    for (int ni = 0; ni < 4; ++ni) {
      int cg = tn0 + wn + ni * 16 + lrow;
      f32x4 v = acc[mi][ni];
#pragma unroll
      for (int r = 0; r < 4; ++r)
        C[(long)(rg + r) * ldc + cg] = f2bf(v[r] * alpha);
    }
  }
}

// ---------------- row softmax, bf16 in-place, cols == 2048 ----------------
__global__ __launch_bounds__(256)
void k_softmax(unsigned short* __restrict__ S, int cols) {
  const long base = (long)blockIdx.x * cols;
  const int tid = threadIdx.x, lane = tid & 63, wave = tid >> 6;
  const int nv = cols >> 3;
  float f[8];
  float mx = -3.0e38f;
  if (tid < nv) {
    uint4 v = *reinterpret_cast<const uint4*>(S + base + tid * 8);
    const unsigned short* pv = (const unsigned short*)&v;
#pragma unroll
    for (int j = 0; j < 8; ++j) { f[j] = bf2f(pv[j]); mx = fmaxf(mx, f[j]); }
  }
  __shared__ float rmax[4], rsum[4];
#pragma unroll
  for (int o = 32; o > 0; o >>= 1) mx = fmaxf(mx, __shfl_down(mx, o));
  if (lane == 0) rmax[wave] = mx;
  __syncthreads();
  mx = fmaxf(fmaxf(rmax[0], rmax[1]), fmaxf(rmax[2], rmax[3]));
  float sum = 0.f;
  if (tid < nv) {
#pragma unroll
    for (int j = 0; j < 8; ++j) { f[j] = __expf(f[j] - mx); sum += f[j]; }
  }
#pragma unroll
  for (int o = 32; o > 0; o >>= 1) sum += __shfl_down(sum, o);
  if (lane == 0) rsum[wave] = sum;
  __syncthreads();
  const float inv = 1.0f / (rsum[0] + rsum[1] + rsum[2] + rsum[3]);
  if (tid < nv) {
    unsigned short o8[8];
#pragma unroll
    for (int j = 0; j < 8; ++j) o8[j] = f2bf(f[j] * inv);
    *reinterpret_cast<uint4*>(S + base + tid * 8) = *reinterpret_cast<const uint4*>(o8);
  }
}

// ---------------- row softmax cols=1024: 2 rows/block, all lanes live -----
__global__ __launch_bounds__(256)
void k_softmax1024(unsigned short* __restrict__ S) {
  const int tid = threadIdx.x;
  const int half = tid >> 7, ht = tid & 127;       // row-pair half, idx in half
  const int lane = tid & 63, wave = tid >> 6;      // waves {0,1}=row0 {2,3}=row1
  const long base = ((long)blockIdx.x * 2 + half) * 1024;
  uint4 v = *reinterpret_cast<const uint4*>(S + base + ht * 8);
  const unsigned short* pv = (const unsigned short*)&v;
  float f[8];
  float mx = -3.0e38f;
#pragma unroll
  for (int j = 0; j < 8; ++j) { f[j] = bf2f(pv[j]); mx = fmaxf(mx, f[j]); }
  __shared__ float rmax[4], rsum[4];
#pragma unroll
  for (int o = 32; o > 0; o >>= 1) mx = fmaxf(mx, __shfl_down(mx, o));
  if (lane == 0) rmax[wave] = mx;
  __syncthreads();
  mx = fmaxf(rmax[half * 2], rmax[half * 2 + 1]);
  float sum = 0.f;
#pragma unroll
  for (int j = 0; j < 8; ++j) { f[j] = __expf(f[j] - mx); sum += f[j]; }
#pragma unroll
  for (int o = 32; o > 0; o >>= 1) sum += __shfl_down(sum, o);
  if (lane == 0) rsum[wave] = sum;
  __syncthreads();
  const float inv = 1.0f / (rsum[half * 2] + rsum[half * 2 + 1]);
  unsigned short o8[8];
#pragma unroll
  for (int j = 0; j < 8; ++j) o8[j] = f2bf(f[j] * inv);
  *reinterpret_cast<uint4*>(S + base + ht * 8) = *reinterpret_cast<const uint4*>(o8);
}

// ---------------- L2-normalize rows of 512 bf16 in-place (wave/row) -------
__global__ __launch_bounds__(256)
void k_l2norm(unsigned short* __restrict__ Q, int ld) {
  const int lane = threadIdx.x & 63, wave = threadIdx.x >> 6;
  const long row = (long)blockIdx.x * 4 + wave;
  unsigned short* p = Q + row * ld + lane * 8;
  uint4 v = *reinterpret_cast<const uint4*>(p);
  const unsigned short* pv = (const unsigned short*)&v;
  float f[8]; float q = 0.f;
#pragma unroll
  for (int j = 0; j < 8; ++j) { f[j] = bf2f(pv[j]); q += f[j] * f[j]; }
#pragma unroll
  for (int o = 32; o > 0; o >>= 1) q += __shfl_xor(q, o);
  float sc = 1.0f / (sqrtf(q) + 1e-8f);
  unsigned short o8[8];
#pragma unroll
  for (int j = 0; j < 8; ++j) o8[j] = f2bf(f[j] * sc);
  *reinterpret_cast<uint4*>(p) = *reinterpret_cast<const uint4*>(o8);
}

// ---------------- LayerNorm rows of 512 bf16 in-place (wave/row) ----------
__global__ __launch_bounds__(256)
void k_ln_bf(unsigned short* __restrict__ X, const float* __restrict__ g,
             const float* __restrict__ b) {
  const int lane = threadIdx.x & 63, wave = threadIdx.x >> 6;
  const long row = (long)blockIdx.x * 4 + wave;
  unsigned short* p = X + row * CDIM + lane * 8;
  uint4 v = *reinterpret_cast<const uint4*>(p);
  const unsigned short* pv = (const unsigned short*)&v;
  float f[8];
  float s = 0.f, q = 0.f;
#pragma unroll
  for (int j = 0; j < 8; ++j) { f[j] = bf2f(pv[j]); s += f[j]; q += f[j] * f[j]; }
#pragma unroll
  for (int o = 32; o > 0; o >>= 1) { s += __shfl_xor(s, o); q += __shfl_xor(q, o); }
  float mu = s * (1.f / 512.f);
  float var = q * (1.f / 512.f) - mu * mu;
  float rs = rsqrtf(var + 1e-5f);
  float gg[8], bb[8];
  *reinterpret_cast<float4*>(&gg[0]) = *reinterpret_cast<const float4*>(g + lane * 8);
  *reinterpret_cast<float4*>(&gg[4]) = *reinterpret_cast<const float4*>(g + lane * 8 + 4);
  *reinterpret_cast<float4*>(&bb[0]) = *reinterpret_cast<const float4*>(b + lane * 8);
  *reinterpret_cast<float4*>(&bb[4]) = *reinterpret_cast<const float4*>(b + lane * 8 + 4);
  unsigned short o8[8];
#pragma unroll
  for (int j = 0; j < 8; ++j) o8[j] = f2bf((f[j] - mu) * rs * gg[j] + bb[j]);
  *reinterpret_cast<uint4*>(p) = *reinterpret_cast<const uint4*>(o8);
}

// ---------------- gating fusion (bf16 inputs): one wave per position ------
__global__ __launch_bounds__(256)
void k_gate(const unsigned short* __restrict__ o0, const unsigned short* __restrict__ o1,
            const unsigned short* __restrict__ o2, const float* __restrict__ gw,
            const float* __restrict__ gb, float* __restrict__ out) {
  __shared__ float gws[3 * 1536];
  for (int i = threadIdx.x; i < 3 * 1536; i += 256) gws[i] = gw[i];
  __syncthreads();
  const int lane = threadIdx.x & 63, wave = threadIdx.x >> 6;
  const long pos = (long)blockIdx.x * 4 + wave;
  const long off = pos * CDIM + lane * 8;
  float a[8], bq[8], cq[8];
  {
    uint4 va = *reinterpret_cast<const uint4*>(o0 + off);
    uint4 vb = *reinterpret_cast<const uint4*>(o1 + off);
    uint4 vc = *reinterpret_cast<const uint4*>(o2 + off);
    const unsigned short* pa = (const unsigned short*)&va;
    const unsigned short* pb = (const unsigned short*)&vb;
    const unsigned short* pc = (const unsigned short*)&vc;
#pragma unroll
    for (int j = 0; j < 8; ++j) { a[j] = bf2f(pa[j]); bq[j] = bf2f(pb[j]); cq[j] = bf2f(pc[j]); }
  }
  float l0 = 0.f, l1 = 0.f, l2 = 0.f;
  const int ch = lane * 8;
#pragma unroll
  for (int j = 0; j < 8; ++j) {
    l0 += a[j] * gws[ch + j] + bq[j] * gws[512 + ch + j] + cq[j] * gws[1024 + ch + j];
    l1 += a[j] * gws[1536 + ch + j] + bq[j] * gws[2048 + ch + j] + cq[j] * gws[2560 + ch + j];
    l2 += a[j] * gws[3072 + ch + j] + bq[j] * gws[3584 + ch + j] + cq[j] * gws[4096 + ch + j];
  }
#pragma unroll
  for (int o = 32; o > 0; o >>= 1) {
    l0 += __shfl_xor(l0, o); l1 += __shfl_xor(l1, o); l2 += __shfl_xor(l2, o);
  }
  l0 += gb[0]; l1 += gb[1]; l2 += gb[2];
  float m = fmaxf(l0, fmaxf(l1, l2));
  float e0 = __expf(l0 - m), e1 = __expf(l1 - m), e2 = __expf(l2 - m);
  float inv = 1.f / (e0 + e1 + e2);
  float g0 = e0 * inv, g1 = e1 * inv, g2 = e2 * inv;
  float r[8];
#pragma unroll
  for (int j = 0; j < 8; ++j) r[j] = g0 * a[j] + g1 * bq[j] + g2 * cq[j];
  *reinterpret_cast<float4*>(out + off) = *reinterpret_cast<const float4*>(&r[0]);
  *reinterpret_cast<float4*>(out + off + 4) = *reinterpret_cast<const float4*>(&r[4]);
}

// ===========================================================================
extern "C" void kernel_launch(void* const* d_in, const int* in_sizes, int n_in,
                              void* d_out, int out_size, void* d_ws, size_t ws_size,
                              hipStream_t stream) {
  (void)in_sizes; (void)n_in; (void)out_size;
  const float* x = (const float*)d_in[0];
  const float* dw = (const float*)d_in[1];
  const float* db = (const float*)d_in[2];
  // WB order: 0 wq_cr, 1 wq_d, 2 wk_d, 3 wq_c, 4 wk_c, 5 wv_d, 6 wv_c,
  //           7 wk_cr, 8 wv_cr
  WPtrs wp;
  wp.p[0] = (const float*)d_in[3];   // wq_cr
  wp.p[1] = (const float*)d_in[11];  // wq_d
  wp.p[2] = (const float*)d_in[13];  // wk_d
  wp.p[3] = (const float*)d_in[19];  // wq_c
  wp.p[4] = (const float*)d_in[21];  // wk_c
  wp.p[5] = (const float*)d_in[15];  // wv_d
  wp.p[6] = (const float*)d_in[23];  // wv_c
  wp.p[7] = (const float*)d_in[5];   // wk_cr
  wp.p[8] = (const float*)d_in[7];   // wv_cr
  const float* bq_cr = (const float*)d_in[4];
  const float* bk_cr = (const float*)d_in[6];
  const float* bv_cr = (const float*)d_in[8];
  const float* ln_cr_g = (const float*)d_in[9];
  const float* ln_cr_b = (const float*)d_in[10];
  const float* bq_d = (const float*)d_in[12];
  const float* bk_d = (const float*)d_in[14];
  const float* bv_d = (const float*)d_in[16];
  const float* ln_d_g = (const float*)d_in[17];
  const float* ln_d_b = (const float*)d_in[18];
  const float* bq_c = (const float*)d_in[20];
  const float* bk_c = (const float*)d_in[22];
  const float* bv_c = (const float*)d_in[24];
  const float* ln_c_g = (const float*)d_in[25];
  const float* ln_c_b = (const float*)d_in[26];
  const float* temp = (const float*)d_in[27];
  const float* gw = (const float*)d_in[28];
  const float* gb = (const float*)d_in[29];

  if (ws_size < 240000000ULL) return;  // plan needs ~226 MiB

  char* p = (char*)d_ws;
  auto alloc = [&](size_t bytes) {
    void* r = (void*)p;
    p += (bytes + 255) & ~(size_t)255;
    return r;
  };
  alloc(1024);                                                     // front pad
  unsigned short* XB  = (unsigned short*)alloc(16384L * 512 * 2);
  unsigned short* XD  = (unsigned short*)alloc(8192L * 512 * 2);
  unsigned short* WB  = (unsigned short*)alloc(9L * 262144 * 2);
  unsigned short* DWB = (unsigned short*)alloc(512L * 1536 * 2);
  unsigned short* QB  = (unsigned short*)alloc(16384L * 512 * 2);   // q_cr
  unsigned short* KB  = (unsigned short*)alloc(8192L * 512 * 2);    // k_cr
  unsigned short* VT  = (unsigned short*)alloc(512L * 16384 * 2);   // V^T, reused
  unsigned short* OUT0 = (unsigned short*)alloc(16384L * 512 * 2);
  unsigned short* OUT1 = (unsigned short*)alloc(16384L * 512 * 2);
  unsigned short* OUT2 = (unsigned short*)alloc(16384L * 512 * 2);
  unsigned short* QK2 = (unsigned short*)alloc(16384L * 1024 * 2);  // per-branch Q|K
  float* BC = (float*)alloc(2048 * 4);                              // bias concat
  unsigned short* SB = (unsigned short*)alloc(8L * 2048 * 2048 * 2);

  const float scale = 0.044194173824159216f;  // 1/sqrt(512)

  auto gemm64 = [&](const unsigned short* A, const unsigned short* Bm, void* Cm,
                    int M, int N, int K, int lda, int ldb, int ldc,
                    int batch, long sA, long sB, long sC,
                    const float* bias, float alpha, int mode) {
    dim3 g(M / 128, N / 64, batch);
    k_gemm64<<<g, 256, 0, stream>>>(A, Bm, Cm, K, lda, ldb, ldc, sA, sB, sC,
                                    bias, alpha, mode);
  };
  auto gemm256 = [&](const unsigned short* A, const unsigned short* Bm,
                     unsigned short* Cm, int M, int N, int K,
                     int lda, int ldb, int ldc, int batch,
                     long sA, long sB, long sC, float alpha, const float* tp) {
    dim3 g(M / 256, N / 256, batch);
    k_gemm256<<<g, 512, 0, stream>>>(A, Bm, Cm, K, lda, ldb, ldc, sA, sB, sC, alpha, tp);
  };

  // ---- conversions & bias concats ----
  k_tobf16<<<8192, 256, 0, stream>>>(x, XB, 16384L * 512 / 4);
  k_tobf16w<<<2304, 256, 0, stream>>>(wp, WB);
  k_dwreorder<<<3072, 256, 0, stream>>>(dw, DWB);
  hipMemcpyAsync(BC,        bq_d, 512 * 4, hipMemcpyDeviceToDevice, stream);
  hipMemcpyAsync(BC + 512,  bk_d, 512 * 4, hipMemcpyDeviceToDevice, stream);
  hipMemcpyAsync(BC + 1024, bq_c, 512 * 4, hipMemcpyDeviceToDevice, stream);
  hipMemcpyAsync(BC + 1536, bk_c, 512 * 4, hipMemcpyDeviceToDevice, stream);

  // ---- downsample conv: strided-A GEMM (row t = x[b][2t-1..2t+1], contig) --
  gemm64(XB - 512, DWB, XD, 1024, 512, 1536, 1024, 1536, 512,
         8, 1048576L, 0, 524288L, db, 1.f, 1);
  k_fix<<<1024, 256, 0, stream>>>(XB, DWB, db, XD);   // exact t=0 rows

  // ================= branch cr (q from x, k/v from x_down) =================
  gemm64(XB, WB + 0 * 262144L, QB, 16384, 512, 512, 512, 512, 512, 1, 0, 0, 0,
         bq_cr, 1.f, 1);
  gemm64(XD, WB + 7 * 262144L, KB, 8192, 512, 512, 512, 512, 512, 1, 0, 0, 0,
         bk_cr, 1.f, 1);
  // V^T = W_v_cr * XD^T : [512][8192], per-batch view VT + b*1024, ldb 8192
  gemm64(WB + 8 * 262144L, XD, VT, 512, 8192, 512, 512, 512, 8192, 1, 0, 0, 0,
         bv_cr, 1.f, 3);
  gemm256(QB, KB, SB, 2048, 1024, 512, 512, 512, 1024, 8,
          2048L * 512, 1024L * 512, 2048L * 1024, scale, nullptr);
  k_softmax1024<<<8192, 256, 0, stream>>>(SB);
  gemm64(SB, VT, OUT0, 2048, 512, 1024, 1024, 8192, 512, 8,
         2048L * 1024, 1024, 2048L * 512, nullptr, 1.f, 1);
  k_ln_bf<<<4096, 256, 0, stream>>>(OUT0, ln_cr_g, ln_cr_b);

  // ================= branch d (standard attention over x) ==================
  gemm64(XB, WB + 1 * 262144L, QK2, 16384, 1024, 512, 512, 512, 1024, 1, 0, 0, 0,
         BC, 1.f, 1);                                // fused Q|K projection
  // V^T = W_v_d * XB^T : [512][16384], per-batch view VT + b*2048, ldb 16384
  gemm64(WB + 5 * 262144L, XB, VT, 512, 16384, 512, 512, 512, 16384, 1, 0, 0, 0,
         bv_d, 1.f, 3);
  gemm256(QK2, QK2 + 512, SB, 2048, 2048, 512, 1024, 1024, 2048, 8,
          2048L * 1024, 2048L * 1024, 2048L * 2048, scale, nullptr);
  k_softmax<<<16384, 256, 0, stream>>>(SB, 2048);
  gemm64(SB, VT, OUT1, 2048, 512, 2048, 2048, 16384, 512, 8,
         2048L * 2048, 2048, 2048L * 512, nullptr, 1.f, 1);
  k_ln_bf<<<4096, 256, 0, stream>>>(OUT1, ln_d_g, ln_d_b);

  // ================= branch c (cosine attention, learnable temp) ===========
  gemm64(XB, WB + 3 * 262144L, QK2, 16384, 1024, 512, 512, 512, 1024, 1, 0, 0, 0,
         BC + 1024, 1.f, 1);                         // fused Q|K projection
  k_l2norm<<<4096, 256, 0, stream>>>(QK2, 1024);
  k_l2norm<<<4096, 256, 0, stream>>>(QK2 + 512, 1024);
  gemm64(WB + 6 * 262144L, XB, VT, 512, 16384, 512, 512, 512, 16384, 1, 0, 0, 0,
         bv_c, 1.f, 3);
  gemm256(QK2, QK2 + 512, SB, 2048, 2048, 512, 1024, 1024, 2048, 8,
          2048L * 1024, 2048L * 1024, 2048L * 2048, 1.f, temp);
  k_softmax<<<16384, 256, 0, stream>>>(SB, 2048);
  gemm64(SB, VT, OUT2, 2048, 512, 2048, 2048, 16384, 512, 8,
         2048L * 2048, 2048, 2048L * 512, nullptr, 1.f, 1);
  k_ln_bf<<<4096, 256, 0, stream>>>(OUT2, ln_c_g, ln_c_b);

  // ================= gated fusion -> d_out ================================
  k_gate<<<4096, 256, 0, stream>>>(OUT0, OUT1, OUT2, gw, gb, (float*)d_out);
}

// Round 12
// 546.292 us; speedup vs baseline: 1.2157x; 1.2157x over previous
//
#include <hip/hip_runtime.h>

// ---------------------------------------------------------------------------
// Hybrid MRHA: conv-downsample + 3 attention branches + LN + gated fusion.
// k_gemm    : 128x128, BK=64, XOR-swizzled LDS, counted-vmcnt 2-barrier loop.
//             Conv, Q|K projections, PV.  (BN=64 regressed PV: 2x A-fetch.)
// k_gemm64  : 128x64 variant — ONLY for V^T projections (M=512: A is
//             L2-resident weights, so BN=64 is traffic-neutral, 2x blocks).
// k_gemm256 : 256x256, BK=32, scores only. Direct write-exact epilogue.
// ---------------------------------------------------------------------------

typedef __attribute__((ext_vector_type(8))) __bf16 bf16x8;
typedef __attribute__((ext_vector_type(4))) float f32x4;

#define CDIM 512
#define TFULL 2048

#define GLL16(gp, lp)                                                        \
  __builtin_amdgcn_global_load_lds(                                          \
      (const __attribute__((address_space(1))) unsigned int*)(gp),           \
      (__attribute__((address_space(3))) unsigned int*)(lp), 16, 0, 0)

__device__ __forceinline__ unsigned short f2bf(float f) {
  unsigned u = __float_as_uint(f);
  u = (u + 0x7fffu + ((u >> 16) & 1u)) >> 16;   // round-to-nearest-even
  return (unsigned short)u;
}
__device__ __forceinline__ float bf2f(unsigned short h) {
  return __uint_as_float(((unsigned)h) << 16);
}

// ---------------- conversion: f32 -> bf16 (vec4) ----------------
__global__ __launch_bounds__(256)
void k_tobf16(const float* __restrict__ src, unsigned short* __restrict__ dst, long n4) {
  long i = (long)blockIdx.x * 256 + threadIdx.x;
  if (i >= n4) return;
  float4 f = reinterpret_cast<const float4*>(src)[i];
  unsigned short o4[4] = {f2bf(f.x), f2bf(f.y), f2bf(f.z), f2bf(f.w)};
  reinterpret_cast<uint2*>(dst)[i] = *reinterpret_cast<const uint2*>(o4);
}

// ---------------- batched weight conversion: 9 x 512x512 -> WB ----------
struct WPtrs { const float* p[9]; };
__global__ __launch_bounds__(256)
void k_tobf16w(WPtrs w, unsigned short* __restrict__ dst) {
  int idx = blockIdx.x * 256 + threadIdx.x;       // over 9*65536 vec4 units
  if (idx >= 9 * 65536) return;
  int m = idx >> 16, off = idx & 65535;
  float4 f = reinterpret_cast<const float4*>(w.p[m])[off];
  unsigned short o4[4] = {f2bf(f.x), f2bf(f.y), f2bf(f.z), f2bf(f.w)};
  reinterpret_cast<uint2*>(dst + (long)m * 262144)[off] = *reinterpret_cast<const uint2*>(o4);
}

// ---------------- dw [o][i][k] -> DWB bf16 [o][k*512+i] ----------------
__global__ __launch_bounds__(256)
void k_dwreorder(const float* __restrict__ dw, unsigned short* __restrict__ dwb) {
  int idx = blockIdx.x * 256 + threadIdx.x;           // over 512*1536
  if (idx >= 512 * 1536) return;
  int o = idx / 1536, rem = idx - o * 1536;
  int k = rem >> 9, i = rem & 511;
  dwb[idx] = f2bf(dw[(o * 512 + i) * 3 + k]);
}

// ---------------- conv row-0 fixup: one wave per (b,o), coalesced ---------
__global__ __launch_bounds__(256)
void k_fix(const unsigned short* __restrict__ XB, const unsigned short* __restrict__ DWB,
           const float* __restrict__ db, unsigned short* __restrict__ XD) {
  const int lane = threadIdx.x & 63, wave = threadIdx.x >> 6;
  const int idx = blockIdx.x * 4 + wave;      // 4096 = 8 batches * 512 outputs
  const int b = idx >> 9, o = idx & 511;
  const unsigned short* xr = XB + (long)b * TFULL * CDIM + lane * 16;  // rows 0,1
  const unsigned short* wr = DWB + (long)o * 1536 + 512 + lane * 16;   // taps 1,2
  float acc = 0.f;
  uint4 xv0 = *reinterpret_cast<const uint4*>(xr);
  uint4 xv1 = *reinterpret_cast<const uint4*>(xr + 8);
  uint4 wv0 = *reinterpret_cast<const uint4*>(wr);
  uint4 wv1 = *reinterpret_cast<const uint4*>(wr + 8);
  const unsigned short* xp0 = (const unsigned short*)&xv0;
  const unsigned short* xp1 = (const unsigned short*)&xv1;
  const unsigned short* wp0 = (const unsigned short*)&wv0;
  const unsigned short* wp1 = (const unsigned short*)&wv1;
#pragma unroll
  for (int j = 0; j < 8; ++j) acc += bf2f(xp0[j]) * bf2f(wp0[j]);
#pragma unroll
  for (int j = 0; j < 8; ++j) acc += bf2f(xp1[j]) * bf2f(wp1[j]);
#pragma unroll
  for (int off = 32; off > 0; off >>= 1) acc += __shfl_xor(acc, off);
  if (lane == 0) XD[(long)b * 1024 * 512 + o] = f2bf(acc + db[o]);
}

// ---------------- GEMM 128x128: C = alpha * A * B^T + bias ----------------
// mode 1: bf16 store, bias[col] | mode 3: bf16 store, bias[row]
// counted-vmcnt 2-barrier pipeline.
// Requires: M%128==0, N%128==0, K%64==0, (M/128)*(N/128)%8==0.
__global__ __launch_bounds__(256)
void k_gemm(const unsigned short* __restrict__ A,
            const unsigned short* __restrict__ B,
            void* __restrict__ Cp,
            int K, int lda, int ldb, int ldc,
            long sA, long sB, long sC,
            const float* __restrict__ bias,
            float alpha, int mode) {
  const int gx = gridDim.x;
  const int nwg = gx * gridDim.y;
  int wg = blockIdx.x + gx * blockIdx.y;
  wg = (wg & 7) * (nwg >> 3) + (wg >> 3);
  const int tm0 = (wg % gx) * 128, tn0 = (wg / gx) * 128;
  const int bz = blockIdx.z;
  const unsigned short* Ag = A + (long)bz * sA;
  const unsigned short* Bg = B + (long)bz * sB;

  __shared__ __align__(16) unsigned short smem[32768];

  const int tid = threadIdx.x;
  const int lane = tid & 63;
  const int wave = tid >> 6;
  const int wm = (wave >> 1) * 64, wn = (wave & 1) * 64;
  const int lrow = lane & 15, kq = lane >> 4;

  f32x4 acc[4][4];
#pragma unroll
  for (int i = 0; i < 4; ++i)
#pragma unroll
    for (int j = 0; j < 4; ++j) acc[i][j] = f32x4{0.f, 0.f, 0.f, 0.f};

  const int sr = tid >> 3;                 // 0..31
  const int sj = (tid & 7) ^ (sr & 7);     // inverse-swizzled source slot
  const unsigned short* aSrc = Ag + (long)(tm0 + sr) * lda + sj * 8;
  const unsigned short* bSrc = Bg + (long)(tn0 + sr) * ldb + sj * 8;

  const int nt = K >> 6;

#define STAGE(kt_, buf_)                                                     \
  {                                                                          \
    unsigned short* aD = smem + (buf_) * 8192 + wave * 512;                  \
    unsigned short* bD = smem + 16384 + (buf_) * 8192 + wave * 512;          \
    _Pragma("unroll")                                                        \
    for (int rd = 0; rd < 4; ++rd) {                                         \
      GLL16(aSrc + (kt_) + (long)rd * 32 * lda, aD + rd * 2048);             \
      GLL16(bSrc + (kt_) + (long)rd * 32 * ldb, bD + rd * 2048);             \
    }                                                                        \
  }

  STAGE(0, 0);

  const int xr = (lrow & 7) << 3;
  for (int t = 0; t < nt; ++t) {
    if (t + 1 < nt) {
      STAGE((t + 1) << 6, (t + 1) & 1);    // prefetch stays in flight
      asm volatile("s_waitcnt vmcnt(8)" ::: "memory");   // my tile-t loads done
    } else {
      asm volatile("s_waitcnt vmcnt(0)" ::: "memory");   // final drain (once)
    }
    __builtin_amdgcn_s_barrier();          // everyone's tile-t loads done
    __builtin_amdgcn_sched_barrier(0);
    const unsigned short* As_ = smem + (t & 1) * 8192;
    const unsigned short* Bs_ = smem + 16384 + (t & 1) * 8192;
    bf16x8 af[4][2], bfv[4][2];
#pragma unroll
    for (int mi = 0; mi < 4; ++mi)
#pragma unroll
      for (int ks = 0; ks < 2; ++ks)
        af[mi][ks] = *reinterpret_cast<const bf16x8*>(
            &As_[(wm + mi * 16 + lrow) * 64 + ((ks * 32 + kq * 8) ^ xr)]);
#pragma unroll
    for (int ni = 0; ni < 4; ++ni)
#pragma unroll
      for (int ks = 0; ks < 2; ++ks)
        bfv[ni][ks] = *reinterpret_cast<const bf16x8*>(
            &Bs_[(wn + ni * 16 + lrow) * 64 + ((ks * 32 + kq * 8) ^ xr)]);
#pragma unroll
    for (int mi = 0; mi < 4; ++mi)
#pragma unroll
      for (int ni = 0; ni < 4; ++ni) {
        acc[mi][ni] = __builtin_amdgcn_mfma_f32_16x16x32_bf16(af[mi][0], bfv[ni][0], acc[mi][ni], 0, 0, 0);
        acc[mi][ni] = __builtin_amdgcn_mfma_f32_16x16x32_bf16(af[mi][1], bfv[ni][1], acc[mi][ni], 0, 0, 0);
      }
    __builtin_amdgcn_sched_barrier(0);
    if (t + 1 < nt) __builtin_amdgcn_s_barrier();  // reads done: next STAGE may overwrite
  }
#undef STAGE

  unsigned short* Cb = (unsigned short*)Cp + (long)bz * sC;
  if (mode == 1) {
#pragma unroll
    for (int mi = 0; mi < 4; ++mi) {
      int rg = tm0 + wm + mi * 16 + kq * 4;
#pragma unroll
      for (int ni = 0; ni < 4; ++ni) {
        int cg = tn0 + wn + ni * 16 + lrow;
        float bb = bias ? bias[cg] : 0.f;
        f32x4 v = acc[mi][ni];
#pragma unroll
        for (int r = 0; r < 4; ++r)
          Cb[(long)(rg + r) * ldc + cg] = f2bf(v[r] * alpha + bb);
      }
    }
  } else {                                 // mode 3: bias indexed by row
#pragma unroll
    for (int mi = 0; mi < 4; ++mi) {
      int rg = tm0 + wm + mi * 16 + kq * 4;
      float rb[4];
#pragma unroll
      for (int r = 0; r < 4; ++r) rb[r] = bias[rg + r];
#pragma unroll
      for (int ni = 0; ni < 4; ++ni) {
        int cg = tn0 + wn + ni * 16 + lrow;
        f32x4 v = acc[mi][ni];
#pragma unroll
        for (int r = 0; r < 4; ++r)
          Cb[(long)(rg + r) * ldc + cg] = f2bf(v[r] * alpha + rb[r]);
      }
    }
  }
}

// ---------------- GEMM 128x64 (V^T projections only) ----------------------
// mode 3 bias[row]. A (weights) is L2-resident so BN=64 is traffic-neutral.
// Requires: M%128==0, N%64==0, K%64==0, (M/128)*(N/64)%8==0.
__global__ __launch_bounds__(256)
void k_gemm64(const unsigned short* __restrict__ A,
              const unsigned short* __restrict__ B,
              void* __restrict__ Cp,
              int K, int lda, int ldb, int ldc,
              long sA, long sB, long sC,
              const float* __restrict__ bias,
              float alpha, int mode) {
  const int gx = gridDim.x;
  const int nwg = gx * gridDim.y;
  int wg = blockIdx.x + gx * blockIdx.y;
  wg = (wg & 7) * (nwg >> 3) + (wg >> 3);
  const int tm0 = (wg % gx) * 128, tn0 = (wg / gx) * 64;
  const int bz = blockIdx.z;
  const unsigned short* Ag = A + (long)bz * sA;
  const unsigned short* Bg = B + (long)bz * sB;

  __shared__ __align__(16) unsigned short smem[24576];

  const int tid = threadIdx.x;
  const int lane = tid & 63;
  const int wave = tid >> 6;
  const int wm = (wave >> 1) * 64, wn = (wave & 1) * 32;
  const int lrow = lane & 15, kq = lane >> 4;

  f32x4 acc[4][2];
#pragma unroll
  for (int i = 0; i < 4; ++i)
#pragma unroll
    for (int j = 0; j < 2; ++j) acc[i][j] = f32x4{0.f, 0.f, 0.f, 0.f};

  const int sr = tid >> 3;                 // 0..31
  const int sj = (tid & 7) ^ (sr & 7);     // inverse-swizzled source slot
  const unsigned short* aSrc = Ag + (long)(tm0 + sr) * lda + sj * 8;
  const unsigned short* bSrc = Bg + (long)(tn0 + sr) * ldb + sj * 8;

  const int nt = K >> 6;

#define STAGE64(kt_, buf_)                                                   \
  {                                                                          \
    unsigned short* aD = smem + (buf_) * 8192 + wave * 512;                  \
    unsigned short* bD = smem + 16384 + (buf_) * 4096 + wave * 512;          \
    _Pragma("unroll")                                                        \
    for (int rd = 0; rd < 4; ++rd)                                           \
      GLL16(aSrc + (kt_) + (long)rd * 32 * lda, aD + rd * 2048);             \
    _Pragma("unroll")                                                        \
    for (int rd = 0; rd < 2; ++rd)                                           \
      GLL16(bSrc + (kt_) + (long)rd * 32 * ldb, bD + rd * 2048);             \
  }

  STAGE64(0, 0);

  const int xr = (lrow & 7) << 3;
  for (int t = 0; t < nt; ++t) {
    if (t + 1 < nt) {
      STAGE64((t + 1) << 6, (t + 1) & 1);
      asm volatile("s_waitcnt vmcnt(6)" ::: "memory");
    } else {
      asm volatile("s_waitcnt vmcnt(0)" ::: "memory");
    }
    __builtin_amdgcn_s_barrier();
    __builtin_amdgcn_sched_barrier(0);
    const unsigned short* As_ = smem + (t & 1) * 8192;
    const unsigned short* Bs_ = smem + 16384 + (t & 1) * 4096;
    bf16x8 af[4][2], bfv[2][2];
#pragma unroll
    for (int mi = 0; mi < 4; ++mi)
#pragma unroll
      for (int ks = 0; ks < 2; ++ks)
        af[mi][ks] = *reinterpret_cast<const bf16x8*>(
            &As_[(wm + mi * 16 + lrow) * 64 + ((ks * 32 + kq * 8) ^ xr)]);
#pragma unroll
    for (int ni = 0; ni < 2; ++ni)
#pragma unroll
      for (int ks = 0; ks < 2; ++ks)
        bfv[ni][ks] = *reinterpret_cast<const bf16x8*>(
            &Bs_[(wn + ni * 16 + lrow) * 64 + ((ks * 32 + kq * 8) ^ xr)]);
#pragma unroll
    for (int mi = 0; mi < 4; ++mi)
#pragma unroll
      for (int ni = 0; ni < 2; ++ni) {
        acc[mi][ni] = __builtin_amdgcn_mfma_f32_16x16x32_bf16(af[mi][0], bfv[ni][0], acc[mi][ni], 0, 0, 0);
        acc[mi][ni] = __builtin_amdgcn_mfma_f32_16x16x32_bf16(af[mi][1], bfv[ni][1], acc[mi][ni], 0, 0, 0);
      }
    __builtin_amdgcn_sched_barrier(0);
    if (t + 1 < nt) __builtin_amdgcn_s_barrier();
  }
#undef STAGE64

  unsigned short* Cb = (unsigned short*)Cp + (long)bz * sC;
  if (mode == 1) {
#pragma unroll
    for (int mi = 0; mi < 4; ++mi) {
      int rg = tm0 + wm + mi * 16 + kq * 4;
#pragma unroll
      for (int ni = 0; ni < 2; ++ni) {
        int cg = tn0 + wn + ni * 16 + lrow;
        float bb = bias ? bias[cg] : 0.f;
        f32x4 v = acc[mi][ni];
#pragma unroll
        for (int r = 0; r < 4; ++r)
          Cb[(long)(rg + r) * ldc + cg] = f2bf(v[r] * alpha + bb);
      }
    }
  } else {                                 // mode 3: bias indexed by row
#pragma unroll
    for (int mi = 0; mi < 4; ++mi) {
      int rg = tm0 + wm + mi * 16 + kq * 4;
      float rb[4];
#pragma unroll
      for (int r = 0; r < 4; ++r) rb[r] = bias[rg + r];
#pragma unroll
      for (int ni = 0; ni < 2; ++ni) {
        int cg = tn0 + wn + ni * 16 + lrow;
        f32x4 v = acc[mi][ni];
#pragma unroll
        for (int r = 0; r < 4; ++r)
          Cb[(long)(rg + r) * ldc + cg] = f2bf(v[r] * alpha + rb[r]);
      }
    }
  }
}

// ---------------- GEMM 256x256 (scores): C = alpha * A * B^T --------------
// BK=32 dbuf, counted vmcnt(4) + 2 raw barriers per K-tile.
// Requires M%256==0, N%256==0, K%32==0, (M/256)*(N/256)%8==0.
__global__ __launch_bounds__(512)
void k_gemm256(const unsigned short* __restrict__ A,
               const unsigned short* __restrict__ B,
               unsigned short* __restrict__ C,
               int K, int lda, int ldb, int ldc,
               long sA, long sB, long sC,
               float alpha, const float* __restrict__ tempPtr) {
  const int gx = gridDim.x;
  const int nwg = gx * gridDim.y;
  int wg = blockIdx.x + gx * blockIdx.y;
  wg = (wg & 7) * (nwg >> 3) + (wg >> 3);
  const int tm0 = (wg % gx) * 256, tn0 = (wg / gx) * 256;
  const unsigned short* Ag = A + (long)blockIdx.z * sA;
  const unsigned short* Bg = B + (long)blockIdx.z * sB;

  __shared__ __align__(16) unsigned short smem[32768];

  const int tid = threadIdx.x;
  const int lane = tid & 63;
  const int wave = tid >> 6;               // 0..7
  const int wm = (wave >> 2) * 128, wn = (wave & 3) * 64;
  const int lrow = lane & 15, kq = lane >> 4;

  f32x4 acc[8][4];
#pragma unroll
  for (int i = 0; i < 8; ++i)
#pragma unroll
    for (int j = 0; j < 4; ++j) acc[i][j] = f32x4{0.f, 0.f, 0.f, 0.f};

  const int srow = lane >> 2;                          // 0..15
  const int sslot = (lane & 3) ^ ((lane >> 3) & 3);    // inverse swizzle
  const unsigned short* aS0 = Ag + (long)(tm0 + wave * 16 + srow) * lda + sslot * 8;
  const unsigned short* aS1 = aS0 + 128L * lda;
  const unsigned short* bS0 = Bg + (long)(tn0 + wave * 16 + srow) * ldb + sslot * 8;
  const unsigned short* bS1 = bS0 + 128L * ldb;

  const int nt = K >> 5;

#define STAGE256(kt_, buf_)                                                  \
  {                                                                          \
    unsigned short* aD = smem + (buf_) * 8192 + wave * 512;                  \
    unsigned short* bD = smem + 16384 + (buf_) * 8192 + wave * 512;          \
    GLL16(aS0 + (kt_), aD);                                                  \
    GLL16(aS1 + (kt_), aD + 4096);                                           \
    GLL16(bS0 + (kt_), bD);                                                  \
    GLL16(bS1 + (kt_), bD + 4096);                                           \
  }

  STAGE256(0, 0);                          // prologue

  const int xr = ((lrow >> 1) & 3) << 3;   // read-side elem XOR
  for (int t = 0; t < nt; ++t) {
    if (t + 1 < nt) {
      STAGE256((t + 1) << 5, (t + 1) & 1); // prefetch next tile
      asm volatile("s_waitcnt vmcnt(4)" ::: "memory");   // tile t landed (mine)
    } else {
      asm volatile("s_waitcnt vmcnt(0)" ::: "memory");   // final drain (once)
    }
    __builtin_amdgcn_s_barrier();          // tile t landed (everyone)
    __builtin_amdgcn_sched_barrier(0);
    const unsigned short* As_ = smem + (t & 1) * 8192;
    const unsigned short* Bs_ = smem + 16384 + (t & 1) * 8192;
    bf16x8 bfv[4];
#pragma unroll
    for (int ni = 0; ni < 4; ++ni)
      bfv[ni] = *reinterpret_cast<const bf16x8*>(
          &Bs_[(wn + ni * 16 + lrow) * 32 + ((kq * 8) ^ xr)]);
#pragma unroll
    for (int mi = 0; mi < 8; ++mi) {
      bf16x8 af = *reinterpret_cast<const bf16x8*>(
          &As_[(wm + mi * 16 + lrow) * 32 + ((kq * 8) ^ xr)]);
#pragma unroll
      for (int ni = 0; ni < 4; ++ni)
        acc[mi][ni] = __builtin_amdgcn_mfma_f32_16x16x32_bf16(af, bfv[ni], acc[mi][ni], 0, 0, 0);
    }
    __builtin_amdgcn_sched_barrier(0);
    if (t + 1 < nt) __builtin_amdgcn_s_barrier();  // reads done: next STAGE may overwrite
  }
#undef STAGE256

  if (tempPtr) alpha = 1.0f / fmaxf(*tempPtr, 0.01f);

  C += (long)blockIdx.z * sC;
#pragma unroll
  for (int mi = 0; mi < 8; ++mi) {
    int rg = tm0 + wm + mi * 16 + kq * 4;
#pragma unroll
    for (int ni = 0; ni < 4; ++ni) {
      int cg = tn0 + wn + ni * 16 + lrow;
      f32x4 v = acc[mi][ni];
#pragma unroll
      for (int r = 0; r < 4; ++r)
        C[(long)(rg + r) * ldc + cg] = f2bf(v[r] * alpha);
    }
  }
}

// ---------------- row softmax, bf16 in-place, cols == 2048 ----------------
__global__ __launch_bounds__(256)
void k_softmax(unsigned short* __restrict__ S, int cols) {
  const long base = (long)blockIdx.x * cols;
  const int tid = threadIdx.x, lane = tid & 63, wave = tid >> 6;
  const int nv = cols >> 3;
  float f[8];
  float mx = -3.0e38f;
  if (tid < nv) {
    uint4 v = *reinterpret_cast<const uint4*>(S + base + tid * 8);
    const unsigned short* pv = (const unsigned short*)&v;
#pragma unroll
    for (int j = 0; j < 8; ++j) { f[j] = bf2f(pv[j]); mx = fmaxf(mx, f[j]); }
  }
  __shared__ float rmax[4], rsum[4];
#pragma unroll
  for (int o = 32; o > 0; o >>= 1) mx = fmaxf(mx, __shfl_down(mx, o));
  if (lane == 0) rmax[wave] = mx;
  __syncthreads();
  mx = fmaxf(fmaxf(rmax[0], rmax[1]), fmaxf(rmax[2], rmax[3]));
  float sum = 0.f;
  if (tid < nv) {
#pragma unroll
    for (int j = 0; j < 8; ++j) { f[j] = __expf(f[j] - mx); sum += f[j]; }
  }
#pragma unroll
  for (int o = 32; o > 0; o >>= 1) sum += __shfl_down(sum, o);
  if (lane == 0) rsum[wave] = sum;
  __syncthreads();
  const float inv = 1.0f / (rsum[0] + rsum[1] + rsum[2] + rsum[3]);
  if (tid < nv) {
    unsigned short o8[8];
#pragma unroll
    for (int j = 0; j < 8; ++j) o8[j] = f2bf(f[j] * inv);
    *reinterpret_cast<uint4*>(S + base + tid * 8) = *reinterpret_cast<const uint4*>(o8);
  }
}

// ---------------- row softmax cols=1024: 2 rows/block, all lanes live -----
__global__ __launch_bounds__(256)
void k_softmax1024(unsigned short* __restrict__ S) {
  const int tid = threadIdx.x;
  const int half = tid >> 7, ht = tid & 127;       // row-pair half, idx in half
  const int lane = tid & 63, wave = tid >> 6;      // waves {0,1}=row0 {2,3}=row1
  const long base = ((long)blockIdx.x * 2 + half) * 1024;
  uint4 v = *reinterpret_cast<const uint4*>(S + base + ht * 8);
  const unsigned short* pv = (const unsigned short*)&v;
  float f[8];
  float mx = -3.0e38f;
#pragma unroll
  for (int j = 0; j < 8; ++j) { f[j] = bf2f(pv[j]); mx = fmaxf(mx, f[j]); }
  __shared__ float rmax[4], rsum[4];
#pragma unroll
  for (int o = 32; o > 0; o >>= 1) mx = fmaxf(mx, __shfl_down(mx, o));
  if (lane == 0) rmax[wave] = mx;
  __syncthreads();
  mx = fmaxf(rmax[half * 2], rmax[half * 2 + 1]);
  float sum = 0.f;
#pragma unroll
  for (int j = 0; j < 8; ++j) { f[j] = __expf(f[j] - mx); sum += f[j]; }
#pragma unroll
  for (int o = 32; o > 0; o >>= 1) sum += __shfl_down(sum, o);
  if (lane == 0) rsum[wave] = sum;
  __syncthreads();
  const float inv = 1.0f / (rsum[half * 2] + rsum[half * 2 + 1]);
  unsigned short o8[8];
#pragma unroll
  for (int j = 0; j < 8; ++j) o8[j] = f2bf(f[j] * inv);
  *reinterpret_cast<uint4*>(S + base + ht * 8) = *reinterpret_cast<const uint4*>(o8);
}

// ---------------- L2-normalize rows of 512 bf16 in-place (wave/row) -------
__global__ __launch_bounds__(256)
void k_l2norm(unsigned short* __restrict__ Q, int ld) {
  const int lane = threadIdx.x & 63, wave = threadIdx.x >> 6;
  const long row = (long)blockIdx.x * 4 + wave;
  unsigned short* p = Q + row * ld + lane * 8;
  uint4 v = *reinterpret_cast<const uint4*>(p);
  const unsigned short* pv = (const unsigned short*)&v;
  float f[8]; float q = 0.f;
#pragma unroll
  for (int j = 0; j < 8; ++j) { f[j] = bf2f(pv[j]); q += f[j] * f[j]; }
#pragma unroll
  for (int o = 32; o > 0; o >>= 1) q += __shfl_xor(q, o);
  float sc = 1.0f / (sqrtf(q) + 1e-8f);
  unsigned short o8[8];
#pragma unroll
  for (int j = 0; j < 8; ++j) o8[j] = f2bf(f[j] * sc);
  *reinterpret_cast<uint4*>(p) = *reinterpret_cast<const uint4*>(o8);
}

// ---------------- LayerNorm rows of 512 bf16 in-place (wave/row) ----------
__global__ __launch_bounds__(256)
void k_ln_bf(unsigned short* __restrict__ X, const float* __restrict__ g,
             const float* __restrict__ b) {
  const int lane = threadIdx.x & 63, wave = threadIdx.x >> 6;
  const long row = (long)blockIdx.x * 4 + wave;
  unsigned short* p = X + row * CDIM + lane * 8;
  uint4 v = *reinterpret_cast<const uint4*>(p);
  const unsigned short* pv = (const unsigned short*)&v;
  float f[8];
  float s = 0.f, q = 0.f;
#pragma unroll
  for (int j = 0; j < 8; ++j) { f[j] = bf2f(pv[j]); s += f[j]; q += f[j] * f[j]; }
#pragma unroll
  for (int o = 32; o > 0; o >>= 1) { s += __shfl_xor(s, o); q += __shfl_xor(q, o); }
  float mu = s * (1.f / 512.f);
  float var = q * (1.f / 512.f) - mu * mu;
  float rs = rsqrtf(var + 1e-5f);
  float gg[8], bb[8];
  *reinterpret_cast<float4*>(&gg[0]) = *reinterpret_cast<const float4*>(g + lane * 8);
  *reinterpret_cast<float4*>(&gg[4]) = *reinterpret_cast<const float4*>(g + lane * 8 + 4);
  *reinterpret_cast<float4*>(&bb[0]) = *reinterpret_cast<const float4*>(b + lane * 8);
  *reinterpret_cast<float4*>(&bb[4]) = *reinterpret_cast<const float4*>(b + lane * 8 + 4);
  unsigned short o8[8];
#pragma unroll
  for (int j = 0; j < 8; ++j) o8[j] = f2bf((f[j] - mu) * rs * gg[j] + bb[j]);
  *reinterpret_cast<uint4*>(p) = *reinterpret_cast<const uint4*>(o8);
}

// ---------------- gating fusion (bf16 inputs): one wave per position ------
__global__ __launch_bounds__(256)
void k_gate(const unsigned short* __restrict__ o0, const unsigned short* __restrict__ o1,
            const unsigned short* __restrict__ o2, const float* __restrict__ gw,
            const float* __restrict__ gb, float* __restrict__ out) {
  __shared__ float gws[3 * 1536];
  for (int i = threadIdx.x; i < 3 * 1536; i += 256) gws[i] = gw[i];
  __syncthreads();
  const int lane = threadIdx.x & 63, wave = threadIdx.x >> 6;
  const long pos = (long)blockIdx.x * 4 + wave;
  const long off = pos * CDIM + lane * 8;
  float a[8], bq[8], cq[8];
  {
    uint4 va = *reinterpret_cast<const uint4*>(o0 + off);
    uint4 vb = *reinterpret_cast<const uint4*>(o1 + off);
    uint4 vc = *reinterpret_cast<const uint4*>(o2 + off);
    const unsigned short* pa = (const unsigned short*)&va;
    const unsigned short* pb = (const unsigned short*)&vb;
    const unsigned short* pc = (const unsigned short*)&vc;
#pragma unroll
    for (int j = 0; j < 8; ++j) { a[j] = bf2f(pa[j]); bq[j] = bf2f(pb[j]); cq[j] = bf2f(pc[j]); }
  }
  float l0 = 0.f, l1 = 0.f, l2 = 0.f;
  const int ch = lane * 8;
#pragma unroll
  for (int j = 0; j < 8; ++j) {
    l0 += a[j] * gws[ch + j] + bq[j] * gws[512 + ch + j] + cq[j] * gws[1024 + ch + j];
    l1 += a[j] * gws[1536 + ch + j] + bq[j] * gws[2048 + ch + j] + cq[j] * gws[2560 + ch + j];
    l2 += a[j] * gws[3072 + ch + j] + bq[j] * gws[3584 + ch + j] + cq[j] * gws[4096 + ch + j];
  }
#pragma unroll
  for (int o = 32; o > 0; o >>= 1) {
    l0 += __shfl_xor(l0, o); l1 += __shfl_xor(l1, o); l2 += __shfl_xor(l2, o);
  }
  l0 += gb[0]; l1 += gb[1]; l2 += gb[2];
  float m = fmaxf(l0, fmaxf(l1, l2));
  float e0 = __expf(l0 - m), e1 = __expf(l1 - m), e2 = __expf(l2 - m);
  float inv = 1.f / (e0 + e1 + e2);
  float g0 = e0 * inv, g1 = e1 * inv, g2 = e2 * inv;
  float r[8];
#pragma unroll
  for (int j = 0; j < 8; ++j) r[j] = g0 * a[j] + g1 * bq[j] + g2 * cq[j];
  *reinterpret_cast<float4*>(out + off) = *reinterpret_cast<const float4*>(&r[0]);
  *reinterpret_cast<float4*>(out + off + 4) = *reinterpret_cast<const float4*>(&r[4]);
}

// ===========================================================================
extern "C" void kernel_launch(void* const* d_in, const int* in_sizes, int n_in,
                              void* d_out, int out_size, void* d_ws, size_t ws_size,
                              hipStream_t stream) {
  (void)in_sizes; (void)n_in; (void)out_size;
  const float* x = (const float*)d_in[0];
  const float* dw = (const float*)d_in[1];
  const float* db = (const float*)d_in[2];
  // WB order: 0 wq_cr, 1 wq_d, 2 wk_d, 3 wq_c, 4 wk_c, 5 wv_d, 6 wv_c,
  //           7 wk_cr, 8 wv_cr
  WPtrs wp;
  wp.p[0] = (const float*)d_in[3];   // wq_cr
  wp.p[1] = (const float*)d_in[11];  // wq_d
  wp.p[2] = (const float*)d_in[13];  // wk_d
  wp.p[3] = (const float*)d_in[19];  // wq_c
  wp.p[4] = (const float*)d_in[21];  // wk_c
  wp.p[5] = (const float*)d_in[15];  // wv_d
  wp.p[6] = (const float*)d_in[23];  // wv_c
  wp.p[7] = (const float*)d_in[5];   // wk_cr
  wp.p[8] = (const float*)d_in[7];   // wv_cr
  const float* bq_cr = (const float*)d_in[4];
  const float* bk_cr = (const float*)d_in[6];
  const float* bv_cr = (const float*)d_in[8];
  const float* ln_cr_g = (const float*)d_in[9];
  const float* ln_cr_b = (const float*)d_in[10];
  const float* bq_d = (const float*)d_in[12];
  const float* bk_d = (const float*)d_in[14];
  const float* bv_d = (const float*)d_in[16];
  const float* ln_d_g = (const float*)d_in[17];
  const float* ln_d_b = (const float*)d_in[18];
  const float* bq_c = (const float*)d_in[20];
  const float* bk_c = (const float*)d_in[22];
  const float* bv_c = (const float*)d_in[24];
  const float* ln_c_g = (const float*)d_in[25];
  const float* ln_c_b = (const float*)d_in[26];
  const float* temp = (const float*)d_in[27];
  const float* gw = (const float*)d_in[28];
  const float* gb = (const float*)d_in[29];

  if (ws_size < 240000000ULL) return;  // plan needs ~226 MiB

  char* p = (char*)d_ws;
  auto alloc = [&](size_t bytes) {
    void* r = (void*)p;
    p += (bytes + 255) & ~(size_t)255;
    return r;
  };
  alloc(1024);                                                     // front pad
  unsigned short* XB  = (unsigned short*)alloc(16384L * 512 * 2);
  unsigned short* XD  = (unsigned short*)alloc(8192L * 512 * 2);
  unsigned short* WB  = (unsigned short*)alloc(9L * 262144 * 2);
  unsigned short* DWB = (unsigned short*)alloc(512L * 1536 * 2);
  unsigned short* QB  = (unsigned short*)alloc(16384L * 512 * 2);   // q_cr
  unsigned short* KB  = (unsigned short*)alloc(8192L * 512 * 2);    // k_cr
  unsigned short* VT  = (unsigned short*)alloc(512L * 16384 * 2);   // V^T, reused
  unsigned short* OUT0 = (unsigned short*)alloc(16384L * 512 * 2);
  unsigned short* OUT1 = (unsigned short*)alloc(16384L * 512 * 2);
  unsigned short* OUT2 = (unsigned short*)alloc(16384L * 512 * 2);
  unsigned short* QK2 = (unsigned short*)alloc(16384L * 1024 * 2);  // per-branch Q|K
  float* BC = (float*)alloc(2048 * 4);                              // bias concat
  unsigned short* SB = (unsigned short*)alloc(8L * 2048 * 2048 * 2);

  const float scale = 0.044194173824159216f;  // 1/sqrt(512)

  auto gemm = [&](const unsigned short* A, const unsigned short* Bm, void* Cm,
                  int M, int N, int K, int lda, int ldb, int ldc,
                  int batch, long sA, long sB, long sC,
                  const float* bias, float alpha, int mode) {
    dim3 g(M / 128, N / 128, batch);
    k_gemm<<<g, 256, 0, stream>>>(A, Bm, Cm, K, lda, ldb, ldc, sA, sB, sC,
                                  bias, alpha, mode);
  };
  auto gemm64 = [&](const unsigned short* A, const unsigned short* Bm, void* Cm,
                    int M, int N, int K, int lda, int ldb, int ldc,
                    int batch, long sA, long sB, long sC,
                    const float* bias, float alpha, int mode) {
    dim3 g(M / 128, N / 64, batch);
    k_gemm64<<<g, 256, 0, stream>>>(A, Bm, Cm, K, lda, ldb, ldc, sA, sB, sC,
                                    bias, alpha, mode);
  };
  auto gemm256 = [&](const unsigned short* A, const unsigned short* Bm,
                     unsigned short* Cm, int M, int N, int K,
                     int lda, int ldb, int ldc, int batch,
                     long sA, long sB, long sC, float alpha, const float* tp) {
    dim3 g(M / 256, N / 256, batch);
    k_gemm256<<<g, 512, 0, stream>>>(A, Bm, Cm, K, lda, ldb, ldc, sA, sB, sC, alpha, tp);
  };

  // ---- conversions & bias concats ----
  k_tobf16<<<8192, 256, 0, stream>>>(x, XB, 16384L * 512 / 4);
  k_tobf16w<<<2304, 256, 0, stream>>>(wp, WB);
  k_dwreorder<<<3072, 256, 0, stream>>>(dw, DWB);
  hipMemcpyAsync(BC,        bq_d, 512 * 4, hipMemcpyDeviceToDevice, stream);
  hipMemcpyAsync(BC + 512,  bk_d, 512 * 4, hipMemcpyDeviceToDevice, stream);
  hipMemcpyAsync(BC + 1024, bq_c, 512 * 4, hipMemcpyDeviceToDevice, stream);
  hipMemcpyAsync(BC + 1536, bk_c, 512 * 4, hipMemcpyDeviceToDevice, stream);

  // ---- downsample conv: strided-A GEMM (row t = x[b][2t-1..2t+1], contig) --
  gemm(XB - 512, DWB, XD, 1024, 512, 1536, 1024, 1536, 512,
       8, 1048576L, 0, 524288L, db, 1.f, 1);
  k_fix<<<1024, 256, 0, stream>>>(XB, DWB, db, XD);   // exact t=0 rows

  // ================= branch cr (q from x, k/v from x_down) =================
  gemm(XB, WB + 0 * 262144L, QB, 16384, 512, 512, 512, 512, 512, 1, 0, 0, 0,
       bq_cr, 1.f, 1);
  gemm(XD, WB + 7 * 262144L, KB, 8192, 512, 512, 512, 512, 512, 1, 0, 0, 0,
       bk_cr, 1.f, 1);
  // V^T = W_v_cr * XD^T : [512][8192], per-batch view VT + b*1024, ldb 8192
  gemm64(WB + 8 * 262144L, XD, VT, 512, 8192, 512, 512, 512, 8192, 1, 0, 0, 0,
         bv_cr, 1.f, 3);
  gemm256(QB, KB, SB, 2048, 1024, 512, 512, 512, 1024, 8,
          2048L * 512, 1024L * 512, 2048L * 1024, scale, nullptr);
  k_softmax1024<<<8192, 256, 0, stream>>>(SB);
  gemm(SB, VT, OUT0, 2048, 512, 1024, 1024, 8192, 512, 8,
       2048L * 1024, 1024, 2048L * 512, nullptr, 1.f, 1);
  k_ln_bf<<<4096, 256, 0, stream>>>(OUT0, ln_cr_g, ln_cr_b);

  // ================= branch d (standard attention over x) ==================
  gemm(XB, WB + 1 * 262144L, QK2, 16384, 1024, 512, 512, 512, 1024, 1, 0, 0, 0,
       BC, 1.f, 1);                                  // fused Q|K projection
  // V^T = W_v_d * XB^T : [512][16384], per-batch view VT + b*2048, ldb 16384
  gemm64(WB + 5 * 262144L, XB, VT, 512, 16384, 512, 512, 512, 16384, 1, 0, 0, 0,
         bv_d, 1.f, 3);
  gemm256(QK2, QK2 + 512, SB, 2048, 2048, 512, 1024, 1024, 2048, 8,
          2048L * 1024, 2048L * 1024, 2048L * 2048, scale, nullptr);
  k_softmax<<<16384, 256, 0, stream>>>(SB, 2048);
  gemm(SB, VT, OUT1, 2048, 512, 2048, 2048, 16384, 512, 8,
       2048L * 2048, 2048, 2048L * 512, nullptr, 1.f, 1);
  k_ln_bf<<<4096, 256, 0, stream>>>(OUT1, ln_d_g, ln_d_b);

  // ================= branch c (cosine attention, learnable temp) ===========
  gemm(XB, WB + 3 * 262144L, QK2, 16384, 1024, 512, 512, 512, 1024, 1, 0, 0, 0,
       BC + 1024, 1.f, 1);                           // fused Q|K projection
  k_l2norm<<<4096, 256, 0, stream>>>(QK2, 1024);
  k_l2norm<<<4096, 256, 0, stream>>>(QK2 + 512, 1024);
  gemm64(WB + 6 * 262144L, XB, VT, 512, 16384, 512, 512, 512, 16384, 1, 0, 0, 0,
         bv_c, 1.f, 3);
  gemm256(QK2, QK2 + 512, SB, 2048, 2048, 512, 1024, 1024, 2048, 8,
          2048L * 1024, 2048L * 1024, 2048L * 2048, 1.f, temp);
  k_softmax<<<16384, 256, 0, stream>>>(SB, 2048);
  gemm(SB, VT, OUT2, 2048, 512, 2048, 2048, 16384, 512, 8,
       2048L * 2048, 2048, 2048L * 512, nullptr, 1.f, 1);
  k_ln_bf<<<4096, 256, 0, stream>>>(OUT2, ln_c_g, ln_c_b);

  // ================= gated fusion -> d_out ================================
  k_gate<<<4096, 256, 0, stream>>>(OUT0, OUT1, OUT2, gw, gb, (float*)d_out);
}

// Round 13
// 539.770 us; speedup vs baseline: 1.2303x; 1.0121x over previous
//
#include <hip/hip_runtime.h>

// ---------------------------------------------------------------------------
// Hybrid MRHA: conv-downsample + 3 attention branches + LN + gated fusion.
// k_gemm    : 128x128, BK=64, XOR-swizzled LDS, counted-vmcnt 2-barrier loop.
// k_gemm64  : 128x64 variant — V^T projections, conv, K-cr (L2-resident B or
//             L3-resident A: BN=64 traffic-neutral, 2x blocks/CU).
// k_gemm256 : 256x256, BK=32, scores only.
// k_gate    : LayerNorm (all 3 branches) + gating fusion in one pass.
// ---------------------------------------------------------------------------

typedef __attribute__((ext_vector_type(8))) __bf16 bf16x8;
typedef __attribute__((ext_vector_type(4))) float f32x4;

#define CDIM 512
#define TFULL 2048

#define GLL16(gp, lp)                                                        \
  __builtin_amdgcn_global_load_lds(                                          \
      (const __attribute__((address_space(1))) unsigned int*)(gp),           \
      (__attribute__((address_space(3))) unsigned int*)(lp), 16, 0, 0)

__device__ __forceinline__ unsigned short f2bf(float f) {
  unsigned u = __float_as_uint(f);
  u = (u + 0x7fffu + ((u >> 16) & 1u)) >> 16;   // round-to-nearest-even
  return (unsigned short)u;
}
__device__ __forceinline__ float bf2f(unsigned short h) {
  return __uint_as_float(((unsigned)h) << 16);
}

// ---------------- conversion: f32 -> bf16 (vec4) ----------------
__global__ __launch_bounds__(256)
void k_tobf16(const float* __restrict__ src, unsigned short* __restrict__ dst, long n4) {
  long i = (long)blockIdx.x * 256 + threadIdx.x;
  if (i >= n4) return;
  float4 f = reinterpret_cast<const float4*>(src)[i];
  unsigned short o4[4] = {f2bf(f.x), f2bf(f.y), f2bf(f.z), f2bf(f.w)};
  reinterpret_cast<uint2*>(dst)[i] = *reinterpret_cast<const uint2*>(o4);
}

// ---------------- batched weight conversion: 9 x 512x512 -> WB ----------
struct WPtrs { const float* p[9]; };
__global__ __launch_bounds__(256)
void k_tobf16w(WPtrs w, unsigned short* __restrict__ dst) {
  int idx = blockIdx.x * 256 + threadIdx.x;       // over 9*65536 vec4 units
  if (idx >= 9 * 65536) return;
  int m = idx >> 16, off = idx & 65535;
  float4 f = reinterpret_cast<const float4*>(w.p[m])[off];
  unsigned short o4[4] = {f2bf(f.x), f2bf(f.y), f2bf(f.z), f2bf(f.w)};
  reinterpret_cast<uint2*>(dst + (long)m * 262144)[off] = *reinterpret_cast<const uint2*>(o4);
}

// ---------------- dw [o][i][k] -> DWB bf16 [o][k*512+i] ----------------
__global__ __launch_bounds__(256)
void k_dwreorder(const float* __restrict__ dw, unsigned short* __restrict__ dwb) {
  int idx = blockIdx.x * 256 + threadIdx.x;           // over 512*1536
  if (idx >= 512 * 1536) return;
  int o = idx / 1536, rem = idx - o * 1536;
  int k = rem >> 9, i = rem & 511;
  dwb[idx] = f2bf(dw[(o * 512 + i) * 3 + k]);
}

// ---------------- conv row-0 fixup: one wave per (b,o), coalesced ---------
__global__ __launch_bounds__(256)
void k_fix(const unsigned short* __restrict__ XB, const unsigned short* __restrict__ DWB,
           const float* __restrict__ db, unsigned short* __restrict__ XD) {
  const int lane = threadIdx.x & 63, wave = threadIdx.x >> 6;
  const int idx = blockIdx.x * 4 + wave;      // 4096 = 8 batches * 512 outputs
  const int b = idx >> 9, o = idx & 511;
  const unsigned short* xr = XB + (long)b * TFULL * CDIM + lane * 16;  // rows 0,1
  const unsigned short* wr = DWB + (long)o * 1536 + 512 + lane * 16;   // taps 1,2
  float acc = 0.f;
  uint4 xv0 = *reinterpret_cast<const uint4*>(xr);
  uint4 xv1 = *reinterpret_cast<const uint4*>(xr + 8);
  uint4 wv0 = *reinterpret_cast<const uint4*>(wr);
  uint4 wv1 = *reinterpret_cast<const uint4*>(wr + 8);
  const unsigned short* xp0 = (const unsigned short*)&xv0;
  const unsigned short* xp1 = (const unsigned short*)&xv1;
  const unsigned short* wp0 = (const unsigned short*)&wv0;
  const unsigned short* wp1 = (const unsigned short*)&wv1;
#pragma unroll
  for (int j = 0; j < 8; ++j) acc += bf2f(xp0[j]) * bf2f(wp0[j]);
#pragma unroll
  for (int j = 0; j < 8; ++j) acc += bf2f(xp1[j]) * bf2f(wp1[j]);
#pragma unroll
  for (int off = 32; off > 0; off >>= 1) acc += __shfl_xor(acc, off);
  if (lane == 0) XD[(long)b * 1024 * 512 + o] = f2bf(acc + db[o]);
}

// ---------------- GEMM 128x128: C = alpha * A * B^T + bias ----------------
// mode 1: bf16 store, bias[col] | mode 3: bf16 store, bias[row]
__global__ __launch_bounds__(256)
void k_gemm(const unsigned short* __restrict__ A,
            const unsigned short* __restrict__ B,
            void* __restrict__ Cp,
            int K, int lda, int ldb, int ldc,
            long sA, long sB, long sC,
            const float* __restrict__ bias,
            float alpha, int mode) {
  const int gx = gridDim.x;
  const int nwg = gx * gridDim.y;
  int wg = blockIdx.x + gx * blockIdx.y;
  wg = (wg & 7) * (nwg >> 3) + (wg >> 3);
  const int tm0 = (wg % gx) * 128, tn0 = (wg / gx) * 128;
  const int bz = blockIdx.z;
  const unsigned short* Ag = A + (long)bz * sA;
  const unsigned short* Bg = B + (long)bz * sB;

  __shared__ __align__(16) unsigned short smem[32768];

  const int tid = threadIdx.x;
  const int lane = tid & 63;
  const int wave = tid >> 6;
  const int wm = (wave >> 1) * 64, wn = (wave & 1) * 64;
  const int lrow = lane & 15, kq = lane >> 4;

  f32x4 acc[4][4];
#pragma unroll
  for (int i = 0; i < 4; ++i)
#pragma unroll
    for (int j = 0; j < 4; ++j) acc[i][j] = f32x4{0.f, 0.f, 0.f, 0.f};

  const int sr = tid >> 3;                 // 0..31
  const int sj = (tid & 7) ^ (sr & 7);     // inverse-swizzled source slot
  const unsigned short* aSrc = Ag + (long)(tm0 + sr) * lda + sj * 8;
  const unsigned short* bSrc = Bg + (long)(tn0 + sr) * ldb + sj * 8;

  const int nt = K >> 6;

#define STAGE(kt_, buf_)                                                     \
  {                                                                          \
    unsigned short* aD = smem + (buf_) * 8192 + wave * 512;                  \
    unsigned short* bD = smem + 16384 + (buf_) * 8192 + wave * 512;          \
    _Pragma("unroll")                                                        \
    for (int rd = 0; rd < 4; ++rd) {                                         \
      GLL16(aSrc + (kt_) + (long)rd * 32 * lda, aD + rd * 2048);             \
      GLL16(bSrc + (kt_) + (long)rd * 32 * ldb, bD + rd * 2048);             \
    }                                                                        \
  }

  STAGE(0, 0);

  const int xr = (lrow & 7) << 3;
  for (int t = 0; t < nt; ++t) {
    if (t + 1 < nt) {
      STAGE((t + 1) << 6, (t + 1) & 1);    // prefetch stays in flight
      asm volatile("s_waitcnt vmcnt(8)" ::: "memory");   // my tile-t loads done
    } else {
      asm volatile("s_waitcnt vmcnt(0)" ::: "memory");   // final drain (once)
    }
    __builtin_amdgcn_s_barrier();          // everyone's tile-t loads done
    __builtin_amdgcn_sched_barrier(0);
    const unsigned short* As_ = smem + (t & 1) * 8192;
    const unsigned short* Bs_ = smem + 16384 + (t & 1) * 8192;
    bf16x8 af[4][2], bfv[4][2];
#pragma unroll
    for (int mi = 0; mi < 4; ++mi)
#pragma unroll
      for (int ks = 0; ks < 2; ++ks)
        af[mi][ks] = *reinterpret_cast<const bf16x8*>(
            &As_[(wm + mi * 16 + lrow) * 64 + ((ks * 32 + kq * 8) ^ xr)]);
#pragma unroll
    for (int ni = 0; ni < 4; ++ni)
#pragma unroll
      for (int ks = 0; ks < 2; ++ks)
        bfv[ni][ks] = *reinterpret_cast<const bf16x8*>(
            &Bs_[(wn + ni * 16 + lrow) * 64 + ((ks * 32 + kq * 8) ^ xr)]);
#pragma unroll
    for (int mi = 0; mi < 4; ++mi)
#pragma unroll
      for (int ni = 0; ni < 4; ++ni) {
        acc[mi][ni] = __builtin_amdgcn_mfma_f32_16x16x32_bf16(af[mi][0], bfv[ni][0], acc[mi][ni], 0, 0, 0);
        acc[mi][ni] = __builtin_amdgcn_mfma_f32_16x16x32_bf16(af[mi][1], bfv[ni][1], acc[mi][ni], 0, 0, 0);
      }
    __builtin_amdgcn_sched_barrier(0);
    if (t + 1 < nt) __builtin_amdgcn_s_barrier();  // reads done: next STAGE may overwrite
  }
#undef STAGE

  unsigned short* Cb = (unsigned short*)Cp + (long)bz * sC;
  if (mode == 1) {
#pragma unroll
    for (int mi = 0; mi < 4; ++mi) {
      int rg = tm0 + wm + mi * 16 + kq * 4;
#pragma unroll
      for (int ni = 0; ni < 4; ++ni) {
        int cg = tn0 + wn + ni * 16 + lrow;
        float bb = bias ? bias[cg] : 0.f;
        f32x4 v = acc[mi][ni];
#pragma unroll
        for (int r = 0; r < 4; ++r)
          Cb[(long)(rg + r) * ldc + cg] = f2bf(v[r] * alpha + bb);
      }
    }
  } else {                                 // mode 3: bias indexed by row
#pragma unroll
    for (int mi = 0; mi < 4; ++mi) {
      int rg = tm0 + wm + mi * 16 + kq * 4;
      float rb[4];
#pragma unroll
      for (int r = 0; r < 4; ++r) rb[r] = bias[rg + r];
#pragma unroll
      for (int ni = 0; ni < 4; ++ni) {
        int cg = tn0 + wn + ni * 16 + lrow;
        f32x4 v = acc[mi][ni];
#pragma unroll
        for (int r = 0; r < 4; ++r)
          Cb[(long)(rg + r) * ldc + cg] = f2bf(v[r] * alpha + rb[r]);
      }
    }
  }
}

// ---------------- GEMM 128x64 (L2-resident-operand shapes) ----------------
// Requires: M%128==0, N%64==0, K%64==0, (M/128)*(N/64)%8==0.
__global__ __launch_bounds__(256)
void k_gemm64(const unsigned short* __restrict__ A,
              const unsigned short* __restrict__ B,
              void* __restrict__ Cp,
              int K, int lda, int ldb, int ldc,
              long sA, long sB, long sC,
              const float* __restrict__ bias,
              float alpha, int mode) {
  const int gx = gridDim.x;
  const int nwg = gx * gridDim.y;
  int wg = blockIdx.x + gx * blockIdx.y;
  wg = (wg & 7) * (nwg >> 3) + (wg >> 3);
  const int tm0 = (wg % gx) * 128, tn0 = (wg / gx) * 64;
  const int bz = blockIdx.z;
  const unsigned short* Ag = A + (long)bz * sA;
  const unsigned short* Bg = B + (long)bz * sB;

  __shared__ __align__(16) unsigned short smem[24576];

  const int tid = threadIdx.x;
  const int lane = tid & 63;
  const int wave = tid >> 6;
  const int wm = (wave >> 1) * 64, wn = (wave & 1) * 32;
  const int lrow = lane & 15, kq = lane >> 4;

  f32x4 acc[4][2];
#pragma unroll
  for (int i = 0; i < 4; ++i)
#pragma unroll
    for (int j = 0; j < 2; ++j) acc[i][j] = f32x4{0.f, 0.f, 0.f, 0.f};

  const int sr = tid >> 3;                 // 0..31
  const int sj = (tid & 7) ^ (sr & 7);     // inverse-swizzled source slot
  const unsigned short* aSrc = Ag + (long)(tm0 + sr) * lda + sj * 8;
  const unsigned short* bSrc = Bg + (long)(tn0 + sr) * ldb + sj * 8;

  const int nt = K >> 6;

#define STAGE64(kt_, buf_)                                                   \
  {                                                                          \
    unsigned short* aD = smem + (buf_) * 8192 + wave * 512;                  \
    unsigned short* bD = smem + 16384 + (buf_) * 4096 + wave * 512;          \
    _Pragma("unroll")                                                        \
    for (int rd = 0; rd < 4; ++rd)                                           \
      GLL16(aSrc + (kt_) + (long)rd * 32 * lda, aD + rd * 2048);             \
    _Pragma("unroll")                                                        \
    for (int rd = 0; rd < 2; ++rd)                                           \
      GLL16(bSrc + (kt_) + (long)rd * 32 * ldb, bD + rd * 2048);             \
  }

  STAGE64(0, 0);

  const int xr = (lrow & 7) << 3;
  for (int t = 0; t < nt; ++t) {
    if (t + 1 < nt) {
      STAGE64((t + 1) << 6, (t + 1) & 1);
      asm volatile("s_waitcnt vmcnt(6)" ::: "memory");
    } else {
      asm volatile("s_waitcnt vmcnt(0)" ::: "memory");
    }
    __builtin_amdgcn_s_barrier();
    __builtin_amdgcn_sched_barrier(0);
    const unsigned short* As_ = smem + (t & 1) * 8192;
    const unsigned short* Bs_ = smem + 16384 + (t & 1) * 4096;
    bf16x8 af[4][2], bfv[2][2];
#pragma unroll
    for (int mi = 0; mi < 4; ++mi)
#pragma unroll
      for (int ks = 0; ks < 2; ++ks)
        af[mi][ks] = *reinterpret_cast<const bf16x8*>(
            &As_[(wm + mi * 16 + lrow) * 64 + ((ks * 32 + kq * 8) ^ xr)]);
#pragma unroll
    for (int ni = 0; ni < 2; ++ni)
#pragma unroll
      for (int ks = 0; ks < 2; ++ks)
        bfv[ni][ks] = *reinterpret_cast<const bf16x8*>(
            &Bs_[(wn + ni * 16 + lrow) * 64 + ((ks * 32 + kq * 8) ^ xr)]);
#pragma unroll
    for (int mi = 0; mi < 4; ++mi)
#pragma unroll
      for (int ni = 0; ni < 2; ++ni) {
        acc[mi][ni] = __builtin_amdgcn_mfma_f32_16x16x32_bf16(af[mi][0], bfv[ni][0], acc[mi][ni], 0, 0, 0);
        acc[mi][ni] = __builtin_amdgcn_mfma_f32_16x16x32_bf16(af[mi][1], bfv[ni][1], acc[mi][ni], 0, 0, 0);
      }
    __builtin_amdgcn_sched_barrier(0);
    if (t + 1 < nt) __builtin_amdgcn_s_barrier();
  }
#undef STAGE64

  unsigned short* Cb = (unsigned short*)Cp + (long)bz * sC;
  if (mode == 1) {
#pragma unroll
    for (int mi = 0; mi < 4; ++mi) {
      int rg = tm0 + wm + mi * 16 + kq * 4;
#pragma unroll
      for (int ni = 0; ni < 2; ++ni) {
        int cg = tn0 + wn + ni * 16 + lrow;
        float bb = bias ? bias[cg] : 0.f;
        f32x4 v = acc[mi][ni];
#pragma unroll
        for (int r = 0; r < 4; ++r)
          Cb[(long)(rg + r) * ldc + cg] = f2bf(v[r] * alpha + bb);
      }
    }
  } else {                                 // mode 3: bias indexed by row
#pragma unroll
    for (int mi = 0; mi < 4; ++mi) {
      int rg = tm0 + wm + mi * 16 + kq * 4;
      float rb[4];
#pragma unroll
      for (int r = 0; r < 4; ++r) rb[r] = bias[rg + r];
#pragma unroll
      for (int ni = 0; ni < 2; ++ni) {
        int cg = tn0 + wn + ni * 16 + lrow;
        f32x4 v = acc[mi][ni];
#pragma unroll
        for (int r = 0; r < 4; ++r)
          Cb[(long)(rg + r) * ldc + cg] = f2bf(v[r] * alpha + rb[r]);
      }
    }
  }
}

// ---------------- GEMM 256x256 (scores): C = alpha * A * B^T --------------
// Requires M%256==0, N%256==0, K%32==0, (M/256)*(N/256)%8==0.
__global__ __launch_bounds__(512)
void k_gemm256(const unsigned short* __restrict__ A,
               const unsigned short* __restrict__ B,
               unsigned short* __restrict__ C,
               int K, int lda, int ldb, int ldc,
               long sA, long sB, long sC,
               float alpha, const float* __restrict__ tempPtr) {
  const int gx = gridDim.x;
  const int nwg = gx * gridDim.y;
  int wg = blockIdx.x + gx * blockIdx.y;
  wg = (wg & 7) * (nwg >> 3) + (wg >> 3);
  const int tm0 = (wg % gx) * 256, tn0 = (wg / gx) * 256;
  const unsigned short* Ag = A + (long)blockIdx.z * sA;
  const unsigned short* Bg = B + (long)blockIdx.z * sB;

  __shared__ __align__(16) unsigned short smem[32768];

  const int tid = threadIdx.x;
  const int lane = tid & 63;
  const int wave = tid >> 6;               // 0..7
  const int wm = (wave >> 2) * 128, wn = (wave & 3) * 64;
  const int lrow = lane & 15, kq = lane >> 4;

  f32x4 acc[8][4];
#pragma unroll
  for (int i = 0; i < 8; ++i)
#pragma unroll
    for (int j = 0; j < 4; ++j) acc[i][j] = f32x4{0.f, 0.f, 0.f, 0.f};

  const int srow = lane >> 2;                          // 0..15
  const int sslot = (lane & 3) ^ ((lane >> 3) & 3);    // inverse swizzle
  const unsigned short* aS0 = Ag + (long)(tm0 + wave * 16 + srow) * lda + sslot * 8;
  const unsigned short* aS1 = aS0 + 128L * lda;
  const unsigned short* bS0 = Bg + (long)(tn0 + wave * 16 + srow) * ldb + sslot * 8;
  const unsigned short* bS1 = bS0 + 128L * ldb;

  const int nt = K >> 5;

#define STAGE256(kt_, buf_)                                                  \
  {                                                                          \
    unsigned short* aD = smem + (buf_) * 8192 + wave * 512;                  \
    unsigned short* bD = smem + 16384 + (buf_) * 8192 + wave * 512;          \
    GLL16(aS0 + (kt_), aD);                                                  \
    GLL16(aS1 + (kt_), aD + 4096);                                           \
    GLL16(bS0 + (kt_), bD);                                                  \
    GLL16(bS1 + (kt_), bD + 4096);                                           \
  }

  STAGE256(0, 0);                          // prologue

  const int xr = ((lrow >> 1) & 3) << 3;   // read-side elem XOR
  for (int t = 0; t < nt; ++t) {
    if (t + 1 < nt) {
      STAGE256((t + 1) << 5, (t + 1) & 1); // prefetch next tile
      asm volatile("s_waitcnt vmcnt(4)" ::: "memory");   // tile t landed (mine)
    } else {
      asm volatile("s_waitcnt vmcnt(0)" ::: "memory");   // final drain (once)
    }
    __builtin_amdgcn_s_barrier();          // tile t landed (everyone)
    __builtin_amdgcn_sched_barrier(0);
    const unsigned short* As_ = smem + (t & 1) * 8192;
    const unsigned short* Bs_ = smem + 16384 + (t & 1) * 8192;
    bf16x8 bfv[4];
#pragma unroll
    for (int ni = 0; ni < 4; ++ni)
      bfv[ni] = *reinterpret_cast<const bf16x8*>(
          &Bs_[(wn + ni * 16 + lrow) * 32 + ((kq * 8) ^ xr)]);
#pragma unroll
    for (int mi = 0; mi < 8; ++mi) {
      bf16x8 af = *reinterpret_cast<const bf16x8*>(
          &As_[(wm + mi * 16 + lrow) * 32 + ((kq * 8) ^ xr)]);
#pragma unroll
      for (int ni = 0; ni < 4; ++ni)
        acc[mi][ni] = __builtin_amdgcn_mfma_f32_16x16x32_bf16(af, bfv[ni], acc[mi][ni], 0, 0, 0);
    }
    __builtin_amdgcn_sched_barrier(0);
    if (t + 1 < nt) __builtin_amdgcn_s_barrier();  // reads done: next STAGE may overwrite
  }
#undef STAGE256

  if (tempPtr) alpha = 1.0f / fmaxf(*tempPtr, 0.01f);

  C += (long)blockIdx.z * sC;
#pragma unroll
  for (int mi = 0; mi < 8; ++mi) {
    int rg = tm0 + wm + mi * 16 + kq * 4;
#pragma unroll
    for (int ni = 0; ni < 4; ++ni) {
      int cg = tn0 + wn + ni * 16 + lrow;
      f32x4 v = acc[mi][ni];
#pragma unroll
      for (int r = 0; r < 4; ++r)
        C[(long)(rg + r) * ldc + cg] = f2bf(v[r] * alpha);
    }
  }
}

// ---------------- row softmax, bf16 in-place, cols == 2048 ----------------
__global__ __launch_bounds__(256)
void k_softmax(unsigned short* __restrict__ S, int cols) {
  const long base = (long)blockIdx.x * cols;
  const int tid = threadIdx.x, lane = tid & 63, wave = tid >> 6;
  const int nv = cols >> 3;
  float f[8];
  float mx = -3.0e38f;
  if (tid < nv) {
    uint4 v = *reinterpret_cast<const uint4*>(S + base + tid * 8);
    const unsigned short* pv = (const unsigned short*)&v;
#pragma unroll
    for (int j = 0; j < 8; ++j) { f[j] = bf2f(pv[j]); mx = fmaxf(mx, f[j]); }
  }
  __shared__ float rmax[4], rsum[4];
#pragma unroll
  for (int o = 32; o > 0; o >>= 1) mx = fmaxf(mx, __shfl_down(mx, o));
  if (lane == 0) rmax[wave] = mx;
  __syncthreads();
  mx = fmaxf(fmaxf(rmax[0], rmax[1]), fmaxf(rmax[2], rmax[3]));
  float sum = 0.f;
  if (tid < nv) {
#pragma unroll
    for (int j = 0; j < 8; ++j) { f[j] = __expf(f[j] - mx); sum += f[j]; }
  }
#pragma unroll
  for (int o = 32; o > 0; o >>= 1) sum += __shfl_down(sum, o);
  if (lane == 0) rsum[wave] = sum;
  __syncthreads();
  const float inv = 1.0f / (rsum[0] + rsum[1] + rsum[2] + rsum[3]);
  if (tid < nv) {
    unsigned short o8[8];
#pragma unroll
    for (int j = 0; j < 8; ++j) o8[j] = f2bf(f[j] * inv);
    *reinterpret_cast<uint4*>(S + base + tid * 8) = *reinterpret_cast<const uint4*>(o8);
  }
}

// ---------------- row softmax cols=1024: 2 rows/block, all lanes live -----
__global__ __launch_bounds__(256)
void k_softmax1024(unsigned short* __restrict__ S) {
  const int tid = threadIdx.x;
  const int half = tid >> 7, ht = tid & 127;       // row-pair half, idx in half
  const int lane = tid & 63, wave = tid >> 6;      // waves {0,1}=row0 {2,3}=row1
  const long base = ((long)blockIdx.x * 2 + half) * 1024;
  uint4 v = *reinterpret_cast<const uint4*>(S + base + ht * 8);
  const unsigned short* pv = (const unsigned short*)&v;
  float f[8];
  float mx = -3.0e38f;
#pragma unroll
  for (int j = 0; j < 8; ++j) { f[j] = bf2f(pv[j]); mx = fmaxf(mx, f[j]); }
  __shared__ float rmax[4], rsum[4];
#pragma unroll
  for (int o = 32; o > 0; o >>= 1) mx = fmaxf(mx, __shfl_down(mx, o));
  if (lane == 0) rmax[wave] = mx;
  __syncthreads();
  mx = fmaxf(rmax[half * 2], rmax[half * 2 + 1]);
  float sum = 0.f;
#pragma unroll
  for (int j = 0; j < 8; ++j) { f[j] = __expf(f[j] - mx); sum += f[j]; }
#pragma unroll
  for (int o = 32; o > 0; o >>= 1) sum += __shfl_down(sum, o);
  if (lane == 0) rsum[wave] = sum;
  __syncthreads();
  const float inv = 1.0f / (rsum[half * 2] + rsum[half * 2 + 1]);
  unsigned short o8[8];
#pragma unroll
  for (int j = 0; j < 8; ++j) o8[j] = f2bf(f[j] * inv);
  *reinterpret_cast<uint4*>(S + base + ht * 8) = *reinterpret_cast<const uint4*>(o8);
}

// ---------------- L2-normalize: 32768 rows of 512 in QK2 [.][1024] --------
__global__ __launch_bounds__(256)
void k_l2norm2(unsigned short* __restrict__ Q) {
  const int lane = threadIdx.x & 63, wave = threadIdx.x >> 6;
  const int idx = blockIdx.x * 4 + wave;            // 0..32767
  unsigned short* p = Q + (long)(idx >> 1) * 1024 + (idx & 1) * 512 + lane * 8;
  uint4 v = *reinterpret_cast<const uint4*>(p);
  const unsigned short* pv = (const unsigned short*)&v;
  float f[8]; float q = 0.f;
#pragma unroll
  for (int j = 0; j < 8; ++j) { f[j] = bf2f(pv[j]); q += f[j] * f[j]; }
#pragma unroll
  for (int o = 32; o > 0; o >>= 1) q += __shfl_xor(q, o);
  float sc = 1.0f / (sqrtf(q) + 1e-8f);
  unsigned short o8[8];
#pragma unroll
  for (int j = 0; j < 8; ++j) o8[j] = f2bf(f[j] * sc);
  *reinterpret_cast<uint4*>(p) = *reinterpret_cast<const uint4*>(o8);
}

// -------- fused LayerNorm(3 branches) + gating: one wave per position -----
__global__ __launch_bounds__(256)
void k_gate(const unsigned short* __restrict__ o0, const unsigned short* __restrict__ o1,
            const unsigned short* __restrict__ o2, const float* __restrict__ gw,
            const float* __restrict__ gb,
            const float* __restrict__ g0, const float* __restrict__ b0,
            const float* __restrict__ g1, const float* __restrict__ b1,
            const float* __restrict__ g2, const float* __restrict__ b2,
            float* __restrict__ out) {
  __shared__ float gws[3 * 1536];
  for (int i = threadIdx.x; i < 3 * 1536; i += 256) gws[i] = gw[i];
  __syncthreads();
  const int lane = threadIdx.x & 63, wave = threadIdx.x >> 6;
  const long pos = (long)blockIdx.x * 4 + wave;
  const long off = pos * CDIM + lane * 8;
  float a[8], bq[8], cq[8];
  {
    uint4 va = *reinterpret_cast<const uint4*>(o0 + off);
    uint4 vb = *reinterpret_cast<const uint4*>(o1 + off);
    uint4 vc = *reinterpret_cast<const uint4*>(o2 + off);
    const unsigned short* pa = (const unsigned short*)&va;
    const unsigned short* pb = (const unsigned short*)&vb;
    const unsigned short* pc = (const unsigned short*)&vc;
#pragma unroll
    for (int j = 0; j < 8; ++j) { a[j] = bf2f(pa[j]); bq[j] = bf2f(pb[j]); cq[j] = bf2f(pc[j]); }
  }
  // per-branch LN stats (6-value butterfly)
  float sa = 0.f, qa = 0.f, sb = 0.f, qb = 0.f, sc2 = 0.f, qc = 0.f;
#pragma unroll
  for (int j = 0; j < 8; ++j) {
    sa += a[j];  qa += a[j] * a[j];
    sb += bq[j]; qb += bq[j] * bq[j];
    sc2 += cq[j]; qc += cq[j] * cq[j];
  }
#pragma unroll
  for (int o = 32; o > 0; o >>= 1) {
    sa += __shfl_xor(sa, o);  qa += __shfl_xor(qa, o);
    sb += __shfl_xor(sb, o);  qb += __shfl_xor(qb, o);
    sc2 += __shfl_xor(sc2, o); qc += __shfl_xor(qc, o);
  }
  const float inv512 = 1.f / 512.f;
  float mua = sa * inv512, rsa = rsqrtf(qa * inv512 - mua * mua + 1e-5f);
  float mub = sb * inv512, rsb = rsqrtf(qb * inv512 - mub * mub + 1e-5f);
  float muc = sc2 * inv512, rsc = rsqrtf(qc * inv512 - muc * muc + 1e-5f);
  const int ch = lane * 8;
  float gga[8], bba[8], ggb[8], bbb[8], ggc[8], bbc[8];
  *reinterpret_cast<float4*>(&gga[0]) = *reinterpret_cast<const float4*>(g0 + ch);
  *reinterpret_cast<float4*>(&gga[4]) = *reinterpret_cast<const float4*>(g0 + ch + 4);
  *reinterpret_cast<float4*>(&bba[0]) = *reinterpret_cast<const float4*>(b0 + ch);
  *reinterpret_cast<float4*>(&bba[4]) = *reinterpret_cast<const float4*>(b0 + ch + 4);
  *reinterpret_cast<float4*>(&ggb[0]) = *reinterpret_cast<const float4*>(g1 + ch);
  *reinterpret_cast<float4*>(&ggb[4]) = *reinterpret_cast<const float4*>(g1 + ch + 4);
  *reinterpret_cast<float4*>(&bbb[0]) = *reinterpret_cast<const float4*>(b1 + ch);
  *reinterpret_cast<float4*>(&bbb[4]) = *reinterpret_cast<const float4*>(b1 + ch + 4);
  *reinterpret_cast<float4*>(&ggc[0]) = *reinterpret_cast<const float4*>(g2 + ch);
  *reinterpret_cast<float4*>(&ggc[4]) = *reinterpret_cast<const float4*>(g2 + ch + 4);
  *reinterpret_cast<float4*>(&bbc[0]) = *reinterpret_cast<const float4*>(b2 + ch);
  *reinterpret_cast<float4*>(&bbc[4]) = *reinterpret_cast<const float4*>(b2 + ch + 4);
#pragma unroll
  for (int j = 0; j < 8; ++j) {
    a[j]  = (a[j] - mua) * rsa * gga[j] + bba[j];
    bq[j] = (bq[j] - mub) * rsb * ggb[j] + bbb[j];
    cq[j] = (cq[j] - muc) * rsc * ggc[j] + bbc[j];
  }
  float l0 = 0.f, l1 = 0.f, l2 = 0.f;
#pragma unroll
  for (int j = 0; j < 8; ++j) {
    l0 += a[j] * gws[ch + j] + bq[j] * gws[512 + ch + j] + cq[j] * gws[1024 + ch + j];
    l1 += a[j] * gws[1536 + ch + j] + bq[j] * gws[2048 + ch + j] + cq[j] * gws[2560 + ch + j];
    l2 += a[j] * gws[3072 + ch + j] + bq[j] * gws[3584 + ch + j] + cq[j] * gws[4096 + ch + j];
  }
#pragma unroll
  for (int o = 32; o > 0; o >>= 1) {
    l0 += __shfl_xor(l0, o); l1 += __shfl_xor(l1, o); l2 += __shfl_xor(l2, o);
  }
  l0 += gb[0]; l1 += gb[1]; l2 += gb[2];
  float m = fmaxf(l0, fmaxf(l1, l2));
  float e0 = __expf(l0 - m), e1 = __expf(l1 - m), e2 = __expf(l2 - m);
  float inv = 1.f / (e0 + e1 + e2);
  float w0 = e0 * inv, w1 = e1 * inv, w2 = e2 * inv;
  float r[8];
#pragma unroll
  for (int j = 0; j < 8; ++j) r[j] = w0 * a[j] + w1 * bq[j] + w2 * cq[j];
  *reinterpret_cast<float4*>(out + off) = *reinterpret_cast<const float4*>(&r[0]);
  *reinterpret_cast<float4*>(out + off + 4) = *reinterpret_cast<const float4*>(&r[4]);
}

// ===========================================================================
extern "C" void kernel_launch(void* const* d_in, const int* in_sizes, int n_in,
                              void* d_out, int out_size, void* d_ws, size_t ws_size,
                              hipStream_t stream) {
  (void)in_sizes; (void)n_in; (void)out_size;
  const float* x = (const float*)d_in[0];
  const float* dw = (const float*)d_in[1];
  const float* db = (const float*)d_in[2];
  // WB order: 0 wq_cr, 1 wq_d, 2 wk_d, 3 wq_c, 4 wk_c, 5 wv_d, 6 wv_c,
  //           7 wk_cr, 8 wv_cr
  WPtrs wp;
  wp.p[0] = (const float*)d_in[3];   // wq_cr
  wp.p[1] = (const float*)d_in[11];  // wq_d
  wp.p[2] = (const float*)d_in[13];  // wk_d
  wp.p[3] = (const float*)d_in[19];  // wq_c
  wp.p[4] = (const float*)d_in[21];  // wk_c
  wp.p[5] = (const float*)d_in[15];  // wv_d
  wp.p[6] = (const float*)d_in[23];  // wv_c
  wp.p[7] = (const float*)d_in[5];   // wk_cr
  wp.p[8] = (const float*)d_in[7];   // wv_cr
  const float* bq_cr = (const float*)d_in[4];
  const float* bk_cr = (const float*)d_in[6];
  const float* bv_cr = (const float*)d_in[8];
  const float* ln_cr_g = (const float*)d_in[9];
  const float* ln_cr_b = (const float*)d_in[10];
  const float* bq_d = (const float*)d_in[12];
  const float* bk_d = (const float*)d_in[14];
  const float* bv_d = (const float*)d_in[16];
  const float* ln_d_g = (const float*)d_in[17];
  const float* ln_d_b = (const float*)d_in[18];
  const float* bq_c = (const float*)d_in[20];
  const float* bk_c = (const float*)d_in[22];
  const float* bv_c = (const float*)d_in[24];
  const float* ln_c_g = (const float*)d_in[25];
  const float* ln_c_b = (const float*)d_in[26];
  const float* temp = (const float*)d_in[27];
  const float* gw = (const float*)d_in[28];
  const float* gb = (const float*)d_in[29];

  if (ws_size < 240000000ULL) return;  // plan needs ~226 MiB

  char* p = (char*)d_ws;
  auto alloc = [&](size_t bytes) {
    void* r = (void*)p;
    p += (bytes + 255) & ~(size_t)255;
    return r;
  };
  alloc(1024);                                                     // front pad
  unsigned short* XB  = (unsigned short*)alloc(16384L * 512 * 2);
  unsigned short* XD  = (unsigned short*)alloc(8192L * 512 * 2);
  unsigned short* WB  = (unsigned short*)alloc(9L * 262144 * 2);
  unsigned short* DWB = (unsigned short*)alloc(512L * 1536 * 2);
  unsigned short* QB  = (unsigned short*)alloc(16384L * 512 * 2);   // q_cr
  unsigned short* KB  = (unsigned short*)alloc(8192L * 512 * 2);    // k_cr
  unsigned short* VT  = (unsigned short*)alloc(512L * 16384 * 2);   // V^T, reused
  unsigned short* OUT0 = (unsigned short*)alloc(16384L * 512 * 2);
  unsigned short* OUT1 = (unsigned short*)alloc(16384L * 512 * 2);
  unsigned short* OUT2 = (unsigned short*)alloc(16384L * 512 * 2);
  unsigned short* QK2 = (unsigned short*)alloc(16384L * 1024 * 2);  // per-branch Q|K
  float* BC = (float*)alloc(2048 * 4);                              // bias concat
  unsigned short* SB = (unsigned short*)alloc(8L * 2048 * 2048 * 2);

  const float scale = 0.044194173824159216f;  // 1/sqrt(512)

  auto gemm = [&](const unsigned short* A, const unsigned short* Bm, void* Cm,
                  int M, int N, int K, int lda, int ldb, int ldc,
                  int batch, long sA, long sB, long sC,
                  const float* bias, float alpha, int mode) {
    dim3 g(M / 128, N / 128, batch);
    k_gemm<<<g, 256, 0, stream>>>(A, Bm, Cm, K, lda, ldb, ldc, sA, sB, sC,
                                  bias, alpha, mode);
  };
  auto gemm64 = [&](const unsigned short* A, const unsigned short* Bm, void* Cm,
                    int M, int N, int K, int lda, int ldb, int ldc,
                    int batch, long sA, long sB, long sC,
                    const float* bias, float alpha, int mode) {
    dim3 g(M / 128, N / 64, batch);
    k_gemm64<<<g, 256, 0, stream>>>(A, Bm, Cm, K, lda, ldb, ldc, sA, sB, sC,
                                    bias, alpha, mode);
  };
  auto gemm256 = [&](const unsigned short* A, const unsigned short* Bm,
                     unsigned short* Cm, int M, int N, int K,
                     int lda, int ldb, int ldc, int batch,
                     long sA, long sB, long sC, float alpha, const float* tp) {
    dim3 g(M / 256, N / 256, batch);
    k_gemm256<<<g, 512, 0, stream>>>(A, Bm, Cm, K, lda, ldb, ldc, sA, sB, sC, alpha, tp);
  };

  // ---- conversions & bias concats ----
  k_tobf16<<<8192, 256, 0, stream>>>(x, XB, 16384L * 512 / 4);
  k_tobf16w<<<2304, 256, 0, stream>>>(wp, WB);
  k_dwreorder<<<3072, 256, 0, stream>>>(dw, DWB);
  hipMemcpyAsync(BC,        bq_d, 512 * 4, hipMemcpyDeviceToDevice, stream);
  hipMemcpyAsync(BC + 512,  bk_d, 512 * 4, hipMemcpyDeviceToDevice, stream);
  hipMemcpyAsync(BC + 1024, bq_c, 512 * 4, hipMemcpyDeviceToDevice, stream);
  hipMemcpyAsync(BC + 1536, bk_c, 512 * 4, hipMemcpyDeviceToDevice, stream);

  // ---- downsample conv: strided-A GEMM (A = XB view, 16 MB, L3-resident) --
  gemm64(XB - 512, DWB, XD, 1024, 512, 1536, 1024, 1536, 512,
         8, 1048576L, 0, 524288L, db, 1.f, 1);
  k_fix<<<1024, 256, 0, stream>>>(XB, DWB, db, XD);   // exact t=0 rows

  // ================= branch cr (q from x, k/v from x_down) =================
  gemm(XB, WB + 0 * 262144L, QB, 16384, 512, 512, 512, 512, 512, 1, 0, 0, 0,
       bq_cr, 1.f, 1);
  gemm64(XD, WB + 7 * 262144L, KB, 8192, 512, 512, 512, 512, 512, 1, 0, 0, 0,
         bk_cr, 1.f, 1);
  gemm64(WB + 8 * 262144L, XD, VT, 512, 8192, 512, 512, 512, 8192, 1, 0, 0, 0,
         bv_cr, 1.f, 3);
  gemm256(QB, KB, SB, 2048, 1024, 512, 512, 512, 1024, 8,
          2048L * 512, 1024L * 512, 2048L * 1024, scale, nullptr);
  k_softmax1024<<<8192, 256, 0, stream>>>(SB);
  gemm(SB, VT, OUT0, 2048, 512, 1024, 1024, 8192, 512, 8,
       2048L * 1024, 1024, 2048L * 512, nullptr, 1.f, 1);

  // ================= branch d (standard attention over x) ==================
  gemm(XB, WB + 1 * 262144L, QK2, 16384, 1024, 512, 512, 512, 1024, 1, 0, 0, 0,
       BC, 1.f, 1);                                  // fused Q|K projection
  gemm64(WB + 5 * 262144L, XB, VT, 512, 16384, 512, 512, 512, 16384, 1, 0, 0, 0,
         bv_d, 1.f, 3);
  gemm256(QK2, QK2 + 512, SB, 2048, 2048, 512, 1024, 1024, 2048, 8,
          2048L * 1024, 2048L * 1024, 2048L * 2048, scale, nullptr);
  k_softmax<<<16384, 256, 0, stream>>>(SB, 2048);
  gemm(SB, VT, OUT1, 2048, 512, 2048, 2048, 16384, 512, 8,
       2048L * 2048, 2048, 2048L * 512, nullptr, 1.f, 1);

  // ================= branch c (cosine attention, learnable temp) ===========
  gemm(XB, WB + 3 * 262144L, QK2, 16384, 1024, 512, 512, 512, 1024, 1, 0, 0, 0,
       BC + 1024, 1.f, 1);                           // fused Q|K projection
  k_l2norm2<<<8192, 256, 0, stream>>>(QK2);          // Q and K halves together
  gemm64(WB + 6 * 262144L, XB, VT, 512, 16384, 512, 512, 512, 16384, 1, 0, 0, 0,
         bv_c, 1.f, 3);
  gemm256(QK2, QK2 + 512, SB, 2048, 2048, 512, 1024, 1024, 2048, 8,
          2048L * 1024, 2048L * 1024, 2048L * 2048, 1.f, temp);
  k_softmax<<<16384, 256, 0, stream>>>(SB, 2048);
  gemm(SB, VT, OUT2, 2048, 512, 2048, 2048, 16384, 512, 8,
       2048L * 2048, 2048, 2048L * 512, nullptr, 1.f, 1);

  // ============ fused LN(3 branches) + gating -> d_out ====================
  k_gate<<<4096, 256, 0, stream>>>(OUT0, OUT1, OUT2, gw, gb,
                                   ln_cr_g, ln_cr_b, ln_d_g, ln_d_b,
                                   ln_c_g, ln_c_b, (float*)d_out);
}

// Round 14
// 538.349 us; speedup vs baseline: 1.2336x; 1.0026x over previous
//
#include <hip/hip_runtime.h>

// ---------------------------------------------------------------------------
// Hybrid MRHA: conv-downsample + 3 attention branches + LN + gated fusion.
// k_gemm    : 128x128, BK=64, XOR-swizzled LDS, counted-vmcnt 2-barrier loop.
// k_gemm64  : 128x64 variant — V^T projections, conv, K-cr.
// k_gemm256 : 256x256, BK=32, scores only. NEW: depth-2 prefetch via
//             3-buffer ring (96 KB LDS), vmcnt(8) counted wait.
// k_gate    : LayerNorm (all 3 branches) + gating fusion in one pass.
// ---------------------------------------------------------------------------

typedef __attribute__((ext_vector_type(8))) __bf16 bf16x8;
typedef __attribute__((ext_vector_type(4))) float f32x4;

#define CDIM 512
#define TFULL 2048

#define GLL16(gp, lp)                                                        \
  __builtin_amdgcn_global_load_lds(                                          \
      (const __attribute__((address_space(1))) unsigned int*)(gp),           \
      (__attribute__((address_space(3))) unsigned int*)(lp), 16, 0, 0)

__device__ __forceinline__ unsigned short f2bf(float f) {
  unsigned u = __float_as_uint(f);
  u = (u + 0x7fffu + ((u >> 16) & 1u)) >> 16;   // round-to-nearest-even
  return (unsigned short)u;
}
__device__ __forceinline__ float bf2f(unsigned short h) {
  return __uint_as_float(((unsigned)h) << 16);
}

// ---------------- conversion: f32 -> bf16 (vec4) ----------------
__global__ __launch_bounds__(256)
void k_tobf16(const float* __restrict__ src, unsigned short* __restrict__ dst, long n4) {
  long i = (long)blockIdx.x * 256 + threadIdx.x;
  if (i >= n4) return;
  float4 f = reinterpret_cast<const float4*>(src)[i];
  unsigned short o4[4] = {f2bf(f.x), f2bf(f.y), f2bf(f.z), f2bf(f.w)};
  reinterpret_cast<uint2*>(dst)[i] = *reinterpret_cast<const uint2*>(o4);
}

// ---------------- batched weight conversion: 9 x 512x512 -> WB ----------
struct WPtrs { const float* p[9]; };
__global__ __launch_bounds__(256)
void k_tobf16w(WPtrs w, unsigned short* __restrict__ dst) {
  int idx = blockIdx.x * 256 + threadIdx.x;       // over 9*65536 vec4 units
  if (idx >= 9 * 65536) return;
  int m = idx >> 16, off = idx & 65535;
  float4 f = reinterpret_cast<const float4*>(w.p[m])[off];
  unsigned short o4[4] = {f2bf(f.x), f2bf(f.y), f2bf(f.z), f2bf(f.w)};
  reinterpret_cast<uint2*>(dst + (long)m * 262144)[off] = *reinterpret_cast<const uint2*>(o4);
}

// ---------------- dw [o][i][k] -> DWB bf16 [o][k*512+i] ----------------
__global__ __launch_bounds__(256)
void k_dwreorder(const float* __restrict__ dw, unsigned short* __restrict__ dwb) {
  int idx = blockIdx.x * 256 + threadIdx.x;           // over 512*1536
  if (idx >= 512 * 1536) return;
  int o = idx / 1536, rem = idx - o * 1536;
  int k = rem >> 9, i = rem & 511;
  dwb[idx] = f2bf(dw[(o * 512 + i) * 3 + k]);
}

// ---------------- conv row-0 fixup: one wave per (b,o), coalesced ---------
__global__ __launch_bounds__(256)
void k_fix(const unsigned short* __restrict__ XB, const unsigned short* __restrict__ DWB,
           const float* __restrict__ db, unsigned short* __restrict__ XD) {
  const int lane = threadIdx.x & 63, wave = threadIdx.x >> 6;
  const int idx = blockIdx.x * 4 + wave;      // 4096 = 8 batches * 512 outputs
  const int b = idx >> 9, o = idx & 511;
  const unsigned short* xr = XB + (long)b * TFULL * CDIM + lane * 16;  // rows 0,1
  const unsigned short* wr = DWB + (long)o * 1536 + 512 + lane * 16;   // taps 1,2
  float acc = 0.f;
  uint4 xv0 = *reinterpret_cast<const uint4*>(xr);
  uint4 xv1 = *reinterpret_cast<const uint4*>(xr + 8);
  uint4 wv0 = *reinterpret_cast<const uint4*>(wr);
  uint4 wv1 = *reinterpret_cast<const uint4*>(wr + 8);
  const unsigned short* xp0 = (const unsigned short*)&xv0;
  const unsigned short* xp1 = (const unsigned short*)&xv1;
  const unsigned short* wp0 = (const unsigned short*)&wv0;
  const unsigned short* wp1 = (const unsigned short*)&wv1;
#pragma unroll
  for (int j = 0; j < 8; ++j) acc += bf2f(xp0[j]) * bf2f(wp0[j]);
#pragma unroll
  for (int j = 0; j < 8; ++j) acc += bf2f(xp1[j]) * bf2f(wp1[j]);
#pragma unroll
  for (int off = 32; off > 0; off >>= 1) acc += __shfl_xor(acc, off);
  if (lane == 0) XD[(long)b * 1024 * 512 + o] = f2bf(acc + db[o]);
}

// ---------------- GEMM 128x128: C = alpha * A * B^T + bias ----------------
// mode 1: bf16 store, bias[col] | mode 3: bf16 store, bias[row]
__global__ __launch_bounds__(256)
void k_gemm(const unsigned short* __restrict__ A,
            const unsigned short* __restrict__ B,
            void* __restrict__ Cp,
            int K, int lda, int ldb, int ldc,
            long sA, long sB, long sC,
            const float* __restrict__ bias,
            float alpha, int mode) {
  const int gx = gridDim.x;
  const int nwg = gx * gridDim.y;
  int wg = blockIdx.x + gx * blockIdx.y;
  wg = (wg & 7) * (nwg >> 3) + (wg >> 3);
  const int tm0 = (wg % gx) * 128, tn0 = (wg / gx) * 128;
  const int bz = blockIdx.z;
  const unsigned short* Ag = A + (long)bz * sA;
  const unsigned short* Bg = B + (long)bz * sB;

  __shared__ __align__(16) unsigned short smem[32768];

  const int tid = threadIdx.x;
  const int lane = tid & 63;
  const int wave = tid >> 6;
  const int wm = (wave >> 1) * 64, wn = (wave & 1) * 64;
  const int lrow = lane & 15, kq = lane >> 4;

  f32x4 acc[4][4];
#pragma unroll
  for (int i = 0; i < 4; ++i)
#pragma unroll
    for (int j = 0; j < 4; ++j) acc[i][j] = f32x4{0.f, 0.f, 0.f, 0.f};

  const int sr = tid >> 3;                 // 0..31
  const int sj = (tid & 7) ^ (sr & 7);     // inverse-swizzled source slot
  const unsigned short* aSrc = Ag + (long)(tm0 + sr) * lda + sj * 8;
  const unsigned short* bSrc = Bg + (long)(tn0 + sr) * ldb + sj * 8;

  const int nt = K >> 6;

#define STAGE(kt_, buf_)                                                     \
  {                                                                          \
    unsigned short* aD = smem + (buf_) * 8192 + wave * 512;                  \
    unsigned short* bD = smem + 16384 + (buf_) * 8192 + wave * 512;          \
    _Pragma("unroll")                                                        \
    for (int rd = 0; rd < 4; ++rd) {                                         \
      GLL16(aSrc + (kt_) + (long)rd * 32 * lda, aD + rd * 2048);             \
      GLL16(bSrc + (kt_) + (long)rd * 32 * ldb, bD + rd * 2048);             \
    }                                                                        \
  }

  STAGE(0, 0);

  const int xr = (lrow & 7) << 3;
  for (int t = 0; t < nt; ++t) {
    if (t + 1 < nt) {
      STAGE((t + 1) << 6, (t + 1) & 1);    // prefetch stays in flight
      asm volatile("s_waitcnt vmcnt(8)" ::: "memory");   // my tile-t loads done
    } else {
      asm volatile("s_waitcnt vmcnt(0)" ::: "memory");   // final drain (once)
    }
    __builtin_amdgcn_s_barrier();          // everyone's tile-t loads done
    __builtin_amdgcn_sched_barrier(0);
    const unsigned short* As_ = smem + (t & 1) * 8192;
    const unsigned short* Bs_ = smem + 16384 + (t & 1) * 8192;
    bf16x8 af[4][2], bfv[4][2];
#pragma unroll
    for (int mi = 0; mi < 4; ++mi)
#pragma unroll
      for (int ks = 0; ks < 2; ++ks)
        af[mi][ks] = *reinterpret_cast<const bf16x8*>(
            &As_[(wm + mi * 16 + lrow) * 64 + ((ks * 32 + kq * 8) ^ xr)]);
#pragma unroll
    for (int ni = 0; ni < 4; ++ni)
#pragma unroll
      for (int ks = 0; ks < 2; ++ks)
        bfv[ni][ks] = *reinterpret_cast<const bf16x8*>(
            &Bs_[(wn + ni * 16 + lrow) * 64 + ((ks * 32 + kq * 8) ^ xr)]);
#pragma unroll
    for (int mi = 0; mi < 4; ++mi)
#pragma unroll
      for (int ni = 0; ni < 4; ++ni) {
        acc[mi][ni] = __builtin_amdgcn_mfma_f32_16x16x32_bf16(af[mi][0], bfv[ni][0], acc[mi][ni], 0, 0, 0);
        acc[mi][ni] = __builtin_amdgcn_mfma_f32_16x16x32_bf16(af[mi][1], bfv[ni][1], acc[mi][ni], 0, 0, 0);
      }
    __builtin_amdgcn_sched_barrier(0);
    if (t + 1 < nt) __builtin_amdgcn_s_barrier();  // reads done: next STAGE may overwrite
  }
#undef STAGE

  unsigned short* Cb = (unsigned short*)Cp + (long)bz * sC;
  if (mode == 1) {
#pragma unroll
    for (int mi = 0; mi < 4; ++mi) {
      int rg = tm0 + wm + mi * 16 + kq * 4;
#pragma unroll
      for (int ni = 0; ni < 4; ++ni) {
        int cg = tn0 + wn + ni * 16 + lrow;
        float bb = bias ? bias[cg] : 0.f;
        f32x4 v = acc[mi][ni];
#pragma unroll
        for (int r = 0; r < 4; ++r)
          Cb[(long)(rg + r) * ldc + cg] = f2bf(v[r] * alpha + bb);
      }
    }
  } else {                                 // mode 3: bias indexed by row
#pragma unroll
    for (int mi = 0; mi < 4; ++mi) {
      int rg = tm0 + wm + mi * 16 + kq * 4;
      float rb[4];
#pragma unroll
      for (int r = 0; r < 4; ++r) rb[r] = bias[rg + r];
#pragma unroll
      for (int ni = 0; ni < 4; ++ni) {
        int cg = tn0 + wn + ni * 16 + lrow;
        f32x4 v = acc[mi][ni];
#pragma unroll
        for (int r = 0; r < 4; ++r)
          Cb[(long)(rg + r) * ldc + cg] = f2bf(v[r] * alpha + rb[r]);
      }
    }
  }
}

// ---------------- GEMM 128x64 (L2-resident-operand shapes) ----------------
__global__ __launch_bounds__(256)
void k_gemm64(const unsigned short* __restrict__ A,
              const unsigned short* __restrict__ B,
              void* __restrict__ Cp,
              int K, int lda, int ldb, int ldc,
              long sA, long sB, long sC,
              const float* __restrict__ bias,
              float alpha, int mode) {
  const int gx = gridDim.x;
  const int nwg = gx * gridDim.y;
  int wg = blockIdx.x + gx * blockIdx.y;
  wg = (wg & 7) * (nwg >> 3) + (wg >> 3);
  const int tm0 = (wg % gx) * 128, tn0 = (wg / gx) * 64;
  const int bz = blockIdx.z;
  const unsigned short* Ag = A + (long)bz * sA;
  const unsigned short* Bg = B + (long)bz * sB;

  __shared__ __align__(16) unsigned short smem[24576];

  const int tid = threadIdx.x;
  const int lane = tid & 63;
  const int wave = tid >> 6;
  const int wm = (wave >> 1) * 64, wn = (wave & 1) * 32;
  const int lrow = lane & 15, kq = lane >> 4;

  f32x4 acc[4][2];
#pragma unroll
  for (int i = 0; i < 4; ++i)
#pragma unroll
    for (int j = 0; j < 2; ++j) acc[i][j] = f32x4{0.f, 0.f, 0.f, 0.f};

  const int sr = tid >> 3;                 // 0..31
  const int sj = (tid & 7) ^ (sr & 7);     // inverse-swizzled source slot
  const unsigned short* aSrc = Ag + (long)(tm0 + sr) * lda + sj * 8;
  const unsigned short* bSrc = Bg + (long)(tn0 + sr) * ldb + sj * 8;

  const int nt = K >> 6;

#define STAGE64(kt_, buf_)                                                   \
  {                                                                          \
    unsigned short* aD = smem + (buf_) * 8192 + wave * 512;                  \
    unsigned short* bD = smem + 16384 + (buf_) * 4096 + wave * 512;          \
    _Pragma("unroll")                                                        \
    for (int rd = 0; rd < 4; ++rd)                                           \
      GLL16(aSrc + (kt_) + (long)rd * 32 * lda, aD + rd * 2048);             \
    _Pragma("unroll")                                                        \
    for (int rd = 0; rd < 2; ++rd)                                           \
      GLL16(bSrc + (kt_) + (long)rd * 32 * ldb, bD + rd * 2048);             \
  }

  STAGE64(0, 0);

  const int xr = (lrow & 7) << 3;
  for (int t = 0; t < nt; ++t) {
    if (t + 1 < nt) {
      STAGE64((t + 1) << 6, (t + 1) & 1);
      asm volatile("s_waitcnt vmcnt(6)" ::: "memory");
    } else {
      asm volatile("s_waitcnt vmcnt(0)" ::: "memory");
    }
    __builtin_amdgcn_s_barrier();
    __builtin_amdgcn_sched_barrier(0);
    const unsigned short* As_ = smem + (t & 1) * 8192;
    const unsigned short* Bs_ = smem + 16384 + (t & 1) * 4096;
    bf16x8 af[4][2], bfv[2][2];
#pragma unroll
    for (int mi = 0; mi < 4; ++mi)
#pragma unroll
      for (int ks = 0; ks < 2; ++ks)
        af[mi][ks] = *reinterpret_cast<const bf16x8*>(
            &As_[(wm + mi * 16 + lrow) * 64 + ((ks * 32 + kq * 8) ^ xr)]);
#pragma unroll
    for (int ni = 0; ni < 2; ++ni)
#pragma unroll
      for (int ks = 0; ks < 2; ++ks)
        bfv[ni][ks] = *reinterpret_cast<const bf16x8*>(
            &Bs_[(wn + ni * 16 + lrow) * 64 + ((ks * 32 + kq * 8) ^ xr)]);
#pragma unroll
    for (int mi = 0; mi < 4; ++mi)
#pragma unroll
      for (int ni = 0; ni < 2; ++ni) {
        acc[mi][ni] = __builtin_amdgcn_mfma_f32_16x16x32_bf16(af[mi][0], bfv[ni][0], acc[mi][ni], 0, 0, 0);
        acc[mi][ni] = __builtin_amdgcn_mfma_f32_16x16x32_bf16(af[mi][1], bfv[ni][1], acc[mi][ni], 0, 0, 0);
      }
    __builtin_amdgcn_sched_barrier(0);
    if (t + 1 < nt) __builtin_amdgcn_s_barrier();
  }
#undef STAGE64

  unsigned short* Cb = (unsigned short*)Cp + (long)bz * sC;
  if (mode == 1) {
#pragma unroll
    for (int mi = 0; mi < 4; ++mi) {
      int rg = tm0 + wm + mi * 16 + kq * 4;
#pragma unroll
      for (int ni = 0; ni < 2; ++ni) {
        int cg = tn0 + wn + ni * 16 + lrow;
        float bb = bias ? bias[cg] : 0.f;
        f32x4 v = acc[mi][ni];
#pragma unroll
        for (int r = 0; r < 4; ++r)
          Cb[(long)(rg + r) * ldc + cg] = f2bf(v[r] * alpha + bb);
      }
    }
  } else {                                 // mode 3: bias indexed by row
#pragma unroll
    for (int mi = 0; mi < 4; ++mi) {
      int rg = tm0 + wm + mi * 16 + kq * 4;
      float rb[4];
#pragma unroll
      for (int r = 0; r < 4; ++r) rb[r] = bias[rg + r];
#pragma unroll
      for (int ni = 0; ni < 2; ++ni) {
        int cg = tn0 + wn + ni * 16 + lrow;
        f32x4 v = acc[mi][ni];
#pragma unroll
        for (int r = 0; r < 4; ++r)
          Cb[(long)(rg + r) * ldc + cg] = f2bf(v[r] * alpha + rb[r]);
      }
    }
  }
}

// ---------------- GEMM 256x256 (scores): C = alpha * A * B^T --------------
// BK=32, 3-buffer ring (96 KB LDS), depth-2 prefetch, counted vmcnt(8).
// Invariants: STAGE(t+2) overwrites slot (t+2)%3 = slot of tile t-1, whose
// reads completed before end-of-iter barrier of t-1 (all waves). vmcnt(8)
// before the consume barrier leaves tiles t+1,t+2 in flight; tile t landed.
// Requires M%256==0, N%256==0, K%32==0, (M/256)*(N/256)%8==0.
__global__ __launch_bounds__(512)
void k_gemm256(const unsigned short* __restrict__ A,
               const unsigned short* __restrict__ B,
               unsigned short* __restrict__ C,
               int K, int lda, int ldb, int ldc,
               long sA, long sB, long sC,
               float alpha, const float* __restrict__ tempPtr) {
  const int gx = gridDim.x;
  const int nwg = gx * gridDim.y;
  int wg = blockIdx.x + gx * blockIdx.y;
  wg = (wg & 7) * (nwg >> 3) + (wg >> 3);
  const int tm0 = (wg % gx) * 256, tn0 = (wg / gx) * 256;
  const unsigned short* Ag = A + (long)blockIdx.z * sA;
  const unsigned short* Bg = B + (long)blockIdx.z * sB;

  // 96 KiB: A ring 3 x 8192 elems, then B ring 3 x 8192
  __shared__ __align__(16) unsigned short smem[49152];

  const int tid = threadIdx.x;
  const int lane = tid & 63;
  const int wave = tid >> 6;               // 0..7
  const int wm = (wave >> 2) * 128, wn = (wave & 3) * 64;
  const int lrow = lane & 15, kq = lane >> 4;

  f32x4 acc[8][4];
#pragma unroll
  for (int i = 0; i < 8; ++i)
#pragma unroll
    for (int j = 0; j < 4; ++j) acc[i][j] = f32x4{0.f, 0.f, 0.f, 0.f};

  const int srow = lane >> 2;                          // 0..15
  const int sslot = (lane & 3) ^ ((lane >> 3) & 3);    // inverse swizzle
  const unsigned short* aS0 = Ag + (long)(tm0 + wave * 16 + srow) * lda + sslot * 8;
  const unsigned short* aS1 = aS0 + 128L * lda;
  const unsigned short* bS0 = Bg + (long)(tn0 + wave * 16 + srow) * ldb + sslot * 8;
  const unsigned short* bS1 = bS0 + 128L * ldb;

  const int nt = K >> 5;

#define STAGE256(kt_, buf_)                                                  \
  {                                                                          \
    unsigned short* aD = smem + (buf_) * 8192 + wave * 512;                  \
    unsigned short* bD = smem + 24576 + (buf_) * 8192 + wave * 512;          \
    GLL16(aS0 + (kt_), aD);                                                  \
    GLL16(aS1 + (kt_), aD + 4096);                                           \
    GLL16(bS0 + (kt_), bD);                                                  \
    GLL16(bS1 + (kt_), bD + 4096);                                           \
  }

  STAGE256(0, 0);                          // prologue: tiles 0,1
  if (nt > 1) STAGE256(32, 1);

  const int xr = ((lrow >> 1) & 3) << 3;   // read-side elem XOR
  int s = 0;                               // t % 3
  for (int t = 0; t < nt; ++t) {
    if (t + 2 < nt) {
      int sp2 = s + 2; if (sp2 >= 3) sp2 -= 3;
      STAGE256((t + 2) << 5, sp2);         // depth-2 prefetch
      asm volatile("s_waitcnt vmcnt(8)" ::: "memory");   // tile t landed (mine)
    } else if (t + 1 < nt) {
      asm volatile("s_waitcnt vmcnt(4)" ::: "memory");   // tile t landed
    } else {
      asm volatile("s_waitcnt vmcnt(0)" ::: "memory");   // final drain
    }
    __builtin_amdgcn_s_barrier();          // tile t landed (everyone)
    __builtin_amdgcn_sched_barrier(0);
    const unsigned short* As_ = smem + s * 8192;
    const unsigned short* Bs_ = smem + 24576 + s * 8192;
    bf16x8 bfv[4];
#pragma unroll
    for (int ni = 0; ni < 4; ++ni)
      bfv[ni] = *reinterpret_cast<const bf16x8*>(
          &Bs_[(wn + ni * 16 + lrow) * 32 + ((kq * 8) ^ xr)]);
#pragma unroll
    for (int mi = 0; mi < 8; ++mi) {
      bf16x8 af = *reinterpret_cast<const bf16x8*>(
          &As_[(wm + mi * 16 + lrow) * 32 + ((kq * 8) ^ xr)]);
#pragma unroll
      for (int ni = 0; ni < 4; ++ni)
        acc[mi][ni] = __builtin_amdgcn_mfma_f32_16x16x32_bf16(af, bfv[ni], acc[mi][ni], 0, 0, 0);
    }
    __builtin_amdgcn_sched_barrier(0);
    if (t + 1 < nt) __builtin_amdgcn_s_barrier();  // reads done: future STAGE may overwrite
    ++s; if (s >= 3) s = 0;
  }
#undef STAGE256

  if (tempPtr) alpha = 1.0f / fmaxf(*tempPtr, 0.01f);

  C += (long)blockIdx.z * sC;
#pragma unroll
  for (int mi = 0; mi < 8; ++mi) {
    int rg = tm0 + wm + mi * 16 + kq * 4;
#pragma unroll
    for (int ni = 0; ni < 4; ++ni) {
      int cg = tn0 + wn + ni * 16 + lrow;
      f32x4 v = acc[mi][ni];
#pragma unroll
      for (int r = 0; r < 4; ++r)
        C[(long)(rg + r) * ldc + cg] = f2bf(v[r] * alpha);
    }
  }
}

// ---------------- row softmax, bf16 in-place, cols == 2048 ----------------
__global__ __launch_bounds__(256)
void k_softmax(unsigned short* __restrict__ S, int cols) {
  const long base = (long)blockIdx.x * cols;
  const int tid = threadIdx.x, lane = tid & 63, wave = tid >> 6;
  const int nv = cols >> 3;
  float f[8];
  float mx = -3.0e38f;
  if (tid < nv) {
    uint4 v = *reinterpret_cast<const uint4*>(S + base + tid * 8);
    const unsigned short* pv = (const unsigned short*)&v;
#pragma unroll
    for (int j = 0; j < 8; ++j) { f[j] = bf2f(pv[j]); mx = fmaxf(mx, f[j]); }
  }
  __shared__ float rmax[4], rsum[4];
#pragma unroll
  for (int o = 32; o > 0; o >>= 1) mx = fmaxf(mx, __shfl_down(mx, o));
  if (lane == 0) rmax[wave] = mx;
  __syncthreads();
  mx = fmaxf(fmaxf(rmax[0], rmax[1]), fmaxf(rmax[2], rmax[3]));
  float sum = 0.f;
  if (tid < nv) {
#pragma unroll
    for (int j = 0; j < 8; ++j) { f[j] = __expf(f[j] - mx); sum += f[j]; }
  }
#pragma unroll
  for (int o = 32; o > 0; o >>= 1) sum += __shfl_down(sum, o);
  if (lane == 0) rsum[wave] = sum;
  __syncthreads();
  const float inv = 1.0f / (rsum[0] + rsum[1] + rsum[2] + rsum[3]);
  if (tid < nv) {
    unsigned short o8[8];
#pragma unroll
    for (int j = 0; j < 8; ++j) o8[j] = f2bf(f[j] * inv);
    *reinterpret_cast<uint4*>(S + base + tid * 8) = *reinterpret_cast<const uint4*>(o8);
  }
}

// ---------------- row softmax cols=1024: 2 rows/block, all lanes live -----
__global__ __launch_bounds__(256)
void k_softmax1024(unsigned short* __restrict__ S) {
  const int tid = threadIdx.x;
  const int half = tid >> 7, ht = tid & 127;       // row-pair half, idx in half
  const int lane = tid & 63, wave = tid >> 6;      // waves {0,1}=row0 {2,3}=row1
  const long base = ((long)blockIdx.x * 2 + half) * 1024;
  uint4 v = *reinterpret_cast<const uint4*>(S + base + ht * 8);
  const unsigned short* pv = (const unsigned short*)&v;
  float f[8];
  float mx = -3.0e38f;
#pragma unroll
  for (int j = 0; j < 8; ++j) { f[j] = bf2f(pv[j]); mx = fmaxf(mx, f[j]); }
  __shared__ float rmax[4], rsum[4];
#pragma unroll
  for (int o = 32; o > 0; o >>= 1) mx = fmaxf(mx, __shfl_down(mx, o));
  if (lane == 0) rmax[wave] = mx;
  __syncthreads();
  mx = fmaxf(rmax[half * 2], rmax[half * 2 + 1]);
  float sum = 0.f;
#pragma unroll
  for (int j = 0; j < 8; ++j) { f[j] = __expf(f[j] - mx); sum += f[j]; }
#pragma unroll
  for (int o = 32; o > 0; o >>= 1) sum += __shfl_down(sum, o);
  if (lane == 0) rsum[wave] = sum;
  __syncthreads();
  const float inv = 1.0f / (rsum[half * 2] + rsum[half * 2 + 1]);
  unsigned short o8[8];
#pragma unroll
  for (int j = 0; j < 8; ++j) o8[j] = f2bf(f[j] * inv);
  *reinterpret_cast<uint4*>(S + base + ht * 8) = *reinterpret_cast<const uint4*>(o8);
}

// ---------------- L2-normalize: 32768 rows of 512 in QK2 [.][1024] --------
__global__ __launch_bounds__(256)
void k_l2norm2(unsigned short* __restrict__ Q) {
  const int lane = threadIdx.x & 63, wave = threadIdx.x >> 6;
  const int idx = blockIdx.x * 4 + wave;            // 0..32767
  unsigned short* p = Q + (long)(idx >> 1) * 1024 + (idx & 1) * 512 + lane * 8;
  uint4 v = *reinterpret_cast<const uint4*>(p);
  const unsigned short* pv = (const unsigned short*)&v;
  float f[8]; float q = 0.f;
#pragma unroll
  for (int j = 0; j < 8; ++j) { f[j] = bf2f(pv[j]); q += f[j] * f[j]; }
#pragma unroll
  for (int o = 32; o > 0; o >>= 1) q += __shfl_xor(q, o);
  float sc = 1.0f / (sqrtf(q) + 1e-8f);
  unsigned short o8[8];
#pragma unroll
  for (int j = 0; j < 8; ++j) o8[j] = f2bf(f[j] * sc);
  *reinterpret_cast<uint4*>(p) = *reinterpret_cast<const uint4*>(o8);
}

// -------- fused LayerNorm(3 branches) + gating: one wave per position -----
__global__ __launch_bounds__(256)
void k_gate(const unsigned short* __restrict__ o0, const unsigned short* __restrict__ o1,
            const unsigned short* __restrict__ o2, const float* __restrict__ gw,
            const float* __restrict__ gb,
            const float* __restrict__ g0, const float* __restrict__ b0,
            const float* __restrict__ g1, const float* __restrict__ b1,
            const float* __restrict__ g2, const float* __restrict__ b2,
            float* __restrict__ out) {
  __shared__ float gws[3 * 1536];
  for (int i = threadIdx.x; i < 3 * 1536; i += 256) gws[i] = gw[i];
  __syncthreads();
  const int lane = threadIdx.x & 63, wave = threadIdx.x >> 6;
  const long pos = (long)blockIdx.x * 4 + wave;
  const long off = pos * CDIM + lane * 8;
  float a[8], bq[8], cq[8];
  {
    uint4 va = *reinterpret_cast<const uint4*>(o0 + off);
    uint4 vb = *reinterpret_cast<const uint4*>(o1 + off);
    uint4 vc = *reinterpret_cast<const uint4*>(o2 + off);
    const unsigned short* pa = (const unsigned short*)&va;
    const unsigned short* pb = (const unsigned short*)&vb;
    const unsigned short* pc = (const unsigned short*)&vc;
#pragma unroll
    for (int j = 0; j < 8; ++j) { a[j] = bf2f(pa[j]); bq[j] = bf2f(pb[j]); cq[j] = bf2f(pc[j]); }
  }
  float sa = 0.f, qa = 0.f, sb = 0.f, qb = 0.f, sc2 = 0.f, qc = 0.f;
#pragma unroll
  for (int j = 0; j < 8; ++j) {
    sa += a[j];  qa += a[j] * a[j];
    sb += bq[j]; qb += bq[j] * bq[j];
    sc2 += cq[j]; qc += cq[j] * cq[j];
  }
#pragma unroll
  for (int o = 32; o > 0; o >>= 1) {
    sa += __shfl_xor(sa, o);  qa += __shfl_xor(qa, o);
    sb += __shfl_xor(sb, o);  qb += __shfl_xor(qb, o);
    sc2 += __shfl_xor(sc2, o); qc += __shfl_xor(qc, o);
  }
  const float inv512 = 1.f / 512.f;
  float mua = sa * inv512, rsa = rsqrtf(qa * inv512 - mua * mua + 1e-5f);
  float mub = sb * inv512, rsb = rsqrtf(qb * inv512 - mub * mub + 1e-5f);
  float muc = sc2 * inv512, rsc = rsqrtf(qc * inv512 - muc * muc + 1e-5f);
  const int ch = lane * 8;
  float gga[8], bba[8], ggb[8], bbb[8], ggc[8], bbc[8];
  *reinterpret_cast<float4*>(&gga[0]) = *reinterpret_cast<const float4*>(g0 + ch);
  *reinterpret_cast<float4*>(&gga[4]) = *reinterpret_cast<const float4*>(g0 + ch + 4);
  *reinterpret_cast<float4*>(&bba[0]) = *reinterpret_cast<const float4*>(b0 + ch);
  *reinterpret_cast<float4*>(&bba[4]) = *reinterpret_cast<const float4*>(b0 + ch + 4);
  *reinterpret_cast<float4*>(&ggb[0]) = *reinterpret_cast<const float4*>(g1 + ch);
  *reinterpret_cast<float4*>(&ggb[4]) = *reinterpret_cast<const float4*>(g1 + ch + 4);
  *reinterpret_cast<float4*>(&bbb[0]) = *reinterpret_cast<const float4*>(b1 + ch);
  *reinterpret_cast<float4*>(&bbb[4]) = *reinterpret_cast<const float4*>(b1 + ch + 4);
  *reinterpret_cast<float4*>(&ggc[0]) = *reinterpret_cast<const float4*>(g2 + ch);
  *reinterpret_cast<float4*>(&ggc[4]) = *reinterpret_cast<const float4*>(g2 + ch + 4);
  *reinterpret_cast<float4*>(&bbc[0]) = *reinterpret_cast<const float4*>(b2 + ch);
  *reinterpret_cast<float4*>(&bbc[4]) = *reinterpret_cast<const float4*>(b2 + ch + 4);
#pragma unroll
  for (int j = 0; j < 8; ++j) {
    a[j]  = (a[j] - mua) * rsa * gga[j] + bba[j];
    bq[j] = (bq[j] - mub) * rsb * ggb[j] + bbb[j];
    cq[j] = (cq[j] - muc) * rsc * ggc[j] + bbc[j];
  }
  float l0 = 0.f, l1 = 0.f, l2 = 0.f;
#pragma unroll
  for (int j = 0; j < 8; ++j) {
    l0 += a[j] * gws[ch + j] + bq[j] * gws[512 + ch + j] + cq[j] * gws[1024 + ch + j];
    l1 += a[j] * gws[1536 + ch + j] + bq[j] * gws[2048 + ch + j] + cq[j] * gws[2560 + ch + j];
    l2 += a[j] * gws[3072 + ch + j] + bq[j] * gws[3584 + ch + j] + cq[j] * gws[4096 + ch + j];
  }
#pragma unroll
  for (int o = 32; o > 0; o >>= 1) {
    l0 += __shfl_xor(l0, o); l1 += __shfl_xor(l1, o); l2 += __shfl_xor(l2, o);
  }
  l0 += gb[0]; l1 += gb[1]; l2 += gb[2];
  float m = fmaxf(l0, fmaxf(l1, l2));
  float e0 = __expf(l0 - m), e1 = __expf(l1 - m), e2 = __expf(l2 - m);
  float inv = 1.f / (e0 + e1 + e2);
  float w0 = e0 * inv, w1 = e1 * inv, w2 = e2 * inv;
  float r[8];
#pragma unroll
  for (int j = 0; j < 8; ++j) r[j] = w0 * a[j] + w1 * bq[j] + w2 * cq[j];
  *reinterpret_cast<float4*>(out + off) = *reinterpret_cast<const float4*>(&r[0]);
  *reinterpret_cast<float4*>(out + off + 4) = *reinterpret_cast<const float4*>(&r[4]);
}

// ===========================================================================
extern "C" void kernel_launch(void* const* d_in, const int* in_sizes, int n_in,
                              void* d_out, int out_size, void* d_ws, size_t ws_size,
                              hipStream_t stream) {
  (void)in_sizes; (void)n_in; (void)out_size;
  const float* x = (const float*)d_in[0];
  const float* dw = (const float*)d_in[1];
  const float* db = (const float*)d_in[2];
  WPtrs wp;
  wp.p[0] = (const float*)d_in[3];   // wq_cr
  wp.p[1] = (const float*)d_in[11];  // wq_d
  wp.p[2] = (const float*)d_in[13];  // wk_d
  wp.p[3] = (const float*)d_in[19];  // wq_c
  wp.p[4] = (const float*)d_in[21];  // wk_c
  wp.p[5] = (const float*)d_in[15];  // wv_d
  wp.p[6] = (const float*)d_in[23];  // wv_c
  wp.p[7] = (const float*)d_in[5];   // wk_cr
  wp.p[8] = (const float*)d_in[7];   // wv_cr
  const float* bq_cr = (const float*)d_in[4];
  const float* bk_cr = (const float*)d_in[6];
  const float* bv_cr = (const float*)d_in[8];
  const float* ln_cr_g = (const float*)d_in[9];
  const float* ln_cr_b = (const float*)d_in[10];
  const float* bq_d = (const float*)d_in[12];
  const float* bk_d = (const float*)d_in[14];
  const float* bv_d = (const float*)d_in[16];
  const float* ln_d_g = (const float*)d_in[17];
  const float* ln_d_b = (const float*)d_in[18];
  const float* bq_c = (const float*)d_in[20];
  const float* bk_c = (const float*)d_in[22];
  const float* bv_c = (const float*)d_in[24];
  const float* ln_c_g = (const float*)d_in[25];
  const float* ln_c_b = (const float*)d_in[26];
  const float* temp = (const float*)d_in[27];
  const float* gw = (const float*)d_in[28];
  const float* gb = (const float*)d_in[29];

  if (ws_size < 240000000ULL) return;  // plan needs ~226 MiB

  char* p = (char*)d_ws;
  auto alloc = [&](size_t bytes) {
    void* r = (void*)p;
    p += (bytes + 255) & ~(size_t)255;
    return r;
  };
  alloc(1024);                                                     // front pad
  unsigned short* XB  = (unsigned short*)alloc(16384L * 512 * 2);
  unsigned short* XD  = (unsigned short*)alloc(8192L * 512 * 2);
  unsigned short* WB  = (unsigned short*)alloc(9L * 262144 * 2);
  unsigned short* DWB = (unsigned short*)alloc(512L * 1536 * 2);
  unsigned short* QB  = (unsigned short*)alloc(16384L * 512 * 2);   // q_cr
  unsigned short* KB  = (unsigned short*)alloc(8192L * 512 * 2);    // k_cr
  unsigned short* VT  = (unsigned short*)alloc(512L * 16384 * 2);   // V^T, reused
  unsigned short* OUT0 = (unsigned short*)alloc(16384L * 512 * 2);
  unsigned short* OUT1 = (unsigned short*)alloc(16384L * 512 * 2);
  unsigned short* OUT2 = (unsigned short*)alloc(16384L * 512 * 2);
  unsigned short* QK2 = (unsigned short*)alloc(16384L * 1024 * 2);  // per-branch Q|K
  float* BC = (float*)alloc(2048 * 4);                              // bias concat
  unsigned short* SB = (unsigned short*)alloc(8L * 2048 * 2048 * 2);

  const float scale = 0.044194173824159216f;  // 1/sqrt(512)

  auto gemm = [&](const unsigned short* A, const unsigned short* Bm, void* Cm,
                  int M, int N, int K, int lda, int ldb, int ldc,
                  int batch, long sA, long sB, long sC,
                  const float* bias, float alpha, int mode) {
    dim3 g(M / 128, N / 128, batch);
    k_gemm<<<g, 256, 0, stream>>>(A, Bm, Cm, K, lda, ldb, ldc, sA, sB, sC,
                                  bias, alpha, mode);
  };
  auto gemm64 = [&](const unsigned short* A, const unsigned short* Bm, void* Cm,
                    int M, int N, int K, int lda, int ldb, int ldc,
                    int batch, long sA, long sB, long sC,
                    const float* bias, float alpha, int mode) {
    dim3 g(M / 128, N / 64, batch);
    k_gemm64<<<g, 256, 0, stream>>>(A, Bm, Cm, K, lda, ldb, ldc, sA, sB, sC,
                                    bias, alpha, mode);
  };
  auto gemm256 = [&](const unsigned short* A, const unsigned short* Bm,
                     unsigned short* Cm, int M, int N, int K,
                     int lda, int ldb, int ldc, int batch,
                     long sA, long sB, long sC, float alpha, const float* tp) {
    dim3 g(M / 256, N / 256, batch);
    k_gemm256<<<g, 512, 0, stream>>>(A, Bm, Cm, K, lda, ldb, ldc, sA, sB, sC, alpha, tp);
  };

  // ---- conversions & bias concats ----
  k_tobf16<<<8192, 256, 0, stream>>>(x, XB, 16384L * 512 / 4);
  k_tobf16w<<<2304, 256, 0, stream>>>(wp, WB);
  k_dwreorder<<<3072, 256, 0, stream>>>(dw, DWB);
  hipMemcpyAsync(BC,        bq_d, 512 * 4, hipMemcpyDeviceToDevice, stream);
  hipMemcpyAsync(BC + 512,  bk_d, 512 * 4, hipMemcpyDeviceToDevice, stream);
  hipMemcpyAsync(BC + 1024, bq_c, 512 * 4, hipMemcpyDeviceToDevice, stream);
  hipMemcpyAsync(BC + 1536, bk_c, 512 * 4, hipMemcpyDeviceToDevice, stream);

  // ---- downsample conv: strided-A GEMM ----
  gemm64(XB - 512, DWB, XD, 1024, 512, 1536, 1024, 1536, 512,
         8, 1048576L, 0, 524288L, db, 1.f, 1);
  k_fix<<<1024, 256, 0, stream>>>(XB, DWB, db, XD);   // exact t=0 rows

  // ================= branch cr (q from x, k/v from x_down) =================
  gemm(XB, WB + 0 * 262144L, QB, 16384, 512, 512, 512, 512, 512, 1, 0, 0, 0,
       bq_cr, 1.f, 1);
  gemm64(XD, WB + 7 * 262144L, KB, 8192, 512, 512, 512, 512, 512, 1, 0, 0, 0,
         bk_cr, 1.f, 1);
  gemm64(WB + 8 * 262144L, XD, VT, 512, 8192, 512, 512, 512, 8192, 1, 0, 0, 0,
         bv_cr, 1.f, 3);
  gemm256(QB, KB, SB, 2048, 1024, 512, 512, 512, 1024, 8,
          2048L * 512, 1024L * 512, 2048L * 1024, scale, nullptr);
  k_softmax1024<<<8192, 256, 0, stream>>>(SB);
  gemm(SB, VT, OUT0, 2048, 512, 1024, 1024, 8192, 512, 8,
       2048L * 1024, 1024, 2048L * 512, nullptr, 1.f, 1);

  // ================= branch d (standard attention over x) ==================
  gemm(XB, WB + 1 * 262144L, QK2, 16384, 1024, 512, 512, 512, 1024, 1, 0, 0, 0,
       BC, 1.f, 1);                                  // fused Q|K projection
  gemm64(WB + 5 * 262144L, XB, VT, 512, 16384, 512, 512, 512, 16384, 1, 0, 0, 0,
         bv_d, 1.f, 3);
  gemm256(QK2, QK2 + 512, SB, 2048, 2048, 512, 1024, 1024, 2048, 8,
          2048L * 1024, 2048L * 1024, 2048L * 2048, scale, nullptr);
  k_softmax<<<16384, 256, 0, stream>>>(SB, 2048);
  gemm(SB, VT, OUT1, 2048, 512, 2048, 2048, 16384, 512, 8,
       2048L * 2048, 2048, 2048L * 512, nullptr, 1.f, 1);

  // ================= branch c (cosine attention, learnable temp) ===========
  gemm(XB, WB + 3 * 262144L, QK2, 16384, 1024, 512, 512, 512, 1024, 1, 0, 0, 0,
       BC + 1024, 1.f, 1);                           // fused Q|K projection
  k_l2norm2<<<8192, 256, 0, stream>>>(QK2);          // Q and K halves together
  gemm64(WB + 6 * 262144L, XB, VT, 512, 16384, 512, 512, 512, 16384, 1, 0, 0, 0,
         bv_c, 1.f, 3);
  gemm256(QK2, QK2 + 512, SB, 2048, 2048, 512, 1024, 1024, 2048, 8,
          2048L * 1024, 2048L * 1024, 2048L * 2048, 1.f, temp);
  k_softmax<<<16384, 256, 0, stream>>>(SB, 2048);
  gemm(SB, VT, OUT2, 2048, 512, 2048, 2048, 16384, 512, 8,
       2048L * 2048, 2048, 2048L * 512, nullptr, 1.f, 1);

  // ============ fused LN(3 branches) + gating -> d_out ====================
  k_gate<<<4096, 256, 0, stream>>>(OUT0, OUT1, OUT2, gw, gb,
                                   ln_cr_g, ln_cr_b, ln_d_g, ln_d_b,
                                   ln_c_g, ln_c_b, (float*)d_out);
}

// Round 15
// 536.185 us; speedup vs baseline: 1.2386x; 1.0040x over previous
//
#include <hip/hip_runtime.h>

// ---------------------------------------------------------------------------
// Hybrid MRHA: conv-downsample + 3 attention branches + LN + gated fusion.
// k_gemm    : 128x128, BK=64, XOR-swizzled LDS, counted-vmcnt 2-barrier loop.
// k_gemm64  : 128x64 variant — V^T projections, conv, K-cr.
// k_gemm256 : 256x256, BK=32, 2-buffer counted-vmcnt (depth-2 ring was
//             measured neutral; reverted). Scores only.
// k_gate    : LayerNorm (all 3 branches) + gating fusion in one pass.
// V^T d+c branches fused into ONE 1024x16384 projection (adjacent weights).
// ---------------------------------------------------------------------------

typedef __attribute__((ext_vector_type(8))) __bf16 bf16x8;
typedef __attribute__((ext_vector_type(4))) float f32x4;

#define CDIM 512
#define TFULL 2048

#define GLL16(gp, lp)                                                        \
  __builtin_amdgcn_global_load_lds(                                          \
      (const __attribute__((address_space(1))) unsigned int*)(gp),           \
      (__attribute__((address_space(3))) unsigned int*)(lp), 16, 0, 0)

__device__ __forceinline__ unsigned short f2bf(float f) {
  unsigned u = __float_as_uint(f);
  u = (u + 0x7fffu + ((u >> 16) & 1u)) >> 16;   // round-to-nearest-even
  return (unsigned short)u;
}
__device__ __forceinline__ float bf2f(unsigned short h) {
  return __uint_as_float(((unsigned)h) << 16);
}

// ---------------- conversion: f32 -> bf16 (vec4) ----------------
__global__ __launch_bounds__(256)
void k_tobf16(const float* __restrict__ src, unsigned short* __restrict__ dst, long n4) {
  long i = (long)blockIdx.x * 256 + threadIdx.x;
  if (i >= n4) return;
  float4 f = reinterpret_cast<const float4*>(src)[i];
  unsigned short o4[4] = {f2bf(f.x), f2bf(f.y), f2bf(f.z), f2bf(f.w)};
  reinterpret_cast<uint2*>(dst)[i] = *reinterpret_cast<const uint2*>(o4);
}

// ---------------- batched weight conversion: 9 x 512x512 -> WB ----------
struct WPtrs { const float* p[9]; };
__global__ __launch_bounds__(256)
void k_tobf16w(WPtrs w, unsigned short* __restrict__ dst) {
  int idx = blockIdx.x * 256 + threadIdx.x;       // over 9*65536 vec4 units
  if (idx >= 9 * 65536) return;
  int m = idx >> 16, off = idx & 65535;
  float4 f = reinterpret_cast<const float4*>(w.p[m])[off];
  unsigned short o4[4] = {f2bf(f.x), f2bf(f.y), f2bf(f.z), f2bf(f.w)};
  reinterpret_cast<uint2*>(dst + (long)m * 262144)[off] = *reinterpret_cast<const uint2*>(o4);
}

// ---------------- dw [o][i][k] -> DWB bf16 [o][k*512+i] ----------------
__global__ __launch_bounds__(256)
void k_dwreorder(const float* __restrict__ dw, unsigned short* __restrict__ dwb) {
  int idx = blockIdx.x * 256 + threadIdx.x;           // over 512*1536
  if (idx >= 512 * 1536) return;
  int o = idx / 1536, rem = idx - o * 1536;
  int k = rem >> 9, i = rem & 511;
  dwb[idx] = f2bf(dw[(o * 512 + i) * 3 + k]);
}

// ---------------- conv row-0 fixup: one wave per (b,o), coalesced ---------
__global__ __launch_bounds__(256)
void k_fix(const unsigned short* __restrict__ XB, const unsigned short* __restrict__ DWB,
           const float* __restrict__ db, unsigned short* __restrict__ XD) {
  const int lane = threadIdx.x & 63, wave = threadIdx.x >> 6;
  const int idx = blockIdx.x * 4 + wave;      // 4096 = 8 batches * 512 outputs
  const int b = idx >> 9, o = idx & 511;
  const unsigned short* xr = XB + (long)b * TFULL * CDIM + lane * 16;  // rows 0,1
  const unsigned short* wr = DWB + (long)o * 1536 + 512 + lane * 16;   // taps 1,2
  float acc = 0.f;
  uint4 xv0 = *reinterpret_cast<const uint4*>(xr);
  uint4 xv1 = *reinterpret_cast<const uint4*>(xr + 8);
  uint4 wv0 = *reinterpret_cast<const uint4*>(wr);
  uint4 wv1 = *reinterpret_cast<const uint4*>(wr + 8);
  const unsigned short* xp0 = (const unsigned short*)&xv0;
  const unsigned short* xp1 = (const unsigned short*)&xv1;
  const unsigned short* wp0 = (const unsigned short*)&wv0;
  const unsigned short* wp1 = (const unsigned short*)&wv1;
#pragma unroll
  for (int j = 0; j < 8; ++j) acc += bf2f(xp0[j]) * bf2f(wp0[j]);
#pragma unroll
  for (int j = 0; j < 8; ++j) acc += bf2f(xp1[j]) * bf2f(wp1[j]);
#pragma unroll
  for (int off = 32; off > 0; off >>= 1) acc += __shfl_xor(acc, off);
  if (lane == 0) XD[(long)b * 1024 * 512 + o] = f2bf(acc + db[o]);
}

// ---------------- GEMM 128x128: C = alpha * A * B^T + bias ----------------
// mode 1: bf16 store, bias[col] | mode 3: bf16 store, bias[row]
__global__ __launch_bounds__(256)
void k_gemm(const unsigned short* __restrict__ A,
            const unsigned short* __restrict__ B,
            void* __restrict__ Cp,
            int K, int lda, int ldb, int ldc,
            long sA, long sB, long sC,
            const float* __restrict__ bias,
            float alpha, int mode) {
  const int gx = gridDim.x;
  const int nwg = gx * gridDim.y;
  int wg = blockIdx.x + gx * blockIdx.y;
  wg = (wg & 7) * (nwg >> 3) + (wg >> 3);
  const int tm0 = (wg % gx) * 128, tn0 = (wg / gx) * 128;
  const int bz = blockIdx.z;
  const unsigned short* Ag = A + (long)bz * sA;
  const unsigned short* Bg = B + (long)bz * sB;

  __shared__ __align__(16) unsigned short smem[32768];

  const int tid = threadIdx.x;
  const int lane = tid & 63;
  const int wave = tid >> 6;
  const int wm = (wave >> 1) * 64, wn = (wave & 1) * 64;
  const int lrow = lane & 15, kq = lane >> 4;

  f32x4 acc[4][4];
#pragma unroll
  for (int i = 0; i < 4; ++i)
#pragma unroll
    for (int j = 0; j < 4; ++j) acc[i][j] = f32x4{0.f, 0.f, 0.f, 0.f};

  const int sr = tid >> 3;                 // 0..31
  const int sj = (tid & 7) ^ (sr & 7);     // inverse-swizzled source slot
  const unsigned short* aSrc = Ag + (long)(tm0 + sr) * lda + sj * 8;
  const unsigned short* bSrc = Bg + (long)(tn0 + sr) * ldb + sj * 8;

  const int nt = K >> 6;

#define STAGE(kt_, buf_)                                                     \
  {                                                                          \
    unsigned short* aD = smem + (buf_) * 8192 + wave * 512;                  \
    unsigned short* bD = smem + 16384 + (buf_) * 8192 + wave * 512;          \
    _Pragma("unroll")                                                        \
    for (int rd = 0; rd < 4; ++rd) {                                         \
      GLL16(aSrc + (kt_) + (long)rd * 32 * lda, aD + rd * 2048);             \
      GLL16(bSrc + (kt_) + (long)rd * 32 * ldb, bD + rd * 2048);             \
    }                                                                        \
  }

  STAGE(0, 0);

  const int xr = (lrow & 7) << 3;
  for (int t = 0; t < nt; ++t) {
    if (t + 1 < nt) {
      STAGE((t + 1) << 6, (t + 1) & 1);    // prefetch stays in flight
      asm volatile("s_waitcnt vmcnt(8)" ::: "memory");   // my tile-t loads done
    } else {
      asm volatile("s_waitcnt vmcnt(0)" ::: "memory");   // final drain (once)
    }
    __builtin_amdgcn_s_barrier();          // everyone's tile-t loads done
    __builtin_amdgcn_sched_barrier(0);
    const unsigned short* As_ = smem + (t & 1) * 8192;
    const unsigned short* Bs_ = smem + 16384 + (t & 1) * 8192;
    bf16x8 af[4][2], bfv[4][2];
#pragma unroll
    for (int mi = 0; mi < 4; ++mi)
#pragma unroll
      for (int ks = 0; ks < 2; ++ks)
        af[mi][ks] = *reinterpret_cast<const bf16x8*>(
            &As_[(wm + mi * 16 + lrow) * 64 + ((ks * 32 + kq * 8) ^ xr)]);
#pragma unroll
    for (int ni = 0; ni < 4; ++ni)
#pragma unroll
      for (int ks = 0; ks < 2; ++ks)
        bfv[ni][ks] = *reinterpret_cast<const bf16x8*>(
            &Bs_[(wn + ni * 16 + lrow) * 64 + ((ks * 32 + kq * 8) ^ xr)]);
#pragma unroll
    for (int mi = 0; mi < 4; ++mi)
#pragma unroll
      for (int ni = 0; ni < 4; ++ni) {
        acc[mi][ni] = __builtin_amdgcn_mfma_f32_16x16x32_bf16(af[mi][0], bfv[ni][0], acc[mi][ni], 0, 0, 0);
        acc[mi][ni] = __builtin_amdgcn_mfma_f32_16x16x32_bf16(af[mi][1], bfv[ni][1], acc[mi][ni], 0, 0, 0);
      }
    __builtin_amdgcn_sched_barrier(0);
    if (t + 1 < nt) __builtin_amdgcn_s_barrier();  // reads done: next STAGE may overwrite
  }
#undef STAGE

  unsigned short* Cb = (unsigned short*)Cp + (long)bz * sC;
  if (mode == 1) {
#pragma unroll
    for (int mi = 0; mi < 4; ++mi) {
      int rg = tm0 + wm + mi * 16 + kq * 4;
#pragma unroll
      for (int ni = 0; ni < 4; ++ni) {
        int cg = tn0 + wn + ni * 16 + lrow;
        float bb = bias ? bias[cg] : 0.f;
        f32x4 v = acc[mi][ni];
#pragma unroll
        for (int r = 0; r < 4; ++r)
          Cb[(long)(rg + r) * ldc + cg] = f2bf(v[r] * alpha + bb);
      }
    }
  } else {                                 // mode 3: bias indexed by row
#pragma unroll
    for (int mi = 0; mi < 4; ++mi) {
      int rg = tm0 + wm + mi * 16 + kq * 4;
      float rb[4];
#pragma unroll
      for (int r = 0; r < 4; ++r) rb[r] = bias[rg + r];
#pragma unroll
      for (int ni = 0; ni < 4; ++ni) {
        int cg = tn0 + wn + ni * 16 + lrow;
        f32x4 v = acc[mi][ni];
#pragma unroll
        for (int r = 0; r < 4; ++r)
          Cb[(long)(rg + r) * ldc + cg] = f2bf(v[r] * alpha + rb[r]);
      }
    }
  }
}

// ---------------- GEMM 128x64 (L2-resident-operand shapes) ----------------
__global__ __launch_bounds__(256)
void k_gemm64(const unsigned short* __restrict__ A,
              const unsigned short* __restrict__ B,
              void* __restrict__ Cp,
              int K, int lda, int ldb, int ldc,
              long sA, long sB, long sC,
              const float* __restrict__ bias,
              float alpha, int mode) {
  const int gx = gridDim.x;
  const int nwg = gx * gridDim.y;
  int wg = blockIdx.x + gx * blockIdx.y;
  wg = (wg & 7) * (nwg >> 3) + (wg >> 3);
  const int tm0 = (wg % gx) * 128, tn0 = (wg / gx) * 64;
  const int bz = blockIdx.z;
  const unsigned short* Ag = A + (long)bz * sA;
  const unsigned short* Bg = B + (long)bz * sB;

  __shared__ __align__(16) unsigned short smem[24576];

  const int tid = threadIdx.x;
  const int lane = tid & 63;
  const int wave = tid >> 6;
  const int wm = (wave >> 1) * 64, wn = (wave & 1) * 32;
  const int lrow = lane & 15, kq = lane >> 4;

  f32x4 acc[4][2];
#pragma unroll
  for (int i = 0; i < 4; ++i)
#pragma unroll
    for (int j = 0; j < 2; ++j) acc[i][j] = f32x4{0.f, 0.f, 0.f, 0.f};

  const int sr = tid >> 3;                 // 0..31
  const int sj = (tid & 7) ^ (sr & 7);     // inverse-swizzled source slot
  const unsigned short* aSrc = Ag + (long)(tm0 + sr) * lda + sj * 8;
  const unsigned short* bSrc = Bg + (long)(tn0 + sr) * ldb + sj * 8;

  const int nt = K >> 6;

#define STAGE64(kt_, buf_)                                                   \
  {                                                                          \
    unsigned short* aD = smem + (buf_) * 8192 + wave * 512;                  \
    unsigned short* bD = smem + 16384 + (buf_) * 4096 + wave * 512;          \
    _Pragma("unroll")                                                        \
    for (int rd = 0; rd < 4; ++rd)                                           \
      GLL16(aSrc + (kt_) + (long)rd * 32 * lda, aD + rd * 2048);             \
    _Pragma("unroll")                                                        \
    for (int rd = 0; rd < 2; ++rd)                                           \
      GLL16(bSrc + (kt_) + (long)rd * 32 * ldb, bD + rd * 2048);             \
  }

  STAGE64(0, 0);

  const int xr = (lrow & 7) << 3;
  for (int t = 0; t < nt; ++t) {
    if (t + 1 < nt) {
      STAGE64((t + 1) << 6, (t + 1) & 1);
      asm volatile("s_waitcnt vmcnt(6)" ::: "memory");
    } else {
      asm volatile("s_waitcnt vmcnt(0)" ::: "memory");
    }
    __builtin_amdgcn_s_barrier();
    __builtin_amdgcn_sched_barrier(0);
    const unsigned short* As_ = smem + (t & 1) * 8192;
    const unsigned short* Bs_ = smem + 16384 + (t & 1) * 4096;
    bf16x8 af[4][2], bfv[2][2];
#pragma unroll
    for (int mi = 0; mi < 4; ++mi)
#pragma unroll
      for (int ks = 0; ks < 2; ++ks)
        af[mi][ks] = *reinterpret_cast<const bf16x8*>(
            &As_[(wm + mi * 16 + lrow) * 64 + ((ks * 32 + kq * 8) ^ xr)]);
#pragma unroll
    for (int ni = 0; ni < 2; ++ni)
#pragma unroll
      for (int ks = 0; ks < 2; ++ks)
        bfv[ni][ks] = *reinterpret_cast<const bf16x8*>(
            &Bs_[(wn + ni * 16 + lrow) * 64 + ((ks * 32 + kq * 8) ^ xr)]);
#pragma unroll
    for (int mi = 0; mi < 4; ++mi)
#pragma unroll
      for (int ni = 0; ni < 2; ++ni) {
        acc[mi][ni] = __builtin_amdgcn_mfma_f32_16x16x32_bf16(af[mi][0], bfv[ni][0], acc[mi][ni], 0, 0, 0);
        acc[mi][ni] = __builtin_amdgcn_mfma_f32_16x16x32_bf16(af[mi][1], bfv[ni][1], acc[mi][ni], 0, 0, 0);
      }
    __builtin_amdgcn_sched_barrier(0);
    if (t + 1 < nt) __builtin_amdgcn_s_barrier();
  }
#undef STAGE64

  unsigned short* Cb = (unsigned short*)Cp + (long)bz * sC;
  if (mode == 1) {
#pragma unroll
    for (int mi = 0; mi < 4; ++mi) {
      int rg = tm0 + wm + mi * 16 + kq * 4;
#pragma unroll
      for (int ni = 0; ni < 2; ++ni) {
        int cg = tn0 + wn + ni * 16 + lrow;
        float bb = bias ? bias[cg] : 0.f;
        f32x4 v = acc[mi][ni];
#pragma unroll
        for (int r = 0; r < 4; ++r)
          Cb[(long)(rg + r) * ldc + cg] = f2bf(v[r] * alpha + bb);
      }
    }
  } else {                                 // mode 3: bias indexed by row
#pragma unroll
    for (int mi = 0; mi < 4; ++mi) {
      int rg = tm0 + wm + mi * 16 + kq * 4;
      float rb[4];
#pragma unroll
      for (int r = 0; r < 4; ++r) rb[r] = bias[rg + r];
#pragma unroll
      for (int ni = 0; ni < 2; ++ni) {
        int cg = tn0 + wn + ni * 16 + lrow;
        f32x4 v = acc[mi][ni];
#pragma unroll
        for (int r = 0; r < 4; ++r)
          Cb[(long)(rg + r) * ldc + cg] = f2bf(v[r] * alpha + rb[r]);
      }
    }
  }
}

// ---------------- GEMM 256x256 (scores): C = alpha * A * B^T --------------
// BK=32 dbuf, counted vmcnt(4) + 2 raw barriers per K-tile (r13 proven).
// Requires M%256==0, N%256==0, K%32==0, (M/256)*(N/256)%8==0.
__global__ __launch_bounds__(512)
void k_gemm256(const unsigned short* __restrict__ A,
               const unsigned short* __restrict__ B,
               unsigned short* __restrict__ C,
               int K, int lda, int ldb, int ldc,
               long sA, long sB, long sC,
               float alpha, const float* __restrict__ tempPtr) {
  const int gx = gridDim.x;
  const int nwg = gx * gridDim.y;
  int wg = blockIdx.x + gx * blockIdx.y;
  wg = (wg & 7) * (nwg >> 3) + (wg >> 3);
  const int tm0 = (wg % gx) * 256, tn0 = (wg / gx) * 256;
  const unsigned short* Ag = A + (long)blockIdx.z * sA;
  const unsigned short* Bg = B + (long)blockIdx.z * sB;

  __shared__ __align__(16) unsigned short smem[32768];

  const int tid = threadIdx.x;
  const int lane = tid & 63;
  const int wave = tid >> 6;               // 0..7
  const int wm = (wave >> 2) * 128, wn = (wave & 3) * 64;
  const int lrow = lane & 15, kq = lane >> 4;

  f32x4 acc[8][4];
#pragma unroll
  for (int i = 0; i < 8; ++i)
#pragma unroll
    for (int j = 0; j < 4; ++j) acc[i][j] = f32x4{0.f, 0.f, 0.f, 0.f};

  const int srow = lane >> 2;                          // 0..15
  const int sslot = (lane & 3) ^ ((lane >> 3) & 3);    // inverse swizzle
  const unsigned short* aS0 = Ag + (long)(tm0 + wave * 16 + srow) * lda + sslot * 8;
  const unsigned short* aS1 = aS0 + 128L * lda;
  const unsigned short* bS0 = Bg + (long)(tn0 + wave * 16 + srow) * ldb + sslot * 8;
  const unsigned short* bS1 = bS0 + 128L * ldb;

  const int nt = K >> 5;

#define STAGE256(kt_, buf_)                                                  \
  {                                                                          \
    unsigned short* aD = smem + (buf_) * 8192 + wave * 512;                  \
    unsigned short* bD = smem + 16384 + (buf_) * 8192 + wave * 512;          \
    GLL16(aS0 + (kt_), aD);                                                  \
    GLL16(aS1 + (kt_), aD + 4096);                                           \
    GLL16(bS0 + (kt_), bD);                                                  \
    GLL16(bS1 + (kt_), bD + 4096);                                           \
  }

  STAGE256(0, 0);                          // prologue

  const int xr = ((lrow >> 1) & 3) << 3;   // read-side elem XOR
  for (int t = 0; t < nt; ++t) {
    if (t + 1 < nt) {
      STAGE256((t + 1) << 5, (t + 1) & 1); // prefetch next tile
      asm volatile("s_waitcnt vmcnt(4)" ::: "memory");   // tile t landed (mine)
    } else {
      asm volatile("s_waitcnt vmcnt(0)" ::: "memory");   // final drain (once)
    }
    __builtin_amdgcn_s_barrier();          // tile t landed (everyone)
    __builtin_amdgcn_sched_barrier(0);
    const unsigned short* As_ = smem + (t & 1) * 8192;
    const unsigned short* Bs_ = smem + 16384 + (t & 1) * 8192;
    bf16x8 bfv[4];
#pragma unroll
    for (int ni = 0; ni < 4; ++ni)
      bfv[ni] = *reinterpret_cast<const bf16x8*>(
          &Bs_[(wn + ni * 16 + lrow) * 32 + ((kq * 8) ^ xr)]);
#pragma unroll
    for (int mi = 0; mi < 8; ++mi) {
      bf16x8 af = *reinterpret_cast<const bf16x8*>(
          &As_[(wm + mi * 16 + lrow) * 32 + ((kq * 8) ^ xr)]);
#pragma unroll
      for (int ni = 0; ni < 4; ++ni)
        acc[mi][ni] = __builtin_amdgcn_mfma_f32_16x16x32_bf16(af, bfv[ni], acc[mi][ni], 0, 0, 0);
    }
    __builtin_amdgcn_sched_barrier(0);
    if (t + 1 < nt) __builtin_amdgcn_s_barrier();  // reads done: next STAGE may overwrite
  }
#undef STAGE256

  if (tempPtr) alpha = 1.0f / fmaxf(*tempPtr, 0.01f);

  C += (long)blockIdx.z * sC;
#pragma unroll
  for (int mi = 0; mi < 8; ++mi) {
    int rg = tm0 + wm + mi * 16 + kq * 4;
#pragma unroll
    for (int ni = 0; ni < 4; ++ni) {
      int cg = tn0 + wn + ni * 16 + lrow;
      f32x4 v = acc[mi][ni];
#pragma unroll
      for (int r = 0; r < 4; ++r)
        C[(long)(rg + r) * ldc + cg] = f2bf(v[r] * alpha);
    }
  }
}

// ---------------- row softmax, bf16 in-place, cols == 2048 ----------------
__global__ __launch_bounds__(256)
void k_softmax(unsigned short* __restrict__ S, int cols) {
  const long base = (long)blockIdx.x * cols;
  const int tid = threadIdx.x, lane = tid & 63, wave = tid >> 6;
  const int nv = cols >> 3;
  float f[8];
  float mx = -3.0e38f;
  if (tid < nv) {
    uint4 v = *reinterpret_cast<const uint4*>(S + base + tid * 8);
    const unsigned short* pv = (const unsigned short*)&v;
#pragma unroll
    for (int j = 0; j < 8; ++j) { f[j] = bf2f(pv[j]); mx = fmaxf(mx, f[j]); }
  }
  __shared__ float rmax[4], rsum[4];
#pragma unroll
  for (int o = 32; o > 0; o >>= 1) mx = fmaxf(mx, __shfl_down(mx, o));
  if (lane == 0) rmax[wave] = mx;
  __syncthreads();
  mx = fmaxf(fmaxf(rmax[0], rmax[1]), fmaxf(rmax[2], rmax[3]));
  float sum = 0.f;
  if (tid < nv) {
#pragma unroll
    for (int j = 0; j < 8; ++j) { f[j] = __expf(f[j] - mx); sum += f[j]; }
  }
#pragma unroll
  for (int o = 32; o > 0; o >>= 1) sum += __shfl_down(sum, o);
  if (lane == 0) rsum[wave] = sum;
  __syncthreads();
  const float inv = 1.0f / (rsum[0] + rsum[1] + rsum[2] + rsum[3]);
  if (tid < nv) {
    unsigned short o8[8];
#pragma unroll
    for (int j = 0; j < 8; ++j) o8[j] = f2bf(f[j] * inv);
    *reinterpret_cast<uint4*>(S + base + tid * 8) = *reinterpret_cast<const uint4*>(o8);
  }
}

// ---------------- row softmax cols=1024: 2 rows/block, all lanes live -----
__global__ __launch_bounds__(256)
void k_softmax1024(unsigned short* __restrict__ S) {
  const int tid = threadIdx.x;
  const int half = tid >> 7, ht = tid & 127;       // row-pair half, idx in half
  const int lane = tid & 63, wave = tid >> 6;      // waves {0,1}=row0 {2,3}=row1
  const long base = ((long)blockIdx.x * 2 + half) * 1024;
  uint4 v = *reinterpret_cast<const uint4*>(S + base + ht * 8);
  const unsigned short* pv = (const unsigned short*)&v;
  float f[8];
  float mx = -3.0e38f;
#pragma unroll
  for (int j = 0; j < 8; ++j) { f[j] = bf2f(pv[j]); mx = fmaxf(mx, f[j]); }
  __shared__ float rmax[4], rsum[4];
#pragma unroll
  for (int o = 32; o > 0; o >>= 1) mx = fmaxf(mx, __shfl_down(mx, o));
  if (lane == 0) rmax[wave] = mx;
  __syncthreads();
  mx = fmaxf(rmax[half * 2], rmax[half * 2 + 1]);
  float sum = 0.f;
#pragma unroll
  for (int j = 0; j < 8; ++j) { f[j] = __expf(f[j] - mx); sum += f[j]; }
#pragma unroll
  for (int o = 32; o > 0; o >>= 1) sum += __shfl_down(sum, o);
  if (lane == 0) rsum[wave] = sum;
  __syncthreads();
  const float inv = 1.0f / (rsum[half * 2] + rsum[half * 2 + 1]);
  unsigned short o8[8];
#pragma unroll
  for (int j = 0; j < 8; ++j) o8[j] = f2bf(f[j] * inv);
  *reinterpret_cast<uint4*>(S + base + ht * 8) = *reinterpret_cast<const uint4*>(o8);
}

// ---------------- L2-normalize: 32768 rows of 512 in QK2 [.][1024] --------
__global__ __launch_bounds__(256)
void k_l2norm2(unsigned short* __restrict__ Q) {
  const int lane = threadIdx.x & 63, wave = threadIdx.x >> 6;
  const int idx = blockIdx.x * 4 + wave;            // 0..32767
  unsigned short* p = Q + (long)(idx >> 1) * 1024 + (idx & 1) * 512 + lane * 8;
  uint4 v = *reinterpret_cast<const uint4*>(p);
  const unsigned short* pv = (const unsigned short*)&v;
  float f[8]; float q = 0.f;
#pragma unroll
  for (int j = 0; j < 8; ++j) { f[j] = bf2f(pv[j]); q += f[j] * f[j]; }
#pragma unroll
  for (int o = 32; o > 0; o >>= 1) q += __shfl_xor(q, o);
  float sc = 1.0f / (sqrtf(q) + 1e-8f);
  unsigned short o8[8];
#pragma unroll
  for (int j = 0; j < 8; ++j) o8[j] = f2bf(f[j] * sc);
  *reinterpret_cast<uint4*>(p) = *reinterpret_cast<const uint4*>(o8);
}

// -------- fused LayerNorm(3 branches) + gating: one wave per position -----
__global__ __launch_bounds__(256)
void k_gate(const unsigned short* __restrict__ o0, const unsigned short* __restrict__ o1,
            const unsigned short* __restrict__ o2, const float* __restrict__ gw,
            const float* __restrict__ gb,
            const float* __restrict__ g0, const float* __restrict__ b0,
            const float* __restrict__ g1, const float* __restrict__ b1,
            const float* __restrict__ g2, const float* __restrict__ b2,
            float* __restrict__ out) {
  __shared__ float gws[3 * 1536];
  for (int i = threadIdx.x; i < 3 * 1536; i += 256) gws[i] = gw[i];
  __syncthreads();
  const int lane = threadIdx.x & 63, wave = threadIdx.x >> 6;
  const long pos = (long)blockIdx.x * 4 + wave;
  const long off = pos * CDIM + lane * 8;
  float a[8], bq[8], cq[8];
  {
    uint4 va = *reinterpret_cast<const uint4*>(o0 + off);
    uint4 vb = *reinterpret_cast<const uint4*>(o1 + off);
    uint4 vc = *reinterpret_cast<const uint4*>(o2 + off);
    const unsigned short* pa = (const unsigned short*)&va;
    const unsigned short* pb = (const unsigned short*)&vb;
    const unsigned short* pc = (const unsigned short*)&vc;
#pragma unroll
    for (int j = 0; j < 8; ++j) { a[j] = bf2f(pa[j]); bq[j] = bf2f(pb[j]); cq[j] = bf2f(pc[j]); }
  }
  float sa = 0.f, qa = 0.f, sb = 0.f, qb = 0.f, sc2 = 0.f, qc = 0.f;
#pragma unroll
  for (int j = 0; j < 8; ++j) {
    sa += a[j];  qa += a[j] * a[j];
    sb += bq[j]; qb += bq[j] * bq[j];
    sc2 += cq[j]; qc += cq[j] * cq[j];
  }
#pragma unroll
  for (int o = 32; o > 0; o >>= 1) {
    sa += __shfl_xor(sa, o);  qa += __shfl_xor(qa, o);
    sb += __shfl_xor(sb, o);  qb += __shfl_xor(qb, o);
    sc2 += __shfl_xor(sc2, o); qc += __shfl_xor(qc, o);
  }
  const float inv512 = 1.f / 512.f;
  float mua = sa * inv512, rsa = rsqrtf(qa * inv512 - mua * mua + 1e-5f);
  float mub = sb * inv512, rsb = rsqrtf(qb * inv512 - mub * mub + 1e-5f);
  float muc = sc2 * inv512, rsc = rsqrtf(qc * inv512 - muc * muc + 1e-5f);
  const int ch = lane * 8;
  float gga[8], bba[8], ggb[8], bbb[8], ggc[8], bbc[8];
  *reinterpret_cast<float4*>(&gga[0]) = *reinterpret_cast<const float4*>(g0 + ch);
  *reinterpret_cast<float4*>(&gga[4]) = *reinterpret_cast<const float4*>(g0 + ch + 4);
  *reinterpret_cast<float4*>(&bba[0]) = *reinterpret_cast<const float4*>(b0 + ch);
  *reinterpret_cast<float4*>(&bba[4]) = *reinterpret_cast<const float4*>(b0 + ch + 4);
  *reinterpret_cast<float4*>(&ggb[0]) = *reinterpret_cast<const float4*>(g1 + ch);
  *reinterpret_cast<float4*>(&ggb[4]) = *reinterpret_cast<const float4*>(g1 + ch + 4);
  *reinterpret_cast<float4*>(&bbb[0]) = *reinterpret_cast<const float4*>(b1 + ch);
  *reinterpret_cast<float4*>(&bbb[4]) = *reinterpret_cast<const float4*>(b1 + ch + 4);
  *reinterpret_cast<float4*>(&ggc[0]) = *reinterpret_cast<const float4*>(g2 + ch);
  *reinterpret_cast<float4*>(&ggc[4]) = *reinterpret_cast<const float4*>(g2 + ch + 4);
  *reinterpret_cast<float4*>(&bbc[0]) = *reinterpret_cast<const float4*>(b2 + ch);
  *reinterpret_cast<float4*>(&bbc[4]) = *reinterpret_cast<const float4*>(b2 + ch + 4);
#pragma unroll
  for (int j = 0; j < 8; ++j) {
    a[j]  = (a[j] - mua) * rsa * gga[j] + bba[j];
    bq[j] = (bq[j] - mub) * rsb * ggb[j] + bbb[j];
    cq[j] = (cq[j] - muc) * rsc * ggc[j] + bbc[j];
  }
  float l0 = 0.f, l1 = 0.f, l2 = 0.f;
#pragma unroll
  for (int j = 0; j < 8; ++j) {
    l0 += a[j] * gws[ch + j] + bq[j] * gws[512 + ch + j] + cq[j] * gws[1024 + ch + j];
    l1 += a[j] * gws[1536 + ch + j] + bq[j] * gws[2048 + ch + j] + cq[j] * gws[2560 + ch + j];
    l2 += a[j] * gws[3072 + ch + j] + bq[j] * gws[3584 + ch + j] + cq[j] * gws[4096 + ch + j];
  }
#pragma unroll
  for (int o = 32; o > 0; o >>= 1) {
    l0 += __shfl_xor(l0, o); l1 += __shfl_xor(l1, o); l2 += __shfl_xor(l2, o);
  }
  l0 += gb[0]; l1 += gb[1]; l2 += gb[2];
  float m = fmaxf(l0, fmaxf(l1, l2));
  float e0 = __expf(l0 - m), e1 = __expf(l1 - m), e2 = __expf(l2 - m);
  float inv = 1.f / (e0 + e1 + e2);
  float w0 = e0 * inv, w1 = e1 * inv, w2 = e2 * inv;
  float r[8];
#pragma unroll
  for (int j = 0; j < 8; ++j) r[j] = w0 * a[j] + w1 * bq[j] + w2 * cq[j];
  *reinterpret_cast<float4*>(out + off) = *reinterpret_cast<const float4*>(&r[0]);
  *reinterpret_cast<float4*>(out + off + 4) = *reinterpret_cast<const float4*>(&r[4]);
}

// ===========================================================================
extern "C" void kernel_launch(void* const* d_in, const int* in_sizes, int n_in,
                              void* d_out, int out_size, void* d_ws, size_t ws_size,
                              hipStream_t stream) {
  (void)in_sizes; (void)n_in; (void)out_size;
  const float* x = (const float*)d_in[0];
  const float* dw = (const float*)d_in[1];
  const float* db = (const float*)d_in[2];
  WPtrs wp;
  wp.p[0] = (const float*)d_in[3];   // wq_cr
  wp.p[1] = (const float*)d_in[11];  // wq_d
  wp.p[2] = (const float*)d_in[13];  // wk_d
  wp.p[3] = (const float*)d_in[19];  // wq_c
  wp.p[4] = (const float*)d_in[21];  // wk_c
  wp.p[5] = (const float*)d_in[15];  // wv_d
  wp.p[6] = (const float*)d_in[23];  // wv_c
  wp.p[7] = (const float*)d_in[5];   // wk_cr
  wp.p[8] = (const float*)d_in[7];   // wv_cr
  const float* bq_cr = (const float*)d_in[4];
  const float* bk_cr = (const float*)d_in[6];
  const float* bv_cr = (const float*)d_in[8];
  const float* ln_cr_g = (const float*)d_in[9];
  const float* ln_cr_b = (const float*)d_in[10];
  const float* bq_d = (const float*)d_in[12];
  const float* bk_d = (const float*)d_in[14];
  const float* bv_d = (const float*)d_in[16];
  const float* ln_d_g = (const float*)d_in[17];
  const float* ln_d_b = (const float*)d_in[18];
  const float* bq_c = (const float*)d_in[20];
  const float* bk_c = (const float*)d_in[22];
  const float* bv_c = (const float*)d_in[24];
  const float* ln_c_g = (const float*)d_in[25];
  const float* ln_c_b = (const float*)d_in[26];
  const float* temp = (const float*)d_in[27];
  const float* gw = (const float*)d_in[28];
  const float* gb = (const float*)d_in[29];

  if (ws_size < 243000000ULL) return;  // plan needs ~241.5 MiB (ws >= 250 MB known)

  char* p = (char*)d_ws;
  auto alloc = [&](size_t bytes) {
    void* r = (void*)p;
    p += (bytes + 255) & ~(size_t)255;
    return r;
  };
  alloc(1024);                                                     // front pad
  unsigned short* XB  = (unsigned short*)alloc(16384L * 512 * 2);
  unsigned short* XD  = (unsigned short*)alloc(8192L * 512 * 2);
  unsigned short* WB  = (unsigned short*)alloc(9L * 262144 * 2);
  unsigned short* DWB = (unsigned short*)alloc(512L * 1536 * 2);
  unsigned short* QB  = (unsigned short*)alloc(16384L * 512 * 2);   // q_cr
  unsigned short* KB  = (unsigned short*)alloc(8192L * 512 * 2);    // k_cr
  unsigned short* VT  = (unsigned short*)alloc(1024L * 16384 * 2);  // V^T: cr, then d|c
  unsigned short* OUT0 = (unsigned short*)alloc(16384L * 512 * 2);
  unsigned short* OUT1 = (unsigned short*)alloc(16384L * 512 * 2);
  unsigned short* OUT2 = (unsigned short*)alloc(16384L * 512 * 2);
  unsigned short* QK2 = (unsigned short*)alloc(16384L * 1024 * 2);  // per-branch Q|K
  float* BC = (float*)alloc(3072 * 4);                              // bias concat
  unsigned short* SB = (unsigned short*)alloc(8L * 2048 * 2048 * 2);

  const float scale = 0.044194173824159216f;  // 1/sqrt(512)

  auto gemm = [&](const unsigned short* A, const unsigned short* Bm, void* Cm,
                  int M, int N, int K, int lda, int ldb, int ldc,
                  int batch, long sA, long sB, long sC,
                  const float* bias, float alpha, int mode) {
    dim3 g(M / 128, N / 128, batch);
    k_gemm<<<g, 256, 0, stream>>>(A, Bm, Cm, K, lda, ldb, ldc, sA, sB, sC,
                                  bias, alpha, mode);
  };
  auto gemm64 = [&](const unsigned short* A, const unsigned short* Bm, void* Cm,
                    int M, int N, int K, int lda, int ldb, int ldc,
                    int batch, long sA, long sB, long sC,
                    const float* bias, float alpha, int mode) {
    dim3 g(M / 128, N / 64, batch);
    k_gemm64<<<g, 256, 0, stream>>>(A, Bm, Cm, K, lda, ldb, ldc, sA, sB, sC,
                                    bias, alpha, mode);
  };
  auto gemm256 = [&](const unsigned short* A, const unsigned short* Bm,
                     unsigned short* Cm, int M, int N, int K,
                     int lda, int ldb, int ldc, int batch,
                     long sA, long sB, long sC, float alpha, const float* tp) {
    dim3 g(M / 256, N / 256, batch);
    k_gemm256<<<g, 512, 0, stream>>>(A, Bm, Cm, K, lda, ldb, ldc, sA, sB, sC, alpha, tp);
  };

  // ---- conversions & bias concats ----
  k_tobf16<<<8192, 256, 0, stream>>>(x, XB, 16384L * 512 / 4);
  k_tobf16w<<<2304, 256, 0, stream>>>(wp, WB);
  k_dwreorder<<<3072, 256, 0, stream>>>(dw, DWB);
  hipMemcpyAsync(BC,        bq_d, 512 * 4, hipMemcpyDeviceToDevice, stream);
  hipMemcpyAsync(BC + 512,  bk_d, 512 * 4, hipMemcpyDeviceToDevice, stream);
  hipMemcpyAsync(BC + 1024, bq_c, 512 * 4, hipMemcpyDeviceToDevice, stream);
  hipMemcpyAsync(BC + 1536, bk_c, 512 * 4, hipMemcpyDeviceToDevice, stream);
  hipMemcpyAsync(BC + 2048, bv_d, 512 * 4, hipMemcpyDeviceToDevice, stream);
  hipMemcpyAsync(BC + 2560, bv_c, 512 * 4, hipMemcpyDeviceToDevice, stream);

  // ---- downsample conv: strided-A GEMM ----
  gemm64(XB - 512, DWB, XD, 1024, 512, 1536, 1024, 1536, 512,
         8, 1048576L, 0, 524288L, db, 1.f, 1);
  k_fix<<<1024, 256, 0, stream>>>(XB, DWB, db, XD);   // exact t=0 rows

  // ================= branch cr (q from x, k/v from x_down) =================
  gemm(XB, WB + 0 * 262144L, QB, 16384, 512, 512, 512, 512, 512, 1, 0, 0, 0,
       bq_cr, 1.f, 1);
  gemm64(XD, WB + 7 * 262144L, KB, 8192, 512, 512, 512, 512, 512, 1, 0, 0, 0,
         bk_cr, 1.f, 1);
  // V^T_cr = W_v_cr * XD^T : [512][8192] into VT (ld 8192), reused below
  gemm64(WB + 8 * 262144L, XD, VT, 512, 8192, 512, 512, 512, 8192, 1, 0, 0, 0,
         bv_cr, 1.f, 3);
  gemm256(QB, KB, SB, 2048, 1024, 512, 512, 512, 1024, 8,
          2048L * 512, 1024L * 512, 2048L * 1024, scale, nullptr);
  k_softmax1024<<<8192, 256, 0, stream>>>(SB);
  gemm(SB, VT, OUT0, 2048, 512, 1024, 1024, 8192, 512, 8,
       2048L * 1024, 1024, 2048L * 512, nullptr, 1.f, 1);

  // ---- fused V^T for d|c: [1024][16384] = [wv_d; wv_c] * XB^T (after PV-cr)
  gemm64(WB + 5 * 262144L, XB, VT, 1024, 16384, 512, 512, 512, 16384, 1, 0, 0, 0,
         BC + 2048, 1.f, 3);

  // ================= branch d (standard attention over x) ==================
  gemm(XB, WB + 1 * 262144L, QK2, 16384, 1024, 512, 512, 512, 1024, 1, 0, 0, 0,
       BC, 1.f, 1);                                  // fused Q|K projection
  gemm256(QK2, QK2 + 512, SB, 2048, 2048, 512, 1024, 1024, 2048, 8,
          2048L * 1024, 2048L * 1024, 2048L * 2048, scale, nullptr);
  k_softmax<<<16384, 256, 0, stream>>>(SB, 2048);
  gemm(SB, VT, OUT1, 2048, 512, 2048, 2048, 16384, 512, 8,
       2048L * 2048, 2048, 2048L * 512, nullptr, 1.f, 1);

  // ================= branch c (cosine attention, learnable temp) ===========
  gemm(XB, WB + 3 * 262144L, QK2, 16384, 1024, 512, 512, 512, 1024, 1, 0, 0, 0,
       BC + 1024, 1.f, 1);                           // fused Q|K projection
  k_l2norm2<<<8192, 256, 0, stream>>>(QK2);          // Q and K halves together
  gemm256(QK2, QK2 + 512, SB, 2048, 2048, 512, 1024, 1024, 2048, 8,
          2048L * 1024, 2048L * 1024, 2048L * 2048, 1.f, temp);
  k_softmax<<<16384, 256, 0, stream>>>(SB, 2048);
  gemm(SB, VT + 512L * 16384, OUT2, 2048, 512, 2048, 2048, 16384, 512, 8,
       2048L * 2048, 2048, 2048L * 512, nullptr, 1.f, 1);

  // ============ fused LN(3 branches) + gating -> d_out ====================
  k_gate<<<4096, 256, 0, stream>>>(OUT0, OUT1, OUT2, gw, gb,
                                   ln_cr_g, ln_cr_b, ln_d_g, ln_d_b,
                                   ln_c_g, ln_c_b, (float*)d_out);
}

// Round 16
// 529.428 us; speedup vs baseline: 1.2544x; 1.0128x over previous
//
#include <hip/hip_runtime.h>

// ---------------------------------------------------------------------------
// Hybrid MRHA: conv-downsample + 3 attention branches + LN + gated fusion.
// k_gemm    : 128x128, BK=64, XOR-swizzled LDS, counted-vmcnt 2-barrier loop.
// k_gemm64  : 128x64 variant — V^T projections, conv, K-cr.
// k_gemm256 : 256x256, NOW BK=64 (8 iterations instead of 16: halves barrier
//             count; 128 KB LDS, 1 block/CU — proven perf-neutral in r14).
// k_gate    : LayerNorm (all 3 branches) + gating fusion in one pass.
// ---------------------------------------------------------------------------

typedef __attribute__((ext_vector_type(8))) __bf16 bf16x8;
typedef __attribute__((ext_vector_type(4))) float f32x4;

#define CDIM 512
#define TFULL 2048

#define GLL16(gp, lp)                                                        \
  __builtin_amdgcn_global_load_lds(                                          \
      (const __attribute__((address_space(1))) unsigned int*)(gp),           \
      (__attribute__((address_space(3))) unsigned int*)(lp), 16, 0, 0)

__device__ __forceinline__ unsigned short f2bf(float f) {
  unsigned u = __float_as_uint(f);
  u = (u + 0x7fffu + ((u >> 16) & 1u)) >> 16;   // round-to-nearest-even
  return (unsigned short)u;
}
__device__ __forceinline__ float bf2f(unsigned short h) {
  return __uint_as_float(((unsigned)h) << 16);
}

// ---------------- conversion: f32 -> bf16 (vec4) ----------------
__global__ __launch_bounds__(256)
void k_tobf16(const float* __restrict__ src, unsigned short* __restrict__ dst, long n4) {
  long i = (long)blockIdx.x * 256 + threadIdx.x;
  if (i >= n4) return;
  float4 f = reinterpret_cast<const float4*>(src)[i];
  unsigned short o4[4] = {f2bf(f.x), f2bf(f.y), f2bf(f.z), f2bf(f.w)};
  reinterpret_cast<uint2*>(dst)[i] = *reinterpret_cast<const uint2*>(o4);
}

// ---------------- batched weight conversion: 9 x 512x512 -> WB ----------
struct WPtrs { const float* p[9]; };
__global__ __launch_bounds__(256)
void k_tobf16w(WPtrs w, unsigned short* __restrict__ dst) {
  int idx = blockIdx.x * 256 + threadIdx.x;       // over 9*65536 vec4 units
  if (idx >= 9 * 65536) return;
  int m = idx >> 16, off = idx & 65535;
  float4 f = reinterpret_cast<const float4*>(w.p[m])[off];
  unsigned short o4[4] = {f2bf(f.x), f2bf(f.y), f2bf(f.z), f2bf(f.w)};
  reinterpret_cast<uint2*>(dst + (long)m * 262144)[off] = *reinterpret_cast<const uint2*>(o4);
}

// ---------------- dw [o][i][k] -> DWB bf16 [o][k*512+i] ----------------
__global__ __launch_bounds__(256)
void k_dwreorder(const float* __restrict__ dw, unsigned short* __restrict__ dwb) {
  int idx = blockIdx.x * 256 + threadIdx.x;           // over 512*1536
  if (idx >= 512 * 1536) return;
  int o = idx / 1536, rem = idx - o * 1536;
  int k = rem >> 9, i = rem & 511;
  dwb[idx] = f2bf(dw[(o * 512 + i) * 3 + k]);
}

// ---------------- conv row-0 fixup: one wave per (b,o), coalesced ---------
__global__ __launch_bounds__(256)
void k_fix(const unsigned short* __restrict__ XB, const unsigned short* __restrict__ DWB,
           const float* __restrict__ db, unsigned short* __restrict__ XD) {
  const int lane = threadIdx.x & 63, wave = threadIdx.x >> 6;
  const int idx = blockIdx.x * 4 + wave;      // 4096 = 8 batches * 512 outputs
  const int b = idx >> 9, o = idx & 511;
  const unsigned short* xr = XB + (long)b * TFULL * CDIM + lane * 16;  // rows 0,1
  const unsigned short* wr = DWB + (long)o * 1536 + 512 + lane * 16;   // taps 1,2
  float acc = 0.f;
  uint4 xv0 = *reinterpret_cast<const uint4*>(xr);
  uint4 xv1 = *reinterpret_cast<const uint4*>(xr + 8);
  uint4 wv0 = *reinterpret_cast<const uint4*>(wr);
  uint4 wv1 = *reinterpret_cast<const uint4*>(wr + 8);
  const unsigned short* xp0 = (const unsigned short*)&xv0;
  const unsigned short* xp1 = (const unsigned short*)&xv1;
  const unsigned short* wp0 = (const unsigned short*)&wv0;
  const unsigned short* wp1 = (const unsigned short*)&wv1;
#pragma unroll
  for (int j = 0; j < 8; ++j) acc += bf2f(xp0[j]) * bf2f(wp0[j]);
#pragma unroll
  for (int j = 0; j < 8; ++j) acc += bf2f(xp1[j]) * bf2f(wp1[j]);
#pragma unroll
  for (int off = 32; off > 0; off >>= 1) acc += __shfl_xor(acc, off);
  if (lane == 0) XD[(long)b * 1024 * 512 + o] = f2bf(acc + db[o]);
}

// ---------------- GEMM 128x128: C = alpha * A * B^T + bias ----------------
// mode 1: bf16 store, bias[col] | mode 3: bf16 store, bias[row]
__global__ __launch_bounds__(256)
void k_gemm(const unsigned short* __restrict__ A,
            const unsigned short* __restrict__ B,
            void* __restrict__ Cp,
            int K, int lda, int ldb, int ldc,
            long sA, long sB, long sC,
            const float* __restrict__ bias,
            float alpha, int mode) {
  const int gx = gridDim.x;
  const int nwg = gx * gridDim.y;
  int wg = blockIdx.x + gx * blockIdx.y;
  wg = (wg & 7) * (nwg >> 3) + (wg >> 3);
  const int tm0 = (wg % gx) * 128, tn0 = (wg / gx) * 128;
  const int bz = blockIdx.z;
  const unsigned short* Ag = A + (long)bz * sA;
  const unsigned short* Bg = B + (long)bz * sB;

  __shared__ __align__(16) unsigned short smem[32768];

  const int tid = threadIdx.x;
  const int lane = tid & 63;
  const int wave = tid >> 6;
  const int wm = (wave >> 1) * 64, wn = (wave & 1) * 64;
  const int lrow = lane & 15, kq = lane >> 4;

  f32x4 acc[4][4];
#pragma unroll
  for (int i = 0; i < 4; ++i)
#pragma unroll
    for (int j = 0; j < 4; ++j) acc[i][j] = f32x4{0.f, 0.f, 0.f, 0.f};

  const int sr = tid >> 3;                 // 0..31
  const int sj = (tid & 7) ^ (sr & 7);     // inverse-swizzled source slot
  const unsigned short* aSrc = Ag + (long)(tm0 + sr) * lda + sj * 8;
  const unsigned short* bSrc = Bg + (long)(tn0 + sr) * ldb + sj * 8;

  const int nt = K >> 6;

#define STAGE(kt_, buf_)                                                     \
  {                                                                          \
    unsigned short* aD = smem + (buf_) * 8192 + wave * 512;                  \
    unsigned short* bD = smem + 16384 + (buf_) * 8192 + wave * 512;          \
    _Pragma("unroll")                                                        \
    for (int rd = 0; rd < 4; ++rd) {                                         \
      GLL16(aSrc + (kt_) + (long)rd * 32 * lda, aD + rd * 2048);             \
      GLL16(bSrc + (kt_) + (long)rd * 32 * ldb, bD + rd * 2048);             \
    }                                                                        \
  }

  STAGE(0, 0);

  const int xr = (lrow & 7) << 3;
  for (int t = 0; t < nt; ++t) {
    if (t + 1 < nt) {
      STAGE((t + 1) << 6, (t + 1) & 1);    // prefetch stays in flight
      asm volatile("s_waitcnt vmcnt(8)" ::: "memory");   // my tile-t loads done
    } else {
      asm volatile("s_waitcnt vmcnt(0)" ::: "memory");   // final drain (once)
    }
    __builtin_amdgcn_s_barrier();          // everyone's tile-t loads done
    __builtin_amdgcn_sched_barrier(0);
    const unsigned short* As_ = smem + (t & 1) * 8192;
    const unsigned short* Bs_ = smem + 16384 + (t & 1) * 8192;
    bf16x8 af[4][2], bfv[4][2];
#pragma unroll
    for (int mi = 0; mi < 4; ++mi)
#pragma unroll
      for (int ks = 0; ks < 2; ++ks)
        af[mi][ks] = *reinterpret_cast<const bf16x8*>(
            &As_[(wm + mi * 16 + lrow) * 64 + ((ks * 32 + kq * 8) ^ xr)]);
#pragma unroll
    for (int ni = 0; ni < 4; ++ni)
#pragma unroll
      for (int ks = 0; ks < 2; ++ks)
        bfv[ni][ks] = *reinterpret_cast<const bf16x8*>(
            &Bs_[(wn + ni * 16 + lrow) * 64 + ((ks * 32 + kq * 8) ^ xr)]);
#pragma unroll
    for (int mi = 0; mi < 4; ++mi)
#pragma unroll
      for (int ni = 0; ni < 4; ++ni) {
        acc[mi][ni] = __builtin_amdgcn_mfma_f32_16x16x32_bf16(af[mi][0], bfv[ni][0], acc[mi][ni], 0, 0, 0);
        acc[mi][ni] = __builtin_amdgcn_mfma_f32_16x16x32_bf16(af[mi][1], bfv[ni][1], acc[mi][ni], 0, 0, 0);
      }
    __builtin_amdgcn_sched_barrier(0);
    if (t + 1 < nt) __builtin_amdgcn_s_barrier();  // reads done: next STAGE may overwrite
  }
#undef STAGE

  unsigned short* Cb = (unsigned short*)Cp + (long)bz * sC;
  if (mode == 1) {
#pragma unroll
    for (int mi = 0; mi < 4; ++mi) {
      int rg = tm0 + wm + mi * 16 + kq * 4;
#pragma unroll
      for (int ni = 0; ni < 4; ++ni) {
        int cg = tn0 + wn + ni * 16 + lrow;
        float bb = bias ? bias[cg] : 0.f;
        f32x4 v = acc[mi][ni];
#pragma unroll
        for (int r = 0; r < 4; ++r)
          Cb[(long)(rg + r) * ldc + cg] = f2bf(v[r] * alpha + bb);
      }
    }
  } else {                                 // mode 3: bias indexed by row
#pragma unroll
    for (int mi = 0; mi < 4; ++mi) {
      int rg = tm0 + wm + mi * 16 + kq * 4;
      float rb[4];
#pragma unroll
      for (int r = 0; r < 4; ++r) rb[r] = bias[rg + r];
#pragma unroll
      for (int ni = 0; ni < 4; ++ni) {
        int cg = tn0 + wn + ni * 16 + lrow;
        f32x4 v = acc[mi][ni];
#pragma unroll
        for (int r = 0; r < 4; ++r)
          Cb[(long)(rg + r) * ldc + cg] = f2bf(v[r] * alpha + rb[r]);
      }
    }
  }
}

// ---------------- GEMM 128x64 (L2-resident-operand shapes) ----------------
__global__ __launch_bounds__(256)
void k_gemm64(const unsigned short* __restrict__ A,
              const unsigned short* __restrict__ B,
              void* __restrict__ Cp,
              int K, int lda, int ldb, int ldc,
              long sA, long sB, long sC,
              const float* __restrict__ bias,
              float alpha, int mode) {
  const int gx = gridDim.x;
  const int nwg = gx * gridDim.y;
  int wg = blockIdx.x + gx * blockIdx.y;
  wg = (wg & 7) * (nwg >> 3) + (wg >> 3);
  const int tm0 = (wg % gx) * 128, tn0 = (wg / gx) * 64;
  const int bz = blockIdx.z;
  const unsigned short* Ag = A + (long)bz * sA;
  const unsigned short* Bg = B + (long)bz * sB;

  __shared__ __align__(16) unsigned short smem[24576];

  const int tid = threadIdx.x;
  const int lane = tid & 63;
  const int wave = tid >> 6;
  const int wm = (wave >> 1) * 64, wn = (wave & 1) * 32;
  const int lrow = lane & 15, kq = lane >> 4;

  f32x4 acc[4][2];
#pragma unroll
  for (int i = 0; i < 4; ++i)
#pragma unroll
    for (int j = 0; j < 2; ++j) acc[i][j] = f32x4{0.f, 0.f, 0.f, 0.f};

  const int sr = tid >> 3;                 // 0..31
  const int sj = (tid & 7) ^ (sr & 7);     // inverse-swizzled source slot
  const unsigned short* aSrc = Ag + (long)(tm0 + sr) * lda + sj * 8;
  const unsigned short* bSrc = Bg + (long)(tn0 + sr) * ldb + sj * 8;

  const int nt = K >> 6;

#define STAGE64(kt_, buf_)                                                   \
  {                                                                          \
    unsigned short* aD = smem + (buf_) * 8192 + wave * 512;                  \
    unsigned short* bD = smem + 16384 + (buf_) * 4096 + wave * 512;          \
    _Pragma("unroll")                                                        \
    for (int rd = 0; rd < 4; ++rd)                                           \
      GLL16(aSrc + (kt_) + (long)rd * 32 * lda, aD + rd * 2048);             \
    _Pragma("unroll")                                                        \
    for (int rd = 0; rd < 2; ++rd)                                           \
      GLL16(bSrc + (kt_) + (long)rd * 32 * ldb, bD + rd * 2048);             \
  }

  STAGE64(0, 0);

  const int xr = (lrow & 7) << 3;
  for (int t = 0; t < nt; ++t) {
    if (t + 1 < nt) {
      STAGE64((t + 1) << 6, (t + 1) & 1);
      asm volatile("s_waitcnt vmcnt(6)" ::: "memory");
    } else {
      asm volatile("s_waitcnt vmcnt(0)" ::: "memory");
    }
    __builtin_amdgcn_s_barrier();
    __builtin_amdgcn_sched_barrier(0);
    const unsigned short* As_ = smem + (t & 1) * 8192;
    const unsigned short* Bs_ = smem + 16384 + (t & 1) * 4096;
    bf16x8 af[4][2], bfv[2][2];
#pragma unroll
    for (int mi = 0; mi < 4; ++mi)
#pragma unroll
      for (int ks = 0; ks < 2; ++ks)
        af[mi][ks] = *reinterpret_cast<const bf16x8*>(
            &As_[(wm + mi * 16 + lrow) * 64 + ((ks * 32 + kq * 8) ^ xr)]);
#pragma unroll
    for (int ni = 0; ni < 2; ++ni)
#pragma unroll
      for (int ks = 0; ks < 2; ++ks)
        bfv[ni][ks] = *reinterpret_cast<const bf16x8*>(
            &Bs_[(wn + ni * 16 + lrow) * 64 + ((ks * 32 + kq * 8) ^ xr)]);
#pragma unroll
    for (int mi = 0; mi < 4; ++mi)
#pragma unroll
      for (int ni = 0; ni < 2; ++ni) {
        acc[mi][ni] = __builtin_amdgcn_mfma_f32_16x16x32_bf16(af[mi][0], bfv[ni][0], acc[mi][ni], 0, 0, 0);
        acc[mi][ni] = __builtin_amdgcn_mfma_f32_16x16x32_bf16(af[mi][1], bfv[ni][1], acc[mi][ni], 0, 0, 0);
      }
    __builtin_amdgcn_sched_barrier(0);
    if (t + 1 < nt) __builtin_amdgcn_s_barrier();
  }
#undef STAGE64

  unsigned short* Cb = (unsigned short*)Cp + (long)bz * sC;
  if (mode == 1) {
#pragma unroll
    for (int mi = 0; mi < 4; ++mi) {
      int rg = tm0 + wm + mi * 16 + kq * 4;
#pragma unroll
      for (int ni = 0; ni < 2; ++ni) {
        int cg = tn0 + wn + ni * 16 + lrow;
        float bb = bias ? bias[cg] : 0.f;
        f32x4 v = acc[mi][ni];
#pragma unroll
        for (int r = 0; r < 4; ++r)
          Cb[(long)(rg + r) * ldc + cg] = f2bf(v[r] * alpha + bb);
      }
    }
  } else {                                 // mode 3: bias indexed by row
#pragma unroll
    for (int mi = 0; mi < 4; ++mi) {
      int rg = tm0 + wm + mi * 16 + kq * 4;
      float rb[4];
#pragma unroll
      for (int r = 0; r < 4; ++r) rb[r] = bias[rg + r];
#pragma unroll
      for (int ni = 0; ni < 2; ++ni) {
        int cg = tn0 + wn + ni * 16 + lrow;
        f32x4 v = acc[mi][ni];
#pragma unroll
        for (int r = 0; r < 4; ++r)
          Cb[(long)(rg + r) * ldc + cg] = f2bf(v[r] * alpha + rb[r]);
      }
    }
  }
}

// ---------------- GEMM 256x256 (scores): C = alpha * A * B^T --------------
// BK=64 dbuf (8 iterations), counted vmcnt(8) + 2 raw barriers per K-tile.
// LDS [256 rows][64 elems] per operand per buffer = 128 KB total.
// Swizzle identical to k_gemm's proven BK=64 layout: elem ^= (row&7)<<3.
// Staging: per wave 4 A-loads + 4 B-loads; GLL16 covers 8 rows x 64 elems.
// Requires M%256==0, N%256==0, K%64==0, (M/256)*(N/256)%8==0.
__global__ __launch_bounds__(512)
void k_gemm256(const unsigned short* __restrict__ A,
               const unsigned short* __restrict__ B,
               unsigned short* __restrict__ C,
               int K, int lda, int ldb, int ldc,
               long sA, long sB, long sC,
               float alpha, const float* __restrict__ tempPtr) {
  const int gx = gridDim.x;
  const int nwg = gx * gridDim.y;
  int wg = blockIdx.x + gx * blockIdx.y;
  wg = (wg & 7) * (nwg >> 3) + (wg >> 3);
  const int tm0 = (wg % gx) * 256, tn0 = (wg / gx) * 256;
  const unsigned short* Ag = A + (long)blockIdx.z * sA;
  const unsigned short* Bg = B + (long)blockIdx.z * sB;

  // 128 KiB: A[2][16384] elems then B[2][16384]
  __shared__ __align__(16) unsigned short smem[65536];

  const int tid = threadIdx.x;
  const int lane = tid & 63;
  const int wave = tid >> 6;               // 0..7
  const int wm = (wave >> 2) * 128, wn = (wave & 3) * 64;
  const int lrow = lane & 15, kq = lane >> 4;

  f32x4 acc[8][4];
#pragma unroll
  for (int i = 0; i < 8; ++i)
#pragma unroll
    for (int j = 0; j < 4; ++j) acc[i][j] = f32x4{0.f, 0.f, 0.f, 0.f};

  // staging: instr rd covers rows wave*32 + rd*8 + (lane>>3), slot lane&7.
  // source slot inverse-swizzled: (lane&7) ^ (lane>>3)   (row&7 == lane>>3)
  const int srw = lane >> 3;                           // 0..7
  const int ssl = (lane & 7) ^ srw;                    // inverse swizzle
  const unsigned short* aS = Ag + (long)(tm0 + wave * 32 + srw) * lda + ssl * 8;
  const unsigned short* bS = Bg + (long)(tn0 + wave * 32 + srw) * ldb + ssl * 8;

  const int nt = K >> 6;

#define STAGE256(kt_, buf_)                                                  \
  {                                                                          \
    unsigned short* aD = smem + (buf_) * 16384 + wave * 2048;                \
    unsigned short* bD = smem + 32768 + (buf_) * 16384 + wave * 2048;        \
    _Pragma("unroll")                                                        \
    for (int rd = 0; rd < 4; ++rd) {                                         \
      GLL16(aS + (kt_) + (long)rd * 8 * lda, aD + rd * 512);                 \
      GLL16(bS + (kt_) + (long)rd * 8 * ldb, bD + rd * 512);                 \
    }                                                                        \
  }

  STAGE256(0, 0);                          // prologue

  const int xr = (lrow & 7) << 3;          // read-side elem XOR
  for (int t = 0; t < nt; ++t) {
    if (t + 1 < nt) {
      STAGE256((t + 1) << 6, (t + 1) & 1); // prefetch next tile
      asm volatile("s_waitcnt vmcnt(8)" ::: "memory");   // tile t landed (mine)
    } else {
      asm volatile("s_waitcnt vmcnt(0)" ::: "memory");   // final drain (once)
    }
    __builtin_amdgcn_s_barrier();          // tile t landed (everyone)
    __builtin_amdgcn_sched_barrier(0);
    const unsigned short* As_ = smem + (t & 1) * 16384;
    const unsigned short* Bs_ = smem + 32768 + (t & 1) * 16384;
    bf16x8 bfv[4][2];
#pragma unroll
    for (int ni = 0; ni < 4; ++ni)
#pragma unroll
      for (int ks = 0; ks < 2; ++ks)
        bfv[ni][ks] = *reinterpret_cast<const bf16x8*>(
            &Bs_[(wn + ni * 16 + lrow) * 64 + ((ks * 32 + kq * 8) ^ xr)]);
#pragma unroll
    for (int mi = 0; mi < 8; ++mi) {
      bf16x8 af0 = *reinterpret_cast<const bf16x8*>(
          &As_[(wm + mi * 16 + lrow) * 64 + ((kq * 8) ^ xr)]);
      bf16x8 af1 = *reinterpret_cast<const bf16x8*>(
          &As_[(wm + mi * 16 + lrow) * 64 + ((32 + kq * 8) ^ xr)]);
#pragma unroll
      for (int ni = 0; ni < 4; ++ni) {
        acc[mi][ni] = __builtin_amdgcn_mfma_f32_16x16x32_bf16(af0, bfv[ni][0], acc[mi][ni], 0, 0, 0);
        acc[mi][ni] = __builtin_amdgcn_mfma_f32_16x16x32_bf16(af1, bfv[ni][1], acc[mi][ni], 0, 0, 0);
      }
    }
    __builtin_amdgcn_sched_barrier(0);
    if (t + 1 < nt) __builtin_amdgcn_s_barrier();  // reads done: next STAGE may overwrite
  }
#undef STAGE256

  if (tempPtr) alpha = 1.0f / fmaxf(*tempPtr, 0.01f);

  C += (long)blockIdx.z * sC;
#pragma unroll
  for (int mi = 0; mi < 8; ++mi) {
    int rg = tm0 + wm + mi * 16 + kq * 4;
#pragma unroll
    for (int ni = 0; ni < 4; ++ni) {
      int cg = tn0 + wn + ni * 16 + lrow;
      f32x4 v = acc[mi][ni];
#pragma unroll
      for (int r = 0; r < 4; ++r)
        C[(long)(rg + r) * ldc + cg] = f2bf(v[r] * alpha);
    }
  }
}

// ---------------- row softmax, bf16 in-place, cols == 2048 ----------------
__global__ __launch_bounds__(256)
void k_softmax(unsigned short* __restrict__ S, int cols) {
  const long base = (long)blockIdx.x * cols;
  const int tid = threadIdx.x, lane = tid & 63, wave = tid >> 6;
  const int nv = cols >> 3;
  float f[8];
  float mx = -3.0e38f;
  if (tid < nv) {
    uint4 v = *reinterpret_cast<const uint4*>(S + base + tid * 8);
    const unsigned short* pv = (const unsigned short*)&v;
#pragma unroll
    for (int j = 0; j < 8; ++j) { f[j] = bf2f(pv[j]); mx = fmaxf(mx, f[j]); }
  }
  __shared__ float rmax[4], rsum[4];
#pragma unroll
  for (int o = 32; o > 0; o >>= 1) mx = fmaxf(mx, __shfl_down(mx, o));
  if (lane == 0) rmax[wave] = mx;
  __syncthreads();
  mx = fmaxf(fmaxf(rmax[0], rmax[1]), fmaxf(rmax[2], rmax[3]));
  float sum = 0.f;
  if (tid < nv) {
#pragma unroll
    for (int j = 0; j < 8; ++j) { f[j] = __expf(f[j] - mx); sum += f[j]; }
  }
#pragma unroll
  for (int o = 32; o > 0; o >>= 1) sum += __shfl_down(sum, o);
  if (lane == 0) rsum[wave] = sum;
  __syncthreads();
  const float inv = 1.0f / (rsum[0] + rsum[1] + rsum[2] + rsum[3]);
  if (tid < nv) {
    unsigned short o8[8];
#pragma unroll
    for (int j = 0; j < 8; ++j) o8[j] = f2bf(f[j] * inv);
    *reinterpret_cast<uint4*>(S + base + tid * 8) = *reinterpret_cast<const uint4*>(o8);
  }
}

// ---------------- row softmax cols=1024: 2 rows/block, all lanes live -----
__global__ __launch_bounds__(256)
void k_softmax1024(unsigned short* __restrict__ S) {
  const int tid = threadIdx.x;
  const int half = tid >> 7, ht = tid & 127;       // row-pair half, idx in half
  const int lane = tid & 63, wave = tid >> 6;      // waves {0,1}=row0 {2,3}=row1
  const long base = ((long)blockIdx.x * 2 + half) * 1024;
  uint4 v = *reinterpret_cast<const uint4*>(S + base + ht * 8);
  const unsigned short* pv = (const unsigned short*)&v;
  float f[8];
  float mx = -3.0e38f;
#pragma unroll
  for (int j = 0; j < 8; ++j) { f[j] = bf2f(pv[j]); mx = fmaxf(mx, f[j]); }
  __shared__ float rmax[4], rsum[4];
#pragma unroll
  for (int o = 32; o > 0; o >>= 1) mx = fmaxf(mx, __shfl_down(mx, o));
  if (lane == 0) rmax[wave] = mx;
  __syncthreads();
  mx = fmaxf(rmax[half * 2], rmax[half * 2 + 1]);
  float sum = 0.f;
#pragma unroll
  for (int j = 0; j < 8; ++j) { f[j] = __expf(f[j] - mx); sum += f[j]; }
#pragma unroll
  for (int o = 32; o > 0; o >>= 1) sum += __shfl_down(sum, o);
  if (lane == 0) rsum[wave] = sum;
  __syncthreads();
  const float inv = 1.0f / (rsum[half * 2] + rsum[half * 2 + 1]);
  unsigned short o8[8];
#pragma unroll
  for (int j = 0; j < 8; ++j) o8[j] = f2bf(f[j] * inv);
  *reinterpret_cast<uint4*>(S + base + ht * 8) = *reinterpret_cast<const uint4*>(o8);
}

// ---------------- L2-normalize: 32768 rows of 512 in QK2 [.][1024] --------
__global__ __launch_bounds__(256)
void k_l2norm2(unsigned short* __restrict__ Q) {
  const int lane = threadIdx.x & 63, wave = threadIdx.x >> 6;
  const int idx = blockIdx.x * 4 + wave;            // 0..32767
  unsigned short* p = Q + (long)(idx >> 1) * 1024 + (idx & 1) * 512 + lane * 8;
  uint4 v = *reinterpret_cast<const uint4*>(p);
  const unsigned short* pv = (const unsigned short*)&v;
  float f[8]; float q = 0.f;
#pragma unroll
  for (int j = 0; j < 8; ++j) { f[j] = bf2f(pv[j]); q += f[j] * f[j]; }
#pragma unroll
  for (int o = 32; o > 0; o >>= 1) q += __shfl_xor(q, o);
  float sc = 1.0f / (sqrtf(q) + 1e-8f);
  unsigned short o8[8];
#pragma unroll
  for (int j = 0; j < 8; ++j) o8[j] = f2bf(f[j] * sc);
  *reinterpret_cast<uint4*>(p) = *reinterpret_cast<const uint4*>(o8);
}

// -------- fused LayerNorm(3 branches) + gating: one wave per position -----
__global__ __launch_bounds__(256)
void k_gate(const unsigned short* __restrict__ o0, const unsigned short* __restrict__ o1,
            const unsigned short* __restrict__ o2, const float* __restrict__ gw,
            const float* __restrict__ gb,
            const float* __restrict__ g0, const float* __restrict__ b0,
            const float* __restrict__ g1, const float* __restrict__ b1,
            const float* __restrict__ g2, const float* __restrict__ b2,
            float* __restrict__ out) {
  __shared__ float gws[3 * 1536];
  for (int i = threadIdx.x; i < 3 * 1536; i += 256) gws[i] = gw[i];
  __syncthreads();
  const int lane = threadIdx.x & 63, wave = threadIdx.x >> 6;
  const long pos = (long)blockIdx.x * 4 + wave;
  const long off = pos * CDIM + lane * 8;
  float a[8], bq[8], cq[8];
  {
    uint4 va = *reinterpret_cast<const uint4*>(o0 + off);
    uint4 vb = *reinterpret_cast<const uint4*>(o1 + off);
    uint4 vc = *reinterpret_cast<const uint4*>(o2 + off);
    const unsigned short* pa = (const unsigned short*)&va;
    const unsigned short* pb = (const unsigned short*)&vb;
    const unsigned short* pc = (const unsigned short*)&vc;
#pragma unroll
    for (int j = 0; j < 8; ++j) { a[j] = bf2f(pa[j]); bq[j] = bf2f(pb[j]); cq[j] = bf2f(pc[j]); }
  }
  float sa = 0.f, qa = 0.f, sb = 0.f, qb = 0.f, sc2 = 0.f, qc = 0.f;
#pragma unroll
  for (int j = 0; j < 8; ++j) {
    sa += a[j];  qa += a[j] * a[j];
    sb += bq[j]; qb += bq[j] * bq[j];
    sc2 += cq[j]; qc += cq[j] * cq[j];
  }
#pragma unroll
  for (int o = 32; o > 0; o >>= 1) {
    sa += __shfl_xor(sa, o);  qa += __shfl_xor(qa, o);
    sb += __shfl_xor(sb, o);  qb += __shfl_xor(qb, o);
    sc2 += __shfl_xor(sc2, o); qc += __shfl_xor(qc, o);
  }
  const float inv512 = 1.f / 512.f;
  float mua = sa * inv512, rsa = rsqrtf(qa * inv512 - mua * mua + 1e-5f);
  float mub = sb * inv512, rsb = rsqrtf(qb * inv512 - mub * mub + 1e-5f);
  float muc = sc2 * inv512, rsc = rsqrtf(qc * inv512 - muc * muc + 1e-5f);
  const int ch = lane * 8;
  float gga[8], bba[8], ggb[8], bbb[8], ggc[8], bbc[8];
  *reinterpret_cast<float4*>(&gga[0]) = *reinterpret_cast<const float4*>(g0 + ch);
  *reinterpret_cast<float4*>(&gga[4]) = *reinterpret_cast<const float4*>(g0 + ch + 4);
  *reinterpret_cast<float4*>(&bba[0]) = *reinterpret_cast<const float4*>(b0 + ch);
  *reinterpret_cast<float4*>(&bba[4]) = *reinterpret_cast<const float4*>(b0 + ch + 4);
  *reinterpret_cast<float4*>(&ggb[0]) = *reinterpret_cast<const float4*>(g1 + ch);
  *reinterpret_cast<float4*>(&ggb[4]) = *reinterpret_cast<const float4*>(g1 + ch + 4);
  *reinterpret_cast<float4*>(&bbb[0]) = *reinterpret_cast<const float4*>(b1 + ch);
  *reinterpret_cast<float4*>(&bbb[4]) = *reinterpret_cast<const float4*>(b1 + ch + 4);
  *reinterpret_cast<float4*>(&ggc[0]) = *reinterpret_cast<const float4*>(g2 + ch);
  *reinterpret_cast<float4*>(&ggc[4]) = *reinterpret_cast<const float4*>(g2 + ch + 4);
  *reinterpret_cast<float4*>(&bbc[0]) = *reinterpret_cast<const float4*>(b2 + ch);
  *reinterpret_cast<float4*>(&bbc[4]) = *reinterpret_cast<const float4*>(b2 + ch + 4);
#pragma unroll
  for (int j = 0; j < 8; ++j) {
    a[j]  = (a[j] - mua) * rsa * gga[j] + bba[j];
    bq[j] = (bq[j] - mub) * rsb * ggb[j] + bbb[j];
    cq[j] = (cq[j] - muc) * rsc * ggc[j] + bbc[j];
  }
  float l0 = 0.f, l1 = 0.f, l2 = 0.f;
#pragma unroll
  for (int j = 0; j < 8; ++j) {
    l0 += a[j] * gws[ch + j] + bq[j] * gws[512 + ch + j] + cq[j] * gws[1024 + ch + j];
    l1 += a[j] * gws[1536 + ch + j] + bq[j] * gws[2048 + ch + j] + cq[j] * gws[2560 + ch + j];
    l2 += a[j] * gws[3072 + ch + j] + bq[j] * gws[3584 + ch + j] + cq[j] * gws[4096 + ch + j];
  }
#pragma unroll
  for (int o = 32; o > 0; o >>= 1) {
    l0 += __shfl_xor(l0, o); l1 += __shfl_xor(l1, o); l2 += __shfl_xor(l2, o);
  }
  l0 += gb[0]; l1 += gb[1]; l2 += gb[2];
  float m = fmaxf(l0, fmaxf(l1, l2));
  float e0 = __expf(l0 - m), e1 = __expf(l1 - m), e2 = __expf(l2 - m);
  float inv = 1.f / (e0 + e1 + e2);
  float w0 = e0 * inv, w1 = e1 * inv, w2 = e2 * inv;
  float r[8];
#pragma unroll
  for (int j = 0; j < 8; ++j) r[j] = w0 * a[j] + w1 * bq[j] + w2 * cq[j];
  *reinterpret_cast<float4*>(out + off) = *reinterpret_cast<const float4*>(&r[0]);
  *reinterpret_cast<float4*>(out + off + 4) = *reinterpret_cast<const float4*>(&r[4]);
}

// ===========================================================================
extern "C" void kernel_launch(void* const* d_in, const int* in_sizes, int n_in,
                              void* d_out, int out_size, void* d_ws, size_t ws_size,
                              hipStream_t stream) {
  (void)in_sizes; (void)n_in; (void)out_size;
  const float* x = (const float*)d_in[0];
  const float* dw = (const float*)d_in[1];
  const float* db = (const float*)d_in[2];
  WPtrs wp;
  wp.p[0] = (const float*)d_in[3];   // wq_cr
  wp.p[1] = (const float*)d_in[11];  // wq_d
  wp.p[2] = (const float*)d_in[13];  // wk_d
  wp.p[3] = (const float*)d_in[19];  // wq_c
  wp.p[4] = (const float*)d_in[21];  // wk_c
  wp.p[5] = (const float*)d_in[15];  // wv_d
  wp.p[6] = (const float*)d_in[23];  // wv_c
  wp.p[7] = (const float*)d_in[5];   // wk_cr
  wp.p[8] = (const float*)d_in[7];   // wv_cr
  const float* bq_cr = (const float*)d_in[4];
  const float* bk_cr = (const float*)d_in[6];
  const float* bv_cr = (const float*)d_in[8];
  const float* ln_cr_g = (const float*)d_in[9];
  const float* ln_cr_b = (const float*)d_in[10];
  const float* bq_d = (const float*)d_in[12];
  const float* bk_d = (const float*)d_in[14];
  const float* bv_d = (const float*)d_in[16];
  const float* ln_d_g = (const float*)d_in[17];
  const float* ln_d_b = (const float*)d_in[18];
  const float* bq_c = (const float*)d_in[20];
  const float* bk_c = (const float*)d_in[22];
  const float* bv_c = (const float*)d_in[24];
  const float* ln_c_g = (const float*)d_in[25];
  const float* ln_c_b = (const float*)d_in[26];
  const float* temp = (const float*)d_in[27];
  const float* gw = (const float*)d_in[28];
  const float* gb = (const float*)d_in[29];

  if (ws_size < 243000000ULL) return;  // plan needs ~241.5 MiB (ws >= 250 MB known)

  char* p = (char*)d_ws;
  auto alloc = [&](size_t bytes) {
    void* r = (void*)p;
    p += (bytes + 255) & ~(size_t)255;
    return r;
  };
  alloc(1024);                                                     // front pad
  unsigned short* XB  = (unsigned short*)alloc(16384L * 512 * 2);
  unsigned short* XD  = (unsigned short*)alloc(8192L * 512 * 2);
  unsigned short* WB  = (unsigned short*)alloc(9L * 262144 * 2);
  unsigned short* DWB = (unsigned short*)alloc(512L * 1536 * 2);
  unsigned short* QB  = (unsigned short*)alloc(16384L * 512 * 2);   // q_cr
  unsigned short* KB  = (unsigned short*)alloc(8192L * 512 * 2);    // k_cr
  unsigned short* VT  = (unsigned short*)alloc(1024L * 16384 * 2);  // V^T: cr, then d|c
  unsigned short* OUT0 = (unsigned short*)alloc(16384L * 512 * 2);
  unsigned short* OUT1 = (unsigned short*)alloc(16384L * 512 * 2);
  unsigned short* OUT2 = (unsigned short*)alloc(16384L * 512 * 2);
  unsigned short* QK2 = (unsigned short*)alloc(16384L * 1024 * 2);  // per-branch Q|K
  float* BC = (float*)alloc(3072 * 4);                              // bias concat
  unsigned short* SB = (unsigned short*)alloc(8L * 2048 * 2048 * 2);

  const float scale = 0.044194173824159216f;  // 1/sqrt(512)

  auto gemm = [&](const unsigned short* A, const unsigned short* Bm, void* Cm,
                  int M, int N, int K, int lda, int ldb, int ldc,
                  int batch, long sA, long sB, long sC,
                  const float* bias, float alpha, int mode) {
    dim3 g(M / 128, N / 128, batch);
    k_gemm<<<g, 256, 0, stream>>>(A, Bm, Cm, K, lda, ldb, ldc, sA, sB, sC,
                                  bias, alpha, mode);
  };
  auto gemm64 = [&](const unsigned short* A, const unsigned short* Bm, void* Cm,
                    int M, int N, int K, int lda, int ldb, int ldc,
                    int batch, long sA, long sB, long sC,
                    const float* bias, float alpha, int mode) {
    dim3 g(M / 128, N / 64, batch);
    k_gemm64<<<g, 256, 0, stream>>>(A, Bm, Cm, K, lda, ldb, ldc, sA, sB, sC,
                                    bias, alpha, mode);
  };
  auto gemm256 = [&](const unsigned short* A, const unsigned short* Bm,
                     unsigned short* Cm, int M, int N, int K,
                     int lda, int ldb, int ldc, int batch,
                     long sA, long sB, long sC, float alpha, const float* tp) {
    dim3 g(M / 256, N / 256, batch);
    k_gemm256<<<g, 512, 0, stream>>>(A, Bm, Cm, K, lda, ldb, ldc, sA, sB, sC, alpha, tp);
  };

  // ---- conversions & bias concats ----
  k_tobf16<<<8192, 256, 0, stream>>>(x, XB, 16384L * 512 / 4);
  k_tobf16w<<<2304, 256, 0, stream>>>(wp, WB);
  k_dwreorder<<<3072, 256, 0, stream>>>(dw, DWB);
  hipMemcpyAsync(BC,        bq_d, 512 * 4, hipMemcpyDeviceToDevice, stream);
  hipMemcpyAsync(BC + 512,  bk_d, 512 * 4, hipMemcpyDeviceToDevice, stream);
  hipMemcpyAsync(BC + 1024, bq_c, 512 * 4, hipMemcpyDeviceToDevice, stream);
  hipMemcpyAsync(BC + 1536, bk_c, 512 * 4, hipMemcpyDeviceToDevice, stream);
  hipMemcpyAsync(BC + 2048, bv_d, 512 * 4, hipMemcpyDeviceToDevice, stream);
  hipMemcpyAsync(BC + 2560, bv_c, 512 * 4, hipMemcpyDeviceToDevice, stream);

  // ---- downsample conv: strided-A GEMM ----
  gemm64(XB - 512, DWB, XD, 1024, 512, 1536, 1024, 1536, 512,
         8, 1048576L, 0, 524288L, db, 1.f, 1);
  k_fix<<<1024, 256, 0, stream>>>(XB, DWB, db, XD);   // exact t=0 rows

  // ================= branch cr (q from x, k/v from x_down) =================
  gemm(XB, WB + 0 * 262144L, QB, 16384, 512, 512, 512, 512, 512, 1, 0, 0, 0,
       bq_cr, 1.f, 1);
  gemm64(XD, WB + 7 * 262144L, KB, 8192, 512, 512, 512, 512, 512, 1, 0, 0, 0,
         bk_cr, 1.f, 1);
  gemm64(WB + 8 * 262144L, XD, VT, 512, 8192, 512, 512, 512, 8192, 1, 0, 0, 0,
         bv_cr, 1.f, 3);
  gemm256(QB, KB, SB, 2048, 1024, 512, 512, 512, 1024, 8,
          2048L * 512, 1024L * 512, 2048L * 1024, scale, nullptr);
  k_softmax1024<<<8192, 256, 0, stream>>>(SB);
  gemm(SB, VT, OUT0, 2048, 512, 1024, 1024, 8192, 512, 8,
       2048L * 1024, 1024, 2048L * 512, nullptr, 1.f, 1);

  // ---- fused V^T for d|c: [1024][16384] = [wv_d; wv_c] * XB^T ----
  gemm64(WB + 5 * 262144L, XB, VT, 1024, 16384, 512, 512, 512, 16384, 1, 0, 0, 0,
         BC + 2048, 1.f, 3);

  // ================= branch d (standard attention over x) ==================
  gemm(XB, WB + 1 * 262144L, QK2, 16384, 1024, 512, 512, 512, 1024, 1, 0, 0, 0,
       BC, 1.f, 1);                                  // fused Q|K projection
  gemm256(QK2, QK2 + 512, SB, 2048, 2048, 512, 1024, 1024, 2048, 8,
          2048L * 1024, 2048L * 1024, 2048L * 2048, scale, nullptr);
  k_softmax<<<16384, 256, 0, stream>>>(SB, 2048);
  gemm(SB, VT, OUT1, 2048, 512, 2048, 2048, 16384, 512, 8,
       2048L * 2048, 2048, 2048L * 512, nullptr, 1.f, 1);

  // ================= branch c (cosine attention, learnable temp) ===========
  gemm(XB, WB + 3 * 262144L, QK2, 16384, 1024, 512, 512, 512, 1024, 1, 0, 0, 0,
       BC + 1024, 1.f, 1);                           // fused Q|K projection
  k_l2norm2<<<8192, 256, 0, stream>>>(QK2);          // Q and K halves together
  gemm256(QK2, QK2 + 512, SB, 2048, 2048, 512, 1024, 1024, 2048, 8,
          2048L * 1024, 2048L * 1024, 2048L * 2048, 1.f, temp);
  k_softmax<<<16384, 256, 0, stream>>>(SB, 2048);
  gemm(SB, VT + 512L * 16384, OUT2, 2048, 512, 2048, 2048, 16384, 512, 8,
       2048L * 2048, 2048, 2048L * 512, nullptr, 1.f, 1);

  // ============ fused LN(3 branches) + gating -> d_out ====================
  k_gate<<<4096, 256, 0, stream>>>(OUT0, OUT1, OUT2, gw, gb,
                                   ln_cr_g, ln_cr_b, ln_d_g, ln_d_b,
                                   ln_c_g, ln_c_b, (float*)d_out);
}

// Round 17
// 527.100 us; speedup vs baseline: 1.2599x; 1.0044x over previous
//
#include <hip/hip_runtime.h>

// ---------------------------------------------------------------------------
// Hybrid MRHA: conv-downsample + 3 attention branches + LN + gated fusion.
// k_gemm    : 128x128, BK=64, XOR-swizzled LDS, counted-vmcnt 2-barrier loop.
// k_gemm64  : 128x64 variant — V^T projections, conv, K-cr.
// k_gemm256 : 256x256, BK=64, counted-vmcnt. Scores; cosine branch applies
//             1/(|q|+e)/(|k|+e) reciprocal norms in the epilogue (no l2norm
//             pass — norms factor out of the softmax argument exactly).
// k_gate    : LayerNorm (all 3 branches) + gating fusion in one pass.
// ---------------------------------------------------------------------------

typedef __attribute__((ext_vector_type(8))) __bf16 bf16x8;
typedef __attribute__((ext_vector_type(4))) float f32x4;

#define CDIM 512
#define TFULL 2048

#define GLL16(gp, lp)                                                        \
  __builtin_amdgcn_global_load_lds(                                          \
      (const __attribute__((address_space(1))) unsigned int*)(gp),           \
      (__attribute__((address_space(3))) unsigned int*)(lp), 16, 0, 0)

__device__ __forceinline__ unsigned short f2bf(float f) {
  unsigned u = __float_as_uint(f);
  u = (u + 0x7fffu + ((u >> 16) & 1u)) >> 16;   // round-to-nearest-even
  return (unsigned short)u;
}
__device__ __forceinline__ float bf2f(unsigned short h) {
  return __uint_as_float(((unsigned)h) << 16);
}

// ---------------- conversion: f32 -> bf16 (vec4) ----------------
__global__ __launch_bounds__(256)
void k_tobf16(const float* __restrict__ src, unsigned short* __restrict__ dst, long n4) {
  long i = (long)blockIdx.x * 256 + threadIdx.x;
  if (i >= n4) return;
  float4 f = reinterpret_cast<const float4*>(src)[i];
  unsigned short o4[4] = {f2bf(f.x), f2bf(f.y), f2bf(f.z), f2bf(f.w)};
  reinterpret_cast<uint2*>(dst)[i] = *reinterpret_cast<const uint2*>(o4);
}

// ---------------- batched weight conversion: 9 x 512x512 -> WB ----------
struct WPtrs { const float* p[9]; };
__global__ __launch_bounds__(256)
void k_tobf16w(WPtrs w, unsigned short* __restrict__ dst) {
  int idx = blockIdx.x * 256 + threadIdx.x;       // over 9*65536 vec4 units
  if (idx >= 9 * 65536) return;
  int m = idx >> 16, off = idx & 65535;
  float4 f = reinterpret_cast<const float4*>(w.p[m])[off];
  unsigned short o4[4] = {f2bf(f.x), f2bf(f.y), f2bf(f.z), f2bf(f.w)};
  reinterpret_cast<uint2*>(dst + (long)m * 262144)[off] = *reinterpret_cast<const uint2*>(o4);
}

// ---------------- dw [o][i][k] -> DWB bf16 [o][k*512+i] ----------------
__global__ __launch_bounds__(256)
void k_dwreorder(const float* __restrict__ dw, unsigned short* __restrict__ dwb) {
  int idx = blockIdx.x * 256 + threadIdx.x;           // over 512*1536
  if (idx >= 512 * 1536) return;
  int o = idx / 1536, rem = idx - o * 1536;
  int k = rem >> 9, i = rem & 511;
  dwb[idx] = f2bf(dw[(o * 512 + i) * 3 + k]);
}

// ---------------- conv row-0 fixup: one wave per (b,o), coalesced ---------
__global__ __launch_bounds__(256)
void k_fix(const unsigned short* __restrict__ XB, const unsigned short* __restrict__ DWB,
           const float* __restrict__ db, unsigned short* __restrict__ XD) {
  const int lane = threadIdx.x & 63, wave = threadIdx.x >> 6;
  const int idx = blockIdx.x * 4 + wave;      // 4096 = 8 batches * 512 outputs
  const int b = idx >> 9, o = idx & 511;
  const unsigned short* xr = XB + (long)b * TFULL * CDIM + lane * 16;  // rows 0,1
  const unsigned short* wr = DWB + (long)o * 1536 + 512 + lane * 16;   // taps 1,2
  float acc = 0.f;
  uint4 xv0 = *reinterpret_cast<const uint4*>(xr);
  uint4 xv1 = *reinterpret_cast<const uint4*>(xr + 8);
  uint4 wv0 = *reinterpret_cast<const uint4*>(wr);
  uint4 wv1 = *reinterpret_cast<const uint4*>(wr + 8);
  const unsigned short* xp0 = (const unsigned short*)&xv0;
  const unsigned short* xp1 = (const unsigned short*)&xv1;
  const unsigned short* wp0 = (const unsigned short*)&wv0;
  const unsigned short* wp1 = (const unsigned short*)&wv1;
#pragma unroll
  for (int j = 0; j < 8; ++j) acc += bf2f(xp0[j]) * bf2f(wp0[j]);
#pragma unroll
  for (int j = 0; j < 8; ++j) acc += bf2f(xp1[j]) * bf2f(wp1[j]);
#pragma unroll
  for (int off = 32; off > 0; off >>= 1) acc += __shfl_xor(acc, off);
  if (lane == 0) XD[(long)b * 1024 * 512 + o] = f2bf(acc + db[o]);
}

// ---------------- GEMM 128x128: C = alpha * A * B^T + bias ----------------
// mode 1: bf16 store, bias[col] | mode 3: bf16 store, bias[row]
__global__ __launch_bounds__(256)
void k_gemm(const unsigned short* __restrict__ A,
            const unsigned short* __restrict__ B,
            void* __restrict__ Cp,
            int K, int lda, int ldb, int ldc,
            long sA, long sB, long sC,
            const float* __restrict__ bias,
            float alpha, int mode) {
  const int gx = gridDim.x;
  const int nwg = gx * gridDim.y;
  int wg = blockIdx.x + gx * blockIdx.y;
  wg = (wg & 7) * (nwg >> 3) + (wg >> 3);
  const int tm0 = (wg % gx) * 128, tn0 = (wg / gx) * 128;
  const int bz = blockIdx.z;
  const unsigned short* Ag = A + (long)bz * sA;
  const unsigned short* Bg = B + (long)bz * sB;

  __shared__ __align__(16) unsigned short smem[32768];

  const int tid = threadIdx.x;
  const int lane = tid & 63;
  const int wave = tid >> 6;
  const int wm = (wave >> 1) * 64, wn = (wave & 1) * 64;
  const int lrow = lane & 15, kq = lane >> 4;

  f32x4 acc[4][4];
#pragma unroll
  for (int i = 0; i < 4; ++i)
#pragma unroll
    for (int j = 0; j < 4; ++j) acc[i][j] = f32x4{0.f, 0.f, 0.f, 0.f};

  const int sr = tid >> 3;                 // 0..31
  const int sj = (tid & 7) ^ (sr & 7);     // inverse-swizzled source slot
  const unsigned short* aSrc = Ag + (long)(tm0 + sr) * lda + sj * 8;
  const unsigned short* bSrc = Bg + (long)(tn0 + sr) * ldb + sj * 8;

  const int nt = K >> 6;

#define STAGE(kt_, buf_)                                                     \
  {                                                                          \
    unsigned short* aD = smem + (buf_) * 8192 + wave * 512;                  \
    unsigned short* bD = smem + 16384 + (buf_) * 8192 + wave * 512;          \
    _Pragma("unroll")                                                        \
    for (int rd = 0; rd < 4; ++rd) {                                         \
      GLL16(aSrc + (kt_) + (long)rd * 32 * lda, aD + rd * 2048);             \
      GLL16(bSrc + (kt_) + (long)rd * 32 * ldb, bD + rd * 2048);             \
    }                                                                        \
  }

  STAGE(0, 0);

  const int xr = (lrow & 7) << 3;
  for (int t = 0; t < nt; ++t) {
    if (t + 1 < nt) {
      STAGE((t + 1) << 6, (t + 1) & 1);    // prefetch stays in flight
      asm volatile("s_waitcnt vmcnt(8)" ::: "memory");   // my tile-t loads done
    } else {
      asm volatile("s_waitcnt vmcnt(0)" ::: "memory");   // final drain (once)
    }
    __builtin_amdgcn_s_barrier();          // everyone's tile-t loads done
    __builtin_amdgcn_sched_barrier(0);
    const unsigned short* As_ = smem + (t & 1) * 8192;
    const unsigned short* Bs_ = smem + 16384 + (t & 1) * 8192;
    bf16x8 af[4][2], bfv[4][2];
#pragma unroll
    for (int mi = 0; mi < 4; ++mi)
#pragma unroll
      for (int ks = 0; ks < 2; ++ks)
        af[mi][ks] = *reinterpret_cast<const bf16x8*>(
            &As_[(wm + mi * 16 + lrow) * 64 + ((ks * 32 + kq * 8) ^ xr)]);
#pragma unroll
    for (int ni = 0; ni < 4; ++ni)
#pragma unroll
      for (int ks = 0; ks < 2; ++ks)
        bfv[ni][ks] = *reinterpret_cast<const bf16x8*>(
            &Bs_[(wn + ni * 16 + lrow) * 64 + ((ks * 32 + kq * 8) ^ xr)]);
#pragma unroll
    for (int mi = 0; mi < 4; ++mi)
#pragma unroll
      for (int ni = 0; ni < 4; ++ni) {
        acc[mi][ni] = __builtin_amdgcn_mfma_f32_16x16x32_bf16(af[mi][0], bfv[ni][0], acc[mi][ni], 0, 0, 0);
        acc[mi][ni] = __builtin_amdgcn_mfma_f32_16x16x32_bf16(af[mi][1], bfv[ni][1], acc[mi][ni], 0, 0, 0);
      }
    __builtin_amdgcn_sched_barrier(0);
    if (t + 1 < nt) __builtin_amdgcn_s_barrier();  // reads done: next STAGE may overwrite
  }
#undef STAGE

  unsigned short* Cb = (unsigned short*)Cp + (long)bz * sC;
  if (mode == 1) {
#pragma unroll
    for (int mi = 0; mi < 4; ++mi) {
      int rg = tm0 + wm + mi * 16 + kq * 4;
#pragma unroll
      for (int ni = 0; ni < 4; ++ni) {
        int cg = tn0 + wn + ni * 16 + lrow;
        float bb = bias ? bias[cg] : 0.f;
        f32x4 v = acc[mi][ni];
#pragma unroll
        for (int r = 0; r < 4; ++r)
          Cb[(long)(rg + r) * ldc + cg] = f2bf(v[r] * alpha + bb);
      }
    }
  } else {                                 // mode 3: bias indexed by row
#pragma unroll
    for (int mi = 0; mi < 4; ++mi) {
      int rg = tm0 + wm + mi * 16 + kq * 4;
      float rb[4];
#pragma unroll
      for (int r = 0; r < 4; ++r) rb[r] = bias[rg + r];
#pragma unroll
      for (int ni = 0; ni < 4; ++ni) {
        int cg = tn0 + wn + ni * 16 + lrow;
        f32x4 v = acc[mi][ni];
#pragma unroll
        for (int r = 0; r < 4; ++r)
          Cb[(long)(rg + r) * ldc + cg] = f2bf(v[r] * alpha + rb[r]);
      }
    }
  }
}

// ---------------- GEMM 128x64 (L2-resident-operand shapes) ----------------
__global__ __launch_bounds__(256)
void k_gemm64(const unsigned short* __restrict__ A,
              const unsigned short* __restrict__ B,
              void* __restrict__ Cp,
              int K, int lda, int ldb, int ldc,
              long sA, long sB, long sC,
              const float* __restrict__ bias,
              float alpha, int mode) {
  const int gx = gridDim.x;
  const int nwg = gx * gridDim.y;
  int wg = blockIdx.x + gx * blockIdx.y;
  wg = (wg & 7) * (nwg >> 3) + (wg >> 3);
  const int tm0 = (wg % gx) * 128, tn0 = (wg / gx) * 64;
  const int bz = blockIdx.z;
  const unsigned short* Ag = A + (long)bz * sA;
  const unsigned short* Bg = B + (long)bz * sB;

  __shared__ __align__(16) unsigned short smem[24576];

  const int tid = threadIdx.x;
  const int lane = tid & 63;
  const int wave = tid >> 6;
  const int wm = (wave >> 1) * 64, wn = (wave & 1) * 32;
  const int lrow = lane & 15, kq = lane >> 4;

  f32x4 acc[4][2];
#pragma unroll
  for (int i = 0; i < 4; ++i)
#pragma unroll
    for (int j = 0; j < 2; ++j) acc[i][j] = f32x4{0.f, 0.f, 0.f, 0.f};

  const int sr = tid >> 3;                 // 0..31
  const int sj = (tid & 7) ^ (sr & 7);     // inverse-swizzled source slot
  const unsigned short* aSrc = Ag + (long)(tm0 + sr) * lda + sj * 8;
  const unsigned short* bSrc = Bg + (long)(tn0 + sr) * ldb + sj * 8;

  const int nt = K >> 6;

#define STAGE64(kt_, buf_)                                                   \
  {                                                                          \
    unsigned short* aD = smem + (buf_) * 8192 + wave * 512;                  \
    unsigned short* bD = smem + 16384 + (buf_) * 4096 + wave * 512;          \
    _Pragma("unroll")                                                        \
    for (int rd = 0; rd < 4; ++rd)                                           \
      GLL16(aSrc + (kt_) + (long)rd * 32 * lda, aD + rd * 2048);             \
    _Pragma("unroll")                                                        \
    for (int rd = 0; rd < 2; ++rd)                                           \
      GLL16(bSrc + (kt_) + (long)rd * 32 * ldb, bD + rd * 2048);             \
  }

  STAGE64(0, 0);

  const int xr = (lrow & 7) << 3;
  for (int t = 0; t < nt; ++t) {
    if (t + 1 < nt) {
      STAGE64((t + 1) << 6, (t + 1) & 1);
      asm volatile("s_waitcnt vmcnt(6)" ::: "memory");
    } else {
      asm volatile("s_waitcnt vmcnt(0)" ::: "memory");
    }
    __builtin_amdgcn_s_barrier();
    __builtin_amdgcn_sched_barrier(0);
    const unsigned short* As_ = smem + (t & 1) * 8192;
    const unsigned short* Bs_ = smem + 16384 + (t & 1) * 4096;
    bf16x8 af[4][2], bfv[2][2];
#pragma unroll
    for (int mi = 0; mi < 4; ++mi)
#pragma unroll
      for (int ks = 0; ks < 2; ++ks)
        af[mi][ks] = *reinterpret_cast<const bf16x8*>(
            &As_[(wm + mi * 16 + lrow) * 64 + ((ks * 32 + kq * 8) ^ xr)]);
#pragma unroll
    for (int ni = 0; ni < 2; ++ni)
#pragma unroll
      for (int ks = 0; ks < 2; ++ks)
        bfv[ni][ks] = *reinterpret_cast<const bf16x8*>(
            &Bs_[(wn + ni * 16 + lrow) * 64 + ((ks * 32 + kq * 8) ^ xr)]);
#pragma unroll
    for (int mi = 0; mi < 4; ++mi)
#pragma unroll
      for (int ni = 0; ni < 2; ++ni) {
        acc[mi][ni] = __builtin_amdgcn_mfma_f32_16x16x32_bf16(af[mi][0], bfv[ni][0], acc[mi][ni], 0, 0, 0);
        acc[mi][ni] = __builtin_amdgcn_mfma_f32_16x16x32_bf16(af[mi][1], bfv[ni][1], acc[mi][ni], 0, 0, 0);
      }
    __builtin_amdgcn_sched_barrier(0);
    if (t + 1 < nt) __builtin_amdgcn_s_barrier();
  }
#undef STAGE64

  unsigned short* Cb = (unsigned short*)Cp + (long)bz * sC;
  if (mode == 1) {
#pragma unroll
    for (int mi = 0; mi < 4; ++mi) {
      int rg = tm0 + wm + mi * 16 + kq * 4;
#pragma unroll
      for (int ni = 0; ni < 2; ++ni) {
        int cg = tn0 + wn + ni * 16 + lrow;
        float bb = bias ? bias[cg] : 0.f;
        f32x4 v = acc[mi][ni];
#pragma unroll
        for (int r = 0; r < 4; ++r)
          Cb[(long)(rg + r) * ldc + cg] = f2bf(v[r] * alpha + bb);
      }
    }
  } else {                                 // mode 3: bias indexed by row
#pragma unroll
    for (int mi = 0; mi < 4; ++mi) {
      int rg = tm0 + wm + mi * 16 + kq * 4;
      float rb[4];
#pragma unroll
      for (int r = 0; r < 4; ++r) rb[r] = bias[rg + r];
#pragma unroll
      for (int ni = 0; ni < 2; ++ni) {
        int cg = tn0 + wn + ni * 16 + lrow;
        f32x4 v = acc[mi][ni];
#pragma unroll
        for (int r = 0; r < 4; ++r)
          Cb[(long)(rg + r) * ldc + cg] = f2bf(v[r] * alpha + rb[r]);
      }
    }
  }
}

// ---------------- GEMM 256x256 (scores): C = alpha * A * B^T --------------
// BK=64 dbuf (proven r16), counted vmcnt(8) + 2 raw barriers per K-tile.
// If nq != nullptr: C *= nq[zrow]*nk[zcol] (cosine reciprocal norms).
// Requires M%256==0, N%256==0, K%64==0, (M/256)*(N/256)%8==0.
__global__ __launch_bounds__(512)
void k_gemm256(const unsigned short* __restrict__ A,
               const unsigned short* __restrict__ B,
               unsigned short* __restrict__ C,
               int K, int lda, int ldb, int ldc,
               long sA, long sB, long sC,
               float alpha, const float* __restrict__ tempPtr,
               const float* __restrict__ nq, const float* __restrict__ nk) {
  const int gx = gridDim.x;
  const int nwg = gx * gridDim.y;
  int wg = blockIdx.x + gx * blockIdx.y;
  wg = (wg & 7) * (nwg >> 3) + (wg >> 3);
  const int tm0 = (wg % gx) * 256, tn0 = (wg / gx) * 256;
  const unsigned short* Ag = A + (long)blockIdx.z * sA;
  const unsigned short* Bg = B + (long)blockIdx.z * sB;

  // 128 KiB: A[2][16384] elems then B[2][16384]
  __shared__ __align__(16) unsigned short smem[65536];

  const int tid = threadIdx.x;
  const int lane = tid & 63;
  const int wave = tid >> 6;               // 0..7
  const int wm = (wave >> 2) * 128, wn = (wave & 3) * 64;
  const int lrow = lane & 15, kq = lane >> 4;

  f32x4 acc[8][4];
#pragma unroll
  for (int i = 0; i < 8; ++i)
#pragma unroll
    for (int j = 0; j < 4; ++j) acc[i][j] = f32x4{0.f, 0.f, 0.f, 0.f};

  const int srw = lane >> 3;                           // 0..7
  const int ssl = (lane & 7) ^ srw;                    // inverse swizzle
  const unsigned short* aS = Ag + (long)(tm0 + wave * 32 + srw) * lda + ssl * 8;
  const unsigned short* bS = Bg + (long)(tn0 + wave * 32 + srw) * ldb + ssl * 8;

  const int nt = K >> 6;

#define STAGE256(kt_, buf_)                                                  \
  {                                                                          \
    unsigned short* aD = smem + (buf_) * 16384 + wave * 2048;                \
    unsigned short* bD = smem + 32768 + (buf_) * 16384 + wave * 2048;        \
    _Pragma("unroll")                                                        \
    for (int rd = 0; rd < 4; ++rd) {                                         \
      GLL16(aS + (kt_) + (long)rd * 8 * lda, aD + rd * 512);                 \
      GLL16(bS + (kt_) + (long)rd * 8 * ldb, bD + rd * 512);                 \
    }                                                                        \
  }

  STAGE256(0, 0);                          // prologue

  const int xr = (lrow & 7) << 3;          // read-side elem XOR
  for (int t = 0; t < nt; ++t) {
    if (t + 1 < nt) {
      STAGE256((t + 1) << 6, (t + 1) & 1); // prefetch next tile
      asm volatile("s_waitcnt vmcnt(8)" ::: "memory");   // tile t landed (mine)
    } else {
      asm volatile("s_waitcnt vmcnt(0)" ::: "memory");   // final drain (once)
    }
    __builtin_amdgcn_s_barrier();          // tile t landed (everyone)
    __builtin_amdgcn_sched_barrier(0);
    const unsigned short* As_ = smem + (t & 1) * 16384;
    const unsigned short* Bs_ = smem + 32768 + (t & 1) * 16384;
    bf16x8 bfv[4][2];
#pragma unroll
    for (int ni = 0; ni < 4; ++ni)
#pragma unroll
      for (int ks = 0; ks < 2; ++ks)
        bfv[ni][ks] = *reinterpret_cast<const bf16x8*>(
            &Bs_[(wn + ni * 16 + lrow) * 64 + ((ks * 32 + kq * 8) ^ xr)]);
#pragma unroll
    for (int mi = 0; mi < 8; ++mi) {
      bf16x8 af0 = *reinterpret_cast<const bf16x8*>(
          &As_[(wm + mi * 16 + lrow) * 64 + ((kq * 8) ^ xr)]);
      bf16x8 af1 = *reinterpret_cast<const bf16x8*>(
          &As_[(wm + mi * 16 + lrow) * 64 + ((32 + kq * 8) ^ xr)]);
#pragma unroll
      for (int ni = 0; ni < 4; ++ni) {
        acc[mi][ni] = __builtin_amdgcn_mfma_f32_16x16x32_bf16(af0, bfv[ni][0], acc[mi][ni], 0, 0, 0);
        acc[mi][ni] = __builtin_amdgcn_mfma_f32_16x16x32_bf16(af1, bfv[ni][1], acc[mi][ni], 0, 0, 0);
      }
    }
    __builtin_amdgcn_sched_barrier(0);
    if (t + 1 < nt) __builtin_amdgcn_s_barrier();  // reads done: next STAGE may overwrite
  }
#undef STAGE256

  if (tempPtr) alpha = 1.0f / fmaxf(*tempPtr, 0.01f);

  C += (long)blockIdx.z * sC;
  const int zb = blockIdx.z * 2048;        // global row base of this batch
  if (nq) {                                // cosine: scale by recip norms
#pragma unroll
    for (int mi = 0; mi < 8; ++mi) {
      int rg = tm0 + wm + mi * 16 + kq * 4;
      float nqa[4];
#pragma unroll
      for (int r = 0; r < 4; ++r) nqa[r] = nq[zb + rg + r] * alpha;
#pragma unroll
      for (int ni = 0; ni < 4; ++ni) {
        int cg = tn0 + wn + ni * 16 + lrow;
        const float nkv = nk[zb + cg];
        f32x4 v = acc[mi][ni];
#pragma unroll
        for (int r = 0; r < 4; ++r)
          C[(long)(rg + r) * ldc + cg] = f2bf(v[r] * nqa[r] * nkv);
      }
    }
  } else {
#pragma unroll
    for (int mi = 0; mi < 8; ++mi) {
      int rg = tm0 + wm + mi * 16 + kq * 4;
#pragma unroll
      for (int ni = 0; ni < 4; ++ni) {
        int cg = tn0 + wn + ni * 16 + lrow;
        f32x4 v = acc[mi][ni];
#pragma unroll
        for (int r = 0; r < 4; ++r)
          C[(long)(rg + r) * ldc + cg] = f2bf(v[r] * alpha);
      }
    }
  }
}

// ---------------- row softmax, bf16 in-place, cols == 2048 ----------------
__global__ __launch_bounds__(256)
void k_softmax(unsigned short* __restrict__ S, int cols) {
  const long base = (long)blockIdx.x * cols;
  const int tid = threadIdx.x, lane = tid & 63, wave = tid >> 6;
  const int nv = cols >> 3;
  float f[8];
  float mx = -3.0e38f;
  if (tid < nv) {
    uint4 v = *reinterpret_cast<const uint4*>(S + base + tid * 8);
    const unsigned short* pv = (const unsigned short*)&v;
#pragma unroll
    for (int j = 0; j < 8; ++j) { f[j] = bf2f(pv[j]); mx = fmaxf(mx, f[j]); }
  }
  __shared__ float rmax[4], rsum[4];
#pragma unroll
  for (int o = 32; o > 0; o >>= 1) mx = fmaxf(mx, __shfl_down(mx, o));
  if (lane == 0) rmax[wave] = mx;
  __syncthreads();
  mx = fmaxf(fmaxf(rmax[0], rmax[1]), fmaxf(rmax[2], rmax[3]));
  float sum = 0.f;
  if (tid < nv) {
#pragma unroll
    for (int j = 0; j < 8; ++j) { f[j] = __expf(f[j] - mx); sum += f[j]; }
  }
#pragma unroll
  for (int o = 32; o > 0; o >>= 1) sum += __shfl_down(sum, o);
  if (lane == 0) rsum[wave] = sum;
  __syncthreads();
  const float inv = 1.0f / (rsum[0] + rsum[1] + rsum[2] + rsum[3]);
  if (tid < nv) {
    unsigned short o8[8];
#pragma unroll
    for (int j = 0; j < 8; ++j) o8[j] = f2bf(f[j] * inv);
    *reinterpret_cast<uint4*>(S + base + tid * 8) = *reinterpret_cast<const uint4*>(o8);
  }
}

// ---------------- row softmax cols=1024: 2 rows/block, all lanes live -----
__global__ __launch_bounds__(256)
void k_softmax1024(unsigned short* __restrict__ S) {
  const int tid = threadIdx.x;
  const int half = tid >> 7, ht = tid & 127;       // row-pair half, idx in half
  const int lane = tid & 63, wave = tid >> 6;      // waves {0,1}=row0 {2,3}=row1
  const long base = ((long)blockIdx.x * 2 + half) * 1024;
  uint4 v = *reinterpret_cast<const uint4*>(S + base + ht * 8);
  const unsigned short* pv = (const unsigned short*)&v;
  float f[8];
  float mx = -3.0e38f;
#pragma unroll
  for (int j = 0; j < 8; ++j) { f[j] = bf2f(pv[j]); mx = fmaxf(mx, f[j]); }
  __shared__ float rmax[4], rsum[4];
#pragma unroll
  for (int o = 32; o > 0; o >>= 1) mx = fmaxf(mx, __shfl_down(mx, o));
  if (lane == 0) rmax[wave] = mx;
  __syncthreads();
  mx = fmaxf(rmax[half * 2], rmax[half * 2 + 1]);
  float sum = 0.f;
#pragma unroll
  for (int j = 0; j < 8; ++j) { f[j] = __expf(f[j] - mx); sum += f[j]; }
#pragma unroll
  for (int o = 32; o > 0; o >>= 1) sum += __shfl_down(sum, o);
  if (lane == 0) rsum[wave] = sum;
  __syncthreads();
  const float inv = 1.0f / (rsum[half * 2] + rsum[half * 2 + 1]);
  unsigned short o8[8];
#pragma unroll
  for (int j = 0; j < 8; ++j) o8[j] = f2bf(f[j] * inv);
  *reinterpret_cast<uint4*>(S + base + ht * 8) = *reinterpret_cast<const uint4*>(o8);
}

// ------ reciprocal row norms of QK2 [16384][1024]: NRM[half][row] ---------
__global__ __launch_bounds__(256)
void k_rownorm(const unsigned short* __restrict__ Q, float* __restrict__ NRM) {
  const int lane = threadIdx.x & 63, wave = threadIdx.x >> 6;
  const int idx = blockIdx.x * 4 + wave;            // 0..32767
  const unsigned short* p = Q + (long)(idx >> 1) * 1024 + (idx & 1) * 512 + lane * 8;
  uint4 v = *reinterpret_cast<const uint4*>(p);
  const unsigned short* pv = (const unsigned short*)&v;
  float q = 0.f;
#pragma unroll
  for (int j = 0; j < 8; ++j) { float f = bf2f(pv[j]); q += f * f; }
#pragma unroll
  for (int o = 32; o > 0; o >>= 1) q += __shfl_xor(q, o);
  if (lane == 0) NRM[(idx & 1) * 16384 + (idx >> 1)] = 1.0f / (sqrtf(q) + 1e-8f);
}

// -------- fused LayerNorm(3 branches) + gating: one wave per position -----
__global__ __launch_bounds__(256)
void k_gate(const unsigned short* __restrict__ o0, const unsigned short* __restrict__ o1,
            const unsigned short* __restrict__ o2, const float* __restrict__ gw,
            const float* __restrict__ gb,
            const float* __restrict__ g0, const float* __restrict__ b0,
            const float* __restrict__ g1, const float* __restrict__ b1,
            const float* __restrict__ g2, const float* __restrict__ b2,
            float* __restrict__ out) {
  __shared__ float gws[3 * 1536];
  for (int i = threadIdx.x; i < 3 * 1536; i += 256) gws[i] = gw[i];
  __syncthreads();
  const int lane = threadIdx.x & 63, wave = threadIdx.x >> 6;
  const long pos = (long)blockIdx.x * 4 + wave;
  const long off = pos * CDIM + lane * 8;
  float a[8], bq[8], cq[8];
  {
    uint4 va = *reinterpret_cast<const uint4*>(o0 + off);
    uint4 vb = *reinterpret_cast<const uint4*>(o1 + off);
    uint4 vc = *reinterpret_cast<const uint4*>(o2 + off);
    const unsigned short* pa = (const unsigned short*)&va;
    const unsigned short* pb = (const unsigned short*)&vb;
    const unsigned short* pc = (const unsigned short*)&vc;
#pragma unroll
    for (int j = 0; j < 8; ++j) { a[j] = bf2f(pa[j]); bq[j] = bf2f(pb[j]); cq[j] = bf2f(pc[j]); }
  }
  float sa = 0.f, qa = 0.f, sb = 0.f, qb = 0.f, sc2 = 0.f, qc = 0.f;
#pragma unroll
  for (int j = 0; j < 8; ++j) {
    sa += a[j];  qa += a[j] * a[j];
    sb += bq[j]; qb += bq[j] * bq[j];
    sc2 += cq[j]; qc += cq[j] * cq[j];
  }
#pragma unroll
  for (int o = 32; o > 0; o >>= 1) {
    sa += __shfl_xor(sa, o);  qa += __shfl_xor(qa, o);
    sb += __shfl_xor(sb, o);  qb += __shfl_xor(qb, o);
    sc2 += __shfl_xor(sc2, o); qc += __shfl_xor(qc, o);
  }
  const float inv512 = 1.f / 512.f;
  float mua = sa * inv512, rsa = rsqrtf(qa * inv512 - mua * mua + 1e-5f);
  float mub = sb * inv512, rsb = rsqrtf(qb * inv512 - mub * mub + 1e-5f);
  float muc = sc2 * inv512, rsc = rsqrtf(qc * inv512 - muc * muc + 1e-5f);
  const int ch = lane * 8;
  float gga[8], bba[8], ggb[8], bbb[8], ggc[8], bbc[8];
  *reinterpret_cast<float4*>(&gga[0]) = *reinterpret_cast<const float4*>(g0 + ch);
  *reinterpret_cast<float4*>(&gga[4]) = *reinterpret_cast<const float4*>(g0 + ch + 4);
  *reinterpret_cast<float4*>(&bba[0]) = *reinterpret_cast<const float4*>(b0 + ch);
  *reinterpret_cast<float4*>(&bba[4]) = *reinterpret_cast<const float4*>(b0 + ch + 4);
  *reinterpret_cast<float4*>(&ggb[0]) = *reinterpret_cast<const float4*>(g1 + ch);
  *reinterpret_cast<float4*>(&ggb[4]) = *reinterpret_cast<const float4*>(g1 + ch + 4);
  *reinterpret_cast<float4*>(&bbb[0]) = *reinterpret_cast<const float4*>(b1 + ch);
  *reinterpret_cast<float4*>(&bbb[4]) = *reinterpret_cast<const float4*>(b1 + ch + 4);
  *reinterpret_cast<float4*>(&ggc[0]) = *reinterpret_cast<const float4*>(g2 + ch);
  *reinterpret_cast<float4*>(&ggc[4]) = *reinterpret_cast<const float4*>(g2 + ch + 4);
  *reinterpret_cast<float4*>(&bbc[0]) = *reinterpret_cast<const float4*>(b2 + ch);
  *reinterpret_cast<float4*>(&bbc[4]) = *reinterpret_cast<const float4*>(b2 + ch + 4);
#pragma unroll
  for (int j = 0; j < 8; ++j) {
    a[j]  = (a[j] - mua) * rsa * gga[j] + bba[j];
    bq[j] = (bq[j] - mub) * rsb * ggb[j] + bbb[j];
    cq[j] = (cq[j] - muc) * rsc * ggc[j] + bbc[j];
  }
  float l0 = 0.f, l1 = 0.f, l2 = 0.f;
#pragma unroll
  for (int j = 0; j < 8; ++j) {
    l0 += a[j] * gws[ch + j] + bq[j] * gws[512 + ch + j] + cq[j] * gws[1024 + ch + j];
    l1 += a[j] * gws[1536 + ch + j] + bq[j] * gws[2048 + ch + j] + cq[j] * gws[2560 + ch + j];
    l2 += a[j] * gws[3072 + ch + j] + bq[j] * gws[3584 + ch + j] + cq[j] * gws[4096 + ch + j];
  }
#pragma unroll
  for (int o = 32; o > 0; o >>= 1) {
    l0 += __shfl_xor(l0, o); l1 += __shfl_xor(l1, o); l2 += __shfl_xor(l2, o);
  }
  l0 += gb[0]; l1 += gb[1]; l2 += gb[2];
  float m = fmaxf(l0, fmaxf(l1, l2));
  float e0 = __expf(l0 - m), e1 = __expf(l1 - m), e2 = __expf(l2 - m);
  float inv = 1.f / (e0 + e1 + e2);
  float w0 = e0 * inv, w1 = e1 * inv, w2 = e2 * inv;
  float r[8];
#pragma unroll
  for (int j = 0; j < 8; ++j) r[j] = w0 * a[j] + w1 * bq[j] + w2 * cq[j];
  *reinterpret_cast<float4*>(out + off) = *reinterpret_cast<const float4*>(&r[0]);
  *reinterpret_cast<float4*>(out + off + 4) = *reinterpret_cast<const float4*>(&r[4]);
}

// ===========================================================================
extern "C" void kernel_launch(void* const* d_in, const int* in_sizes, int n_in,
                              void* d_out, int out_size, void* d_ws, size_t ws_size,
                              hipStream_t stream) {
  (void)in_sizes; (void)n_in; (void)out_size;
  const float* x = (const float*)d_in[0];
  const float* dw = (const float*)d_in[1];
  const float* db = (const float*)d_in[2];
  WPtrs wp;
  wp.p[0] = (const float*)d_in[3];   // wq_cr
  wp.p[1] = (const float*)d_in[11];  // wq_d
  wp.p[2] = (const float*)d_in[13];  // wk_d
  wp.p[3] = (const float*)d_in[19];  // wq_c
  wp.p[4] = (const float*)d_in[21];  // wk_c
  wp.p[5] = (const float*)d_in[15];  // wv_d
  wp.p[6] = (const float*)d_in[23];  // wv_c
  wp.p[7] = (const float*)d_in[5];   // wk_cr
  wp.p[8] = (const float*)d_in[7];   // wv_cr
  const float* bq_cr = (const float*)d_in[4];
  const float* bk_cr = (const float*)d_in[6];
  const float* bv_cr = (const float*)d_in[8];
  const float* ln_cr_g = (const float*)d_in[9];
  const float* ln_cr_b = (const float*)d_in[10];
  const float* bq_d = (const float*)d_in[12];
  const float* bk_d = (const float*)d_in[14];
  const float* bv_d = (const float*)d_in[16];
  const float* ln_d_g = (const float*)d_in[17];
  const float* ln_d_b = (const float*)d_in[18];
  const float* bq_c = (const float*)d_in[20];
  const float* bk_c = (const float*)d_in[22];
  const float* bv_c = (const float*)d_in[24];
  const float* ln_c_g = (const float*)d_in[25];
  const float* ln_c_b = (const float*)d_in[26];
  const float* temp = (const float*)d_in[27];
  const float* gw = (const float*)d_in[28];
  const float* gb = (const float*)d_in[29];

  if (ws_size < 243000000ULL) return;  // plan needs ~241.7 MiB (ws >= 250 MB known)

  char* p = (char*)d_ws;
  auto alloc = [&](size_t bytes) {
    void* r = (void*)p;
    p += (bytes + 255) & ~(size_t)255;
    return r;
  };
  alloc(1024);                                                     // front pad
  unsigned short* XB  = (unsigned short*)alloc(16384L * 512 * 2);
  unsigned short* XD  = (unsigned short*)alloc(8192L * 512 * 2);
  unsigned short* WB  = (unsigned short*)alloc(9L * 262144 * 2);
  unsigned short* DWB = (unsigned short*)alloc(512L * 1536 * 2);
  unsigned short* QB  = (unsigned short*)alloc(16384L * 512 * 2);   // q_cr
  unsigned short* KB  = (unsigned short*)alloc(8192L * 512 * 2);    // k_cr
  unsigned short* VT  = (unsigned short*)alloc(1024L * 16384 * 2);  // V^T: cr, then d|c
  unsigned short* OUT0 = (unsigned short*)alloc(16384L * 512 * 2);
  unsigned short* OUT1 = (unsigned short*)alloc(16384L * 512 * 2);
  unsigned short* OUT2 = (unsigned short*)alloc(16384L * 512 * 2);
  unsigned short* QK2 = (unsigned short*)alloc(16384L * 1024 * 2);  // per-branch Q|K
  float* BC = (float*)alloc(3072 * 4);                              // bias concat
  float* NRM = (float*)alloc(32768 * 4);                            // recip norms Q|K
  unsigned short* SB = (unsigned short*)alloc(8L * 2048 * 2048 * 2);

  const float scale = 0.044194173824159216f;  // 1/sqrt(512)

  auto gemm = [&](const unsigned short* A, const unsigned short* Bm, void* Cm,
                  int M, int N, int K, int lda, int ldb, int ldc,
                  int batch, long sA, long sB, long sC,
                  const float* bias, float alpha, int mode) {
    dim3 g(M / 128, N / 128, batch);
    k_gemm<<<g, 256, 0, stream>>>(A, Bm, Cm, K, lda, ldb, ldc, sA, sB, sC,
                                  bias, alpha, mode);
  };
  auto gemm64 = [&](const unsigned short* A, const unsigned short* Bm, void* Cm,
                    int M, int N, int K, int lda, int ldb, int ldc,
                    int batch, long sA, long sB, long sC,
                    const float* bias, float alpha, int mode) {
    dim3 g(M / 128, N / 64, batch);
    k_gemm64<<<g, 256, 0, stream>>>(A, Bm, Cm, K, lda, ldb, ldc, sA, sB, sC,
                                    bias, alpha, mode);
  };
  auto gemm256 = [&](const unsigned short* A, const unsigned short* Bm,
                     unsigned short* Cm, int M, int N, int K,
                     int lda, int ldb, int ldc, int batch,
                     long sA, long sB, long sC, float alpha, const float* tp,
                     const float* nq, const float* nk) {
    dim3 g(M / 256, N / 256, batch);
    k_gemm256<<<g, 512, 0, stream>>>(A, Bm, Cm, K, lda, ldb, ldc, sA, sB, sC,
                                     alpha, tp, nq, nk);
  };

  // ---- conversions & bias concats ----
  k_tobf16<<<8192, 256, 0, stream>>>(x, XB, 16384L * 512 / 4);
  k_tobf16w<<<2304, 256, 0, stream>>>(wp, WB);
  k_dwreorder<<<3072, 256, 0, stream>>>(dw, DWB);
  hipMemcpyAsync(BC,        bq_d, 512 * 4, hipMemcpyDeviceToDevice, stream);
  hipMemcpyAsync(BC + 512,  bk_d, 512 * 4, hipMemcpyDeviceToDevice, stream);
  hipMemcpyAsync(BC + 1024, bq_c, 512 * 4, hipMemcpyDeviceToDevice, stream);
  hipMemcpyAsync(BC + 1536, bk_c, 512 * 4, hipMemcpyDeviceToDevice, stream);
  hipMemcpyAsync(BC + 2048, bv_d, 512 * 4, hipMemcpyDeviceToDevice, stream);
  hipMemcpyAsync(BC + 2560, bv_c, 512 * 4, hipMemcpyDeviceToDevice, stream);

  // ---- downsample conv: strided-A GEMM ----
  gemm64(XB - 512, DWB, XD, 1024, 512, 1536, 1024, 1536, 512,
         8, 1048576L, 0, 524288L, db, 1.f, 1);
  k_fix<<<1024, 256, 0, stream>>>(XB, DWB, db, XD);   // exact t=0 rows

  // ================= branch cr (q from x, k/v from x_down) =================
  gemm(XB, WB + 0 * 262144L, QB, 16384, 512, 512, 512, 512, 512, 1, 0, 0, 0,
       bq_cr, 1.f, 1);
  gemm64(XD, WB + 7 * 262144L, KB, 8192, 512, 512, 512, 512, 512, 1, 0, 0, 0,
         bk_cr, 1.f, 1);
  gemm64(WB + 8 * 262144L, XD, VT, 512, 8192, 512, 512, 512, 8192, 1, 0, 0, 0,
         bv_cr, 1.f, 3);
  gemm256(QB, KB, SB, 2048, 1024, 512, 512, 512, 1024, 8,
          2048L * 512, 1024L * 512, 2048L * 1024, scale, nullptr, nullptr, nullptr);
  k_softmax1024<<<8192, 256, 0, stream>>>(SB);
  gemm(SB, VT, OUT0, 2048, 512, 1024, 1024, 8192, 512, 8,
       2048L * 1024, 1024, 2048L * 512, nullptr, 1.f, 1);

  // ---- fused V^T for d|c: [1024][16384] = [wv_d; wv_c] * XB^T ----
  gemm64(WB + 5 * 262144L, XB, VT, 1024, 16384, 512, 512, 512, 16384, 1, 0, 0, 0,
         BC + 2048, 1.f, 3);

  // ================= branch d (standard attention over x) ==================
  gemm(XB, WB + 1 * 262144L, QK2, 16384, 1024, 512, 512, 512, 1024, 1, 0, 0, 0,
       BC, 1.f, 1);                                  // fused Q|K projection
  gemm256(QK2, QK2 + 512, SB, 2048, 2048, 512, 1024, 1024, 2048, 8,
          2048L * 1024, 2048L * 1024, 2048L * 2048, scale, nullptr, nullptr, nullptr);
  k_softmax<<<16384, 256, 0, stream>>>(SB, 2048);
  gemm(SB, VT, OUT1, 2048, 512, 2048, 2048, 16384, 512, 8,
       2048L * 2048, 2048, 2048L * 512, nullptr, 1.f, 1);

  // ================= branch c (cosine attention, learnable temp) ===========
  gemm(XB, WB + 3 * 262144L, QK2, 16384, 1024, 512, 512, 512, 1024, 1, 0, 0, 0,
       BC + 1024, 1.f, 1);                           // fused Q|K projection
  k_rownorm<<<8192, 256, 0, stream>>>(QK2, NRM);     // 1/(|q|+e), 1/(|k|+e)
  gemm256(QK2, QK2 + 512, SB, 2048, 2048, 512, 1024, 1024, 2048, 8,
          2048L * 1024, 2048L * 1024, 2048L * 2048, 1.f, temp, NRM, NRM + 16384);
  k_softmax<<<16384, 256, 0, stream>>>(SB, 2048);
  gemm(SB, VT + 512L * 16384, OUT2, 2048, 512, 2048, 2048, 16384, 512, 8,
       2048L * 2048, 2048, 2048L * 512, nullptr, 1.f, 1);

  // ============ fused LN(3 branches) + gating -> d_out ====================
  k_gate<<<4096, 256, 0, stream>>>(OUT0, OUT1, OUT2, gw, gb,
                                   ln_cr_g, ln_cr_b, ln_d_g, ln_d_b,
                                   ln_c_g, ln_c_b, (float*)d_out);
}